// Round 14
// baseline (1138.886 us; speedup 1.0000x reference)
//
#include <hip/hip_runtime.h>
#include <math.h>

#define CDIM 256
#define LSEQ 4096
#define NBH 16
#define NPTS 65536
#define KC 256

__device__ __forceinline__ float fadd(float a, float b){ return __fadd_rn(a,b); }
__device__ __forceinline__ float fmul(float a, float b){ return __fmul_rn(a,b); }
__device__ __forceinline__ float fsub(float a, float b){ return __fsub_rn(a,b); }

// numpy contiguous n=32 float32 sum, AVX-512 npyv path (verified R5)
__device__ __forceinline__ float sum32_np(const float* e){
    float l[16];
    #pragma unroll
    for (int j = 0; j < 16; j++) l[j] = fadd(e[j], e[j + 16]);
    float t3[8];
    #pragma unroll
    for (int j = 0; j < 8; j++) t3[j] = fadd(l[j], l[j + 8]);
    float t6[4];
    #pragma unroll
    for (int j = 0; j < 4; j++) t6[j] = fadd(t3[j], t3[j + 4]);
    return fadd(fadd(t6[0], t6[2]), fadd(t6[1], t6[3]));
}

// ---------- LayerNorm, numpy semantics (sequential over c) ----------
__global__ __launch_bounds__(64) void ln_np(const float* __restrict__ x,
        const float* __restrict__ g, const float* __restrict__ bt,
        float* __restrict__ y) {
    int gid = blockIdx.x * 64 + threadIdx.x;
    int b = gid >> 12, l = gid & 4095;
    const float* xb = x + (size_t)b * CDIM * LSEQ + l;
    float s = 0.f;
    #pragma unroll 8
    for (int c = 0; c < 256; c++) s = fadd(s, xb[(size_t)c * LSEQ]);
    float mean = __fdiv_rn(s, 256.f);
    float s2 = 0.f;
    #pragma unroll 8
    for (int c = 0; c < 256; c++) {
        float d = fsub(xb[(size_t)c * LSEQ], mean);
        s2 = fadd(s2, fmul(d, d));
    }
    float var = __fdiv_rn(s2, 256.f);
    float den = fadd(__fsqrt_rn(var), 1e-6f);
    float* yb = y + (size_t)b * CDIM * LSEQ + l;
    #pragma unroll 4
    for (int c = 0; c < 256; c++) {
        float d = fsub(xb[(size_t)c * LSEQ], mean);
        yb[(size_t)c * LSEQ] = fadd(__fdiv_rn(fmul(g[c], d), den), bt[c]);
    }
}

// ---------- conv1x1, SOP semantics, NL l-positions per thread -------
template<int COT, int NL>
__global__ __launch_bounds__(256) void conv_nl(const float* __restrict__ W, int wrow0,
        const float* __restrict__ X, float* __restrict__ Y, int nrows) {
    __shared__ float ws[COT * 256];
    int tid = threadIdx.x;
    int l0 = blockIdx.x * (256 * NL) + tid;
    int o0 = blockIdx.y * COT;
    int b = blockIdx.z;
    {
        const float4* wb4 = (const float4*)(W + (size_t)(wrow0 + o0) * CDIM);
        float4* ws4 = (float4*)ws;
        for (int i = tid; i < COT * 64; i += 256) ws4[i] = wb4[i];
    }
    __syncthreads();
    const float* xb = X + (size_t)b * CDIM * LSEQ;
    float acc[COT][NL];
    #pragma unroll
    for (int oo = 0; oo < COT; oo++)
        #pragma unroll
        for (int i = 0; i < NL; i++) acc[oo][i] = 0.f;
    const float4* ws4 = (const float4*)ws;
    for (int c = 0; c < 256; c += 4) {
        float xv[NL][4];
        #pragma unroll
        for (int i = 0; i < NL; i++) {
            #pragma unroll
            for (int k = 0; k < 4; k++)
                xv[i][k] = xb[(size_t)(c + k) * LSEQ + l0 + i * 256];
        }
        #pragma unroll
        for (int oo = 0; oo < COT; oo++) {
            float4 w = ws4[(oo * 256 + c) >> 2];
            #pragma unroll
            for (int i = 0; i < NL; i++) {
                acc[oo][i] = fadd(acc[oo][i], fmul(w.x, xv[i][0]));
                acc[oo][i] = fadd(acc[oo][i], fmul(w.y, xv[i][1]));
                acc[oo][i] = fadd(acc[oo][i], fmul(w.z, xv[i][2]));
                acc[oo][i] = fadd(acc[oo][i], fmul(w.w, xv[i][3]));
            }
        }
    }
    #pragma unroll
    for (int oo = 0; oo < COT; oo++)
        #pragma unroll
        for (int i = 0; i < NL; i++)
            Y[((size_t)b * nrows + o0 + oo) * LSEQ + l0 + i * 256] = acc[oo][i];
}

// ---------- fold (+ l2norm, + xx out, + cent/cc init) ---------------
__global__ __launch_bounds__(256) void fold_np(const float* __restrict__ src,
        int srcRows, int row0, int donorm, float* __restrict__ dst,
        float* __restrict__ xxout, float* __restrict__ centout,
        float* __restrict__ ccout) {
    int p = blockIdx.x * 256 + threadIdx.x;
    int bh = p >> 12, l = p & 4095;
    int b = bh >> 3, h = bh & 7;
    const float* sp = src + ((size_t)b * srcRows + row0 + h * 32) * LSEQ + l;
    float x[32];
    #pragma unroll
    for (int t = 0; t < 32; t++) x[t] = sp[(size_t)t * LSEQ];
    float4* dp4 = (float4*)(dst + (size_t)p * 32);
    if (donorm) {
        float ss = 0.f;
        #pragma unroll
        for (int t = 0; t < 32; t++) ss = fadd(ss, fmul(x[t], x[t]));
        float n = __fsqrt_rn(ss);
        float den = fmaxf(n, 1e-12f);
        #pragma unroll
        for (int t = 0; t < 32; t++) x[t] = __fdiv_rn(x[t], den);
    }
    #pragma unroll
    for (int t = 0; t < 8; t++)
        dp4[t] = make_float4(x[4*t], x[4*t+1], x[4*t+2], x[4*t+3]);
    if (xxout) {
        float e[32];
        #pragma unroll
        for (int t = 0; t < 32; t++) e[t] = fmul(x[t], x[t]);
        float xv = sum32_np(e);
        xxout[p] = xv;
        // initial centroids are rows 0..255 of q_t: cc[j] == xx[j] (same op)
        if (centout && p < KC) {
            float4* cp4 = (float4*)(centout + (size_t)p * 32);
            #pragma unroll
            for (int t = 0; t < 8; t++)
                cp4[t] = make_float4(x[4*t], x[4*t+1], x[4*t+2], x[4*t+3]);
            ccout[p] = xv;
        }
    }
}

// ---------- argmin+hist: 512 thr, half-split per lane pair ----------
// 256 blocks x 256 points; merge strict < (half0 lower-j) == sequential
// argmin 0..255 bit-exact (verified R10/R11).
__global__ __launch_bounds__(512) void assign_512h(const float* __restrict__ pts,
        const float* __restrict__ xx, const float* __restrict__ cent,
        const float* __restrict__ cc, int* __restrict__ asn, int* __restrict__ hist) {
    __shared__ float sc[8192];
    __shared__ float scc[256];
    __shared__ int bins[256];
    int tid = threadIdx.x, c = blockIdx.x;
    {
        const float4* c4 = (const float4*)cent;
        float4* s4 = (float4*)sc;
        for (int i = tid; i < 2048; i += 512) s4[i] = c4[i];
    }
    if (tid < 256) { scc[tid] = cc[tid]; bins[tid] = 0; }
    __syncthreads();
    int pl = tid >> 1, half = tid & 1;
    int p = c * 256 + pl;
    float x[32];
    {
        const float4* pp = (const float4*)(pts + (size_t)p * 32);
        #pragma unroll
        for (int t = 0; t < 8; t++) {
            float4 f = pp[t];
            x[4*t] = f.x; x[4*t+1] = f.y; x[4*t+2] = f.z; x[4*t+3] = f.w;
        }
    }
    float xp = xx[p];
    float bd = 3.4e38f; int bj = 0;
    int jbase = half * 128;
    for (int jj = 0; jj < 128; jj++) {
        int j = jbase + jj;
        const float4* cj = (const float4*)(sc + j * 32);
        float g = 0.f;
        #pragma unroll
        for (int t = 0; t < 8; t++) {
            float4 w = cj[t];
            g = __builtin_fmaf(x[4*t],   w.x, g);
            g = __builtin_fmaf(x[4*t+1], w.y, g);
            g = __builtin_fmaf(x[4*t+2], w.z, g);
            g = __builtin_fmaf(x[4*t+3], w.w, g);
        }
        float d = fadd(fsub(xp, fmul(2.f, g)), scc[j]);
        if (d < bd) { bd = d; bj = j; }
    }
    float bd1 = __shfl_xor(bd, 1);
    int   bj1 = __shfl_xor(bj, 1);
    if (half == 0) {
        if (bd1 < bd) { bd = bd1; bj = bj1; }
        asn[p] = bj;
        atomicAdd(&bins[bj], 1);
    }
    __syncthreads();
    if (tid < 256) hist[c * 256 + tid] = bins[tid];
}

// ---------- per-cluster prefix over 256 chunks ----------------------
__global__ __launch_bounds__(256) void scan_chunks(const int* __restrict__ hist,
        int* __restrict__ chunkbase, int* __restrict__ totals) {
    __shared__ int a[256];
    int j = blockIdx.x, c = threadIdx.x;
    a[c] = hist[(size_t)c * 256 + j];
    __syncthreads();
    for (int d = 1; d < 256; d <<= 1) {
        int v = a[c];
        int u = (c >= d) ? a[c - d] : 0;
        __syncthreads();
        a[c] = v + u;
        __syncthreads();
    }
    chunkbase[(size_t)c * 256 + j] = (c == 0) ? 0 : a[c - 1];
    if (c == 255) totals[j] = a[255];
}

// ---------- scatter: parallel cbase scan + stable rank --------------
__global__ __launch_bounds__(256) void scatter_v5(const int* __restrict__ asn,
        const int* __restrict__ chunkbase, const int* __restrict__ totals,
        int* __restrict__ perm) {
    __shared__ int cb[256];
    __shared__ int al[256];
    int c = blockIdx.x, tid = threadIdx.x;
    cb[tid] = totals[tid];
    al[tid] = asn[c * 256 + tid];
    __syncthreads();
    for (int d = 1; d < 256; d <<= 1) {
        int v = cb[tid];
        int u = (tid >= d) ? cb[tid - d] : 0;
        __syncthreads();
        cb[tid] = v + u;
        __syncthreads();
    }
    int my = al[tid];
    int base = (my == 0) ? 0 : cb[my - 1];
    int r = 0;
    for (int i = 0; i < tid; i++) r += (al[i] == my) ? 1 : 0;
    perm[base + chunkbase[(size_t)c * 256 + my] + r] = c * 256 + tid;
}

// ---------- ordered sum + update + cc (parallel cbase scan) ---------
#define STILE 128
__global__ __launch_bounds__(256) void sumk_v4(const float* __restrict__ pts,
        const int* __restrict__ perm, const int* __restrict__ totals,
        float* __restrict__ cent, float* __restrict__ cc) {
    __shared__ int cb[256];
    __shared__ float buf[2][STILE][32];
    int j = blockIdx.x, tid = threadIdx.x;
    cb[tid] = totals[tid];
    __syncthreads();
    for (int d = 1; d < 256; d <<= 1) {
        int v = cb[tid];
        int u = (tid >= d) ? cb[tid - d] : 0;
        __syncthreads();
        cb[tid] = v + u;
        __syncthreads();
    }
    int base = (j == 0) ? 0 : cb[j - 1];
    int n = totals[j];
    int t = tid & 31, r0 = tid >> 5;
    for (int r = r0; r < STILE; r += 8) {
        if (r < n) buf[0][r][t] = pts[(size_t)perm[base + r] * 32 + t];
    }
    __syncthreads();
    float s = 0.f;
    int b = 0;
    for (int i0 = 0; i0 < n; i0 += STILE, b ^= 1) {
        int nx = i0 + STILE;
        if (nx < n) {
            for (int r = r0; r < STILE; r += 8) {
                int g = nx + r;
                if (g < n) buf[b ^ 1][r][t] = pts[(size_t)perm[base + g] * 32 + t];
            }
        }
        if (tid < 32) {
            int m = n - i0; if (m > STILE) m = STILE;
            int i = 0;
            for (; i + 4 <= m; i += 4) {
                s = fadd(s, buf[b][i][tid]);
                s = fadd(s, buf[b][i + 1][tid]);
                s = fadd(s, buf[b][i + 2][tid]);
                s = fadd(s, buf[b][i + 3][tid]);
            }
            for (; i < m; i++) s = fadd(s, buf[b][i][tid]);
        }
        __syncthreads();
    }
    if (tid < 32) {
        float v;
        if (n > 0) {
            v = __fdiv_rn(s, (float)n);
            cent[(size_t)j * 32 + tid] = v;
        } else {
            v = cent[(size_t)j * 32 + tid];
        }
        float e = fmul(v, v);
        e = fadd(e, __shfl_xor(e, 16));
        e = fadd(e, __shfl_xor(e, 8));
        e = fadd(e, __shfl_xor(e, 4));
        e = fadd(e, __shfl_xor(e, 2));
        e = fadd(e, __shfl_xor(e, 1));
        if (tid == 0) cc[j] = e;
    }
}

// ---------- key assign + L1: 512 thr, half-split, inline xx ---------
__global__ __launch_bounds__(512) void kdist_512h(const float* __restrict__ pts,
        const float* __restrict__ cent, const float* __restrict__ cc,
        float* __restrict__ kd) {
    __shared__ float sc[8192];
    __shared__ float scc[256];
    int tid = threadIdx.x, c = blockIdx.x;
    {
        const float4* c4 = (const float4*)cent;
        float4* s4 = (float4*)sc;
        for (int i = tid; i < 2048; i += 512) s4[i] = c4[i];
    }
    if (tid < 256) scc[tid] = cc[tid];
    __syncthreads();
    int pl = tid >> 1, half = tid & 1;
    int p = c * 256 + pl;
    float x[32];
    {
        const float4* pp = (const float4*)(pts + (size_t)p * 32);
        #pragma unroll
        for (int t = 0; t < 8; t++) {
            float4 f = pp[t];
            x[4*t] = f.x; x[4*t+1] = f.y; x[4*t+2] = f.z; x[4*t+3] = f.w;
        }
    }
    float xp;
    {
        float e[32];
        #pragma unroll
        for (int t = 0; t < 32; t++) e[t] = fmul(x[t], x[t]);
        xp = sum32_np(e);   // identical bits to fold's xx
    }
    float bd = 3.4e38f; int bj = 0;
    int jbase = half * 128;
    for (int jj = 0; jj < 128; jj++) {
        int j = jbase + jj;
        const float4* cj = (const float4*)(sc + j * 32);
        float g = 0.f;
        #pragma unroll
        for (int t = 0; t < 8; t++) {
            float4 w = cj[t];
            g = __builtin_fmaf(x[4*t],   w.x, g);
            g = __builtin_fmaf(x[4*t+1], w.y, g);
            g = __builtin_fmaf(x[4*t+2], w.z, g);
            g = __builtin_fmaf(x[4*t+3], w.w, g);
        }
        float d = fadd(fsub(xp, fmul(2.f, g)), scc[j]);
        if (d < bd) { bd = d; bj = j; }
    }
    float bd1 = __shfl_xor(bd, 1);
    int   bj1 = __shfl_xor(bj, 1);
    if (half == 0) {
        if (bd1 < bd) { bd = bd1; bj = bj1; }
        const float* cb = &sc[bj * 32];
        float e[32];
        #pragma unroll
        for (int t = 0; t < 32; t++) e[t] = fabsf(fsub(cb[t], x[t]));
        kd[p] = sum32_np(e);
    }
}

// ---------- top-256 via radix select (exact stable set) + gather ----
__global__ __launch_bounds__(256) void topk_v2(const float* __restrict__ kd,
        const float* __restrict__ k_t, const float* __restrict__ v_t,
        float* __restrict__ ksel, float* __restrict__ vsel) {
    __shared__ unsigned uv[4096];
    __shared__ int hist[256];
    __shared__ unsigned s_prefix;
    __shared__ int s_rem;
    __shared__ int sc1[256];
    __shared__ int out_src[256];
    int bh = blockIdx.x, tid = threadIdx.x;
    for (int i = tid; i < 4096; i += 256) uv[i] = __float_as_uint(kd[bh * 4096 + i]);
    if (tid == 0) { s_prefix = 0u; s_rem = 256; }
    out_src[tid] = 0;
    __syncthreads();
    for (int pass = 0; pass < 4; pass++) {
        int shift = 24 - 8 * pass;
        hist[tid] = 0;
        __syncthreads();
        unsigned pfx = s_prefix;
        for (int i = tid; i < 4096; i += 256) {
            unsigned u = uv[i];
            bool in = (pass == 0) || ((u >> (shift + 8)) == (pfx >> (shift + 8)));
            if (in) atomicAdd(&hist[(u >> shift) & 255], 1);
        }
        __syncthreads();
        if (tid == 0) {
            int rem = s_rem, cum = 0, b;
            for (b = 255; b >= 0; b--) {
                if (cum + hist[b] >= rem) break;
                cum += hist[b];
            }
            s_rem = rem - cum;
            s_prefix = s_prefix | ((unsigned)b << shift);
        }
        __syncthreads();
    }
    unsigned T = s_prefix;
    int r = s_rem;
    int base_i = tid * 16;
    int ec = 0;
    for (int q = 0; q < 16; q++) ec += (uv[base_i + q] == T) ? 1 : 0;
    sc1[tid] = ec;
    __syncthreads();
    for (int d = 1; d < 256; d <<= 1) {
        int t0 = sc1[tid];
        int u0 = (tid >= d) ? sc1[tid - d] : 0;
        __syncthreads();
        sc1[tid] = t0 + u0;
        __syncthreads();
    }
    int erank = (tid == 0) ? 0 : sc1[tid - 1];
    __syncthreads();
    bool incl[16];
    int ic = 0;
    for (int q = 0; q < 16; q++) {
        unsigned u = uv[base_i + q];
        bool inc;
        if (u > T) inc = true;
        else if (u == T) { inc = (erank < r); erank++; }
        else inc = false;
        incl[q] = inc;
        ic += inc ? 1 : 0;
    }
    sc1[tid] = ic;
    __syncthreads();
    for (int d = 1; d < 256; d <<= 1) {
        int t0 = sc1[tid];
        int u0 = (tid >= d) ? sc1[tid - d] : 0;
        __syncthreads();
        sc1[tid] = t0 + u0;
        __syncthreads();
    }
    int pos = (tid == 0) ? 0 : sc1[tid - 1];
    for (int q = 0; q < 16; q++) {
        if (incl[q]) out_src[pos++] = base_i + q;
    }
    __syncthreads();
    for (int e = tid; e < 256 * 32; e += 256) {
        int jj = e >> 5, t = e & 31;
        int src = out_src[jj];
        ksel[(size_t)bh * 8192 + e] = k_t[((size_t)bh * 4096 + src) * 32 + t];
        vsel[(size_t)bh * 8192 + e] = v_t[((size_t)bh * 4096 + src) * 32 + t];
    }
}

// ---------- attention v4: 512 thr (2 waves/SIMD), padded halves -----
#define HPAD 4112   // 4096 + 16 floats: bank offset 16 between halves
__global__ __launch_bounds__(512) void attn_v4(const float* __restrict__ q_t,
        const float* __restrict__ ksel, const float* __restrict__ vsel,
        float* __restrict__ out) {
    __shared__ float sk[2 * HPAD];
    __shared__ float sv[2 * HPAD];
    int bh = blockIdx.y, tid = threadIdx.x;
    {
        const float4* gk = (const float4*)(ksel + (size_t)bh * 8192);
        const float4* gv = (const float4*)(vsel + (size_t)bh * 8192);
        for (int i = tid; i < 2048; i += 512) {
            int h = i >> 10, idx = i & 1023;
            ((float4*)(sk + h * HPAD))[idx] = gk[i];
            ((float4*)(sv + h * HPAD))[idx] = gv[i];
        }
    }
    __syncthreads();
    int ql = tid >> 1, slice = tid & 1;
    int p = bh * 4096 + blockIdx.x * 256 + ql;
    float q[32];
    {
        const float4* qp = (const float4*)(q_t + (size_t)p * 32);
        #pragma unroll
        for (int t = 0; t < 8; t++) {
            float4 f = qp[t];
            q[4*t] = f.x; q[4*t+1] = f.y; q[4*t+2] = f.z; q[4*t+3] = f.w;
        }
    }
    float o[32];
    #pragma unroll
    for (int t = 0; t < 32; t++) o[t] = 0.f;
    float lsum = 0.f;
    const float4* k4 = (const float4*)(sk + slice * HPAD);
    const float4* v4 = (const float4*)(sv + slice * HPAD);
    for (int j = 0; j < 128; j++) {
        float a0 = 0.f, b0 = 0.f, c0 = 0.f, d0 = 0.f;
        #pragma unroll
        for (int t = 0; t < 8; t++) {
            float4 kf = k4[j * 8 + t];
            a0 += q[4*t]   * kf.x; b0 += q[4*t+1] * kf.y;
            c0 += q[4*t+2] * kf.z; d0 += q[4*t+3] * kf.w;
        }
        float s = (a0 + b0) + (c0 + d0);
        float w = __expf(s - 1.0f);   // s <= 1 (unit vectors)
        lsum += w;
        #pragma unroll
        for (int t = 0; t < 8; t++) {
            float4 vf = v4[j * 8 + t];
            o[4*t]   += w * vf.x; o[4*t+1] += w * vf.y;
            o[4*t+2] += w * vf.z; o[4*t+3] += w * vf.w;
        }
    }
    #pragma unroll
    for (int t = 0; t < 32; t++) o[t] += __shfl_xor(o[t], 1);
    lsum += __shfl_xor(lsum, 1);
    if (slice == 0) {
        float inv = 1.f / lsum;
        float4* op = (float4*)(out + (size_t)p * 32);
        #pragma unroll
        for (int t = 0; t < 8; t++)
            op[t] = make_float4(o[4*t]*inv, o[4*t+1]*inv, o[4*t+2]*inv, o[4*t+3]*inv);
    }
}

// ---------- unfold (bh,L,32) -> (b,256,L) ---------------------------
__global__ __launch_bounds__(256) void unfold_kernel(const float* __restrict__ att,
        float* __restrict__ Fo) {
    __shared__ float tbuf[32][65];
    int bh = blockIdx.y, l0 = blockIdx.x * 64;
    int b = bh >> 3, h = bh & 7;
    int tid = threadIdx.x;
    #pragma unroll
    for (int r = 0; r < 8; r++) {
        int e = r * 256 + tid;
        int l = e >> 5, d = e & 31;
        tbuf[d][l] = att[((size_t)bh * 4096 + l0 + l) * 32 + d];
    }
    __syncthreads();
    #pragma unroll
    for (int r = 0; r < 8; r++) {
        int e = r * 256 + tid;
        int d = e >> 6, l = e & 63;
        Fo[((size_t)b * 256 + h * 32 + d) * LSEQ + l0 + l] = tbuf[d][l];
    }
}

// ---------- final LN + scale + residual (numpy orders) --------------
__global__ __launch_bounds__(64) void lnres_np(const float* __restrict__ x,
        const float* __restrict__ g, const float* __restrict__ bt,
        const float* __restrict__ gs, const float* __restrict__ qsrc,
        float* __restrict__ y) {
    int gid = blockIdx.x * 64 + threadIdx.x;
    int b = gid >> 12, l = gid & 4095;
    const float* xb = x + (size_t)b * CDIM * LSEQ + l;
    float s = 0.f;
    #pragma unroll 8
    for (int c = 0; c < 256; c++) s = fadd(s, xb[(size_t)c * LSEQ]);
    float mean = __fdiv_rn(s, 256.f);
    float s2 = 0.f;
    #pragma unroll 8
    for (int c = 0; c < 256; c++) {
        float d = fsub(xb[(size_t)c * LSEQ], mean);
        s2 = fadd(s2, fmul(d, d));
    }
    float var = __fdiv_rn(s2, 256.f);
    float den = fadd(__fsqrt_rn(var), 1e-6f);
    float scale = gs[0];
    const float* qb = qsrc + (size_t)b * CDIM * LSEQ + l;
    float* yb = y + (size_t)b * CDIM * LSEQ + l;
    #pragma unroll 4
    for (int c = 0; c < 256; c++) {
        float d = fsub(xb[(size_t)c * LSEQ], mean);
        float r = fadd(__fdiv_rn(fmul(g[c], d), den), bt[c]);
        yb[(size_t)c * LSEQ] = fadd(fmul(scale, r), qb[(size_t)c * LSEQ]);
    }
}

// ==================================================================
extern "C" void kernel_launch(void* const* d_in, const int* in_sizes, int n_in,
                              void* d_out, int out_size, void* d_ws, size_t ws_size,
                              hipStream_t stream) {
    const float* qsrc   = (const float*)d_in[0];
    const float* ctx    = (const float*)d_in[1];
    const float* w_q    = (const float*)d_in[2];
    const float* w_kv   = (const float*)d_in[3];
    const float* w_out  = (const float*)d_in[4];
    const float* g_ctx  = (const float*)d_in[5];
    const float* b_ctx  = (const float*)d_in[6];
    const float* g_q    = (const float*)d_in[7];
    const float* b_q    = (const float*)d_in[8];
    const float* g_out  = (const float*)d_in[9];
    const float* b_out  = (const float*)d_in[10];
    const float* gs     = (const float*)d_in[11];

    char* base = (char*)d_ws;
    const size_t MB = 1024 * 1024;
    float* yln   = (float*)base;               // [0,8) LN out; later att
    float* att   = (float*)base;
    float* kvbuf = (float*)(base + 8 * MB);    // [8,24) kv conv; later y32 [8,16)
    float* y32   = (float*)(base + 8 * MB);
    float* qbuf  = (float*)(base + 24 * MB);   // [24,32) q conv; later Fo
    float* Fo    = (float*)(base + 24 * MB);
    float* q_t   = (float*)(base + 32 * MB);   // [32,40)
    float* k_t   = (float*)(base + 40 * MB);   // [40,48)
    float* v_t   = (float*)(base + 48 * MB);   // [48,56)
    char* SM = base + 56 * MB;
    float* xx_q      = (float*)(SM + 0);            // 256 KB
    float* cent      = (float*)(SM + 512 * 1024);   // 32 KB
    float* cc        = (float*)(SM + 576 * 1024);   // 1 KB
    int*   totals    = (int*)  (SM + 640 * 1024);   // 1 KB
    int*   asn       = (int*)  (SM + 704 * 1024);   // 256 KB
    int*   hist      = (int*)  (SM + 960 * 1024);   // 256 KB
    int*   chunkbase = (int*)  (SM + 1472 * 1024);  // 256 KB
    int*   perm      = (int*)  (SM + 1984 * 1024);  // 256 KB
    float* kd        = (float*)(SM + 2240 * 1024);  // 256 KB
    float* ksel      = (float*)(SM + 2496 * 1024);  // 512 KB
    float* vsel      = (float*)(SM + 3008 * 1024);  // 512 KB

    // context branch
    ln_np<<<128, 64, 0, stream>>>(ctx, g_ctx, b_ctx, yln);
    conv_nl<16, 2><<<dim3(8, 32, 2), 256, 0, stream>>>(w_kv, 0, yln, kvbuf, 512);
    fold_np<<<256, 256, 0, stream>>>(kvbuf, 512, 0, 1, k_t, nullptr, nullptr, nullptr);
    fold_np<<<256, 256, 0, stream>>>(kvbuf, 512, 256, 0, v_t, nullptr, nullptr, nullptr);
    // query branch (fold also emits xx and initial cent/cc)
    ln_np<<<128, 64, 0, stream>>>(qsrc, g_q, b_q, yln);
    conv_nl<8, 2><<<dim3(8, 32, 2), 256, 0, stream>>>(w_q, 0, yln, qbuf, 256);
    fold_np<<<256, 256, 0, stream>>>(qbuf, 256, 0, 1, q_t, xx_q, cent, cc);

    for (int it = 0; it < 10; it++) {
        assign_512h<<<256, 512, 0, stream>>>(q_t, xx_q, cent, cc, asn, hist);
        scan_chunks<<<256, 256, 0, stream>>>(hist, chunkbase, totals);
        scatter_v5<<<256, 256, 0, stream>>>(asn, chunkbase, totals, perm);
        sumk_v4<<<256, 256, 0, stream>>>(q_t, perm, totals, cent, cc);
    }

    kdist_512h<<<256, 512, 0, stream>>>(k_t, cent, cc, kd);
    topk_v2<<<16, 256, 0, stream>>>(kd, k_t, v_t, ksel, vsel);
    attn_v4<<<dim3(16, 16), 512, 0, stream>>>(q_t, ksel, vsel, att);
    unfold_kernel<<<dim3(64, 16), 256, 0, stream>>>(att, Fo);
    conv_nl<8, 2><<<dim3(8, 32, 2), 256, 0, stream>>>(w_out, 0, Fo, y32, 256);
    lnres_np<<<128, 64, 0, stream>>>(y32, g_out, b_out, gs, qsrc, (float*)d_out);
}

// Round 15
// 1042.035 us; speedup vs baseline: 1.0929x; 1.0929x over previous
//
#include <hip/hip_runtime.h>
#include <math.h>

#define CDIM 256
#define LSEQ 4096
#define NBH 16
#define NPTS 65536
#define KC 256

__device__ __forceinline__ float fadd(float a, float b){ return __fadd_rn(a,b); }
__device__ __forceinline__ float fmul(float a, float b){ return __fmul_rn(a,b); }
__device__ __forceinline__ float fsub(float a, float b){ return __fsub_rn(a,b); }

// numpy contiguous n=32 float32 sum, AVX-512 npyv path (verified R5)
__device__ __forceinline__ float sum32_np(const float* e){
    float l[16];
    #pragma unroll
    for (int j = 0; j < 16; j++) l[j] = fadd(e[j], e[j + 16]);
    float t3[8];
    #pragma unroll
    for (int j = 0; j < 8; j++) t3[j] = fadd(l[j], l[j + 8]);
    float t6[4];
    #pragma unroll
    for (int j = 0; j < 4; j++) t6[j] = fadd(t3[j], t3[j + 4]);
    return fadd(fadd(t6[0], t6[2]), fadd(t6[1], t6[3]));
}

// ---------- LayerNorm, numpy semantics (sequential over c) ----------
__global__ __launch_bounds__(64) void ln_np(const float* __restrict__ x,
        const float* __restrict__ g, const float* __restrict__ bt,
        float* __restrict__ y) {
    int gid = blockIdx.x * 64 + threadIdx.x;
    int b = gid >> 12, l = gid & 4095;
    const float* xb = x + (size_t)b * CDIM * LSEQ + l;
    float s = 0.f;
    #pragma unroll 8
    for (int c = 0; c < 256; c++) s = fadd(s, xb[(size_t)c * LSEQ]);
    float mean = __fdiv_rn(s, 256.f);
    float s2 = 0.f;
    #pragma unroll 8
    for (int c = 0; c < 256; c++) {
        float d = fsub(xb[(size_t)c * LSEQ], mean);
        s2 = fadd(s2, fmul(d, d));
    }
    float var = __fdiv_rn(s2, 256.f);
    float den = fadd(__fsqrt_rn(var), 1e-6f);
    float* yb = y + (size_t)b * CDIM * LSEQ + l;
    #pragma unroll 4
    for (int c = 0; c < 256; c++) {
        float d = fsub(xb[(size_t)c * LSEQ], mean);
        yb[(size_t)c * LSEQ] = fadd(__fdiv_rn(fmul(g[c], d), den), bt[c]);
    }
}

// ---------- conv1x1, LDS-free: scalar W (wave-uniform o), SOP exact -
// block 256 = 4 waves; wave w handles o-row (o0 + w + 4i), i=0..3;
// each thread 2 l's. Per-(o,l) chain: c ascending, fadd(fmul) — exact.
__global__ __launch_bounds__(256) void conv_sw(const float* __restrict__ W, int wrow0,
        const float* __restrict__ X, float* __restrict__ Y, int nrows) {
    int tid = threadIdx.x;
    int oy = __builtin_amdgcn_readfirstlane(tid >> 6);   // wave-uniform 0..3
    int tx = tid & 63;
    int l0 = blockIdx.x * 128 + tx * 2;
    int o0 = blockIdx.y * 16 + oy;                        // o's: o0+4i
    int b = blockIdx.z;
    const float* xb = X + (size_t)b * CDIM * LSEQ + l0;
    const float* wb = W + (size_t)(wrow0 + o0) * CDIM;
    float acc[4][2];
    #pragma unroll
    for (int i = 0; i < 4; i++) { acc[i][0] = 0.f; acc[i][1] = 0.f; }
    #pragma unroll 8
    for (int c = 0; c < 256; c++) {
        float2 xv = *(const float2*)(xb + (size_t)c * LSEQ);
        float w0 = wb[c];
        float w1 = wb[4 * CDIM + c];
        float w2 = wb[8 * CDIM + c];
        float w3 = wb[12 * CDIM + c];
        acc[0][0] = fadd(acc[0][0], fmul(w0, xv.x));
        acc[0][1] = fadd(acc[0][1], fmul(w0, xv.y));
        acc[1][0] = fadd(acc[1][0], fmul(w1, xv.x));
        acc[1][1] = fadd(acc[1][1], fmul(w1, xv.y));
        acc[2][0] = fadd(acc[2][0], fmul(w2, xv.x));
        acc[2][1] = fadd(acc[2][1], fmul(w2, xv.y));
        acc[3][0] = fadd(acc[3][0], fmul(w3, xv.x));
        acc[3][1] = fadd(acc[3][1], fmul(w3, xv.y));
    }
    #pragma unroll
    for (int i = 0; i < 4; i++)
        *(float2*)(Y + ((size_t)b * nrows + o0 + 4 * i) * LSEQ + l0) =
            make_float2(acc[i][0], acc[i][1]);
}

// ---------- fold (+ l2norm, + xx out, + cent/cc init) ---------------
__global__ __launch_bounds__(256) void fold_np(const float* __restrict__ src,
        int srcRows, int row0, int donorm, float* __restrict__ dst,
        float* __restrict__ xxout, float* __restrict__ centout,
        float* __restrict__ ccout) {
    int p = blockIdx.x * 256 + threadIdx.x;
    int bh = p >> 12, l = p & 4095;
    int b = bh >> 3, h = bh & 7;
    const float* sp = src + ((size_t)b * srcRows + row0 + h * 32) * LSEQ + l;
    float x[32];
    #pragma unroll
    for (int t = 0; t < 32; t++) x[t] = sp[(size_t)t * LSEQ];
    float4* dp4 = (float4*)(dst + (size_t)p * 32);
    if (donorm) {
        float ss = 0.f;
        #pragma unroll
        for (int t = 0; t < 32; t++) ss = fadd(ss, fmul(x[t], x[t]));
        float n = __fsqrt_rn(ss);
        float den = fmaxf(n, 1e-12f);
        #pragma unroll
        for (int t = 0; t < 32; t++) x[t] = __fdiv_rn(x[t], den);
    }
    #pragma unroll
    for (int t = 0; t < 8; t++)
        dp4[t] = make_float4(x[4*t], x[4*t+1], x[4*t+2], x[4*t+3]);
    if (xxout) {
        float e[32];
        #pragma unroll
        for (int t = 0; t < 32; t++) e[t] = fmul(x[t], x[t]);
        float xv = sum32_np(e);
        xxout[p] = xv;
        if (centout && p < KC) {
            float4* cp4 = (float4*)(centout + (size_t)p * 32);
            #pragma unroll
            for (int t = 0; t < 8; t++)
                cp4[t] = make_float4(x[4*t], x[4*t+1], x[4*t+2], x[4*t+3]);
            ccout[p] = xv;
        }
    }
}

// ---------- argmin+hist: 2 points/thread x half clusters (R11) ------
__global__ __launch_bounds__(256) void assign2_half(const float* __restrict__ pts,
        const float* __restrict__ xx, const float* __restrict__ cent,
        const float* __restrict__ cc, int* __restrict__ asn, int* __restrict__ hist) {
    __shared__ float sc[8192];
    __shared__ float scc[256];
    __shared__ int bins[256];
    int tid = threadIdx.x, c = blockIdx.x;
    {
        const float4* c4 = (const float4*)cent;
        float4* s4 = (float4*)sc;
        for (int i = tid; i < 2048; i += 256) s4[i] = c4[i];
    }
    scc[tid] = cc[tid];
    bins[tid] = 0;
    __syncthreads();
    int pl = tid >> 1, half = tid & 1;
    int p0 = c * 256 + pl * 2, p1 = p0 + 1;
    float x0[32], x1[32];
    {
        const float4* pp0 = (const float4*)(pts + (size_t)p0 * 32);
        const float4* pp1 = (const float4*)(pts + (size_t)p1 * 32);
        #pragma unroll
        for (int t = 0; t < 8; t++) {
            float4 f = pp0[t];
            x0[4*t] = f.x; x0[4*t+1] = f.y; x0[4*t+2] = f.z; x0[4*t+3] = f.w;
            float4 g = pp1[t];
            x1[4*t] = g.x; x1[4*t+1] = g.y; x1[4*t+2] = g.z; x1[4*t+3] = g.w;
        }
    }
    float xp0 = xx[p0], xp1 = xx[p1];
    float bd0 = 3.4e38f, bd1 = 3.4e38f;
    int bj0 = 0, bj1 = 0;
    int jbase = half * 128;
    for (int jj = 0; jj < 128; jj++) {
        int j = jbase + jj;
        const float4* cj = (const float4*)(sc + j * 32);
        float g0 = 0.f, g1 = 0.f;
        #pragma unroll
        for (int t = 0; t < 8; t++) {
            float4 w = cj[t];
            g0 = __builtin_fmaf(x0[4*t],   w.x, g0);
            g0 = __builtin_fmaf(x0[4*t+1], w.y, g0);
            g0 = __builtin_fmaf(x0[4*t+2], w.z, g0);
            g0 = __builtin_fmaf(x0[4*t+3], w.w, g0);
            g1 = __builtin_fmaf(x1[4*t],   w.x, g1);
            g1 = __builtin_fmaf(x1[4*t+1], w.y, g1);
            g1 = __builtin_fmaf(x1[4*t+2], w.z, g1);
            g1 = __builtin_fmaf(x1[4*t+3], w.w, g1);
        }
        float sj = scc[j];
        float d0 = fadd(fsub(xp0, fmul(2.f, g0)), sj);
        float d1 = fadd(fsub(xp1, fmul(2.f, g1)), sj);
        if (d0 < bd0) { bd0 = d0; bj0 = j; }
        if (d1 < bd1) { bd1 = d1; bj1 = j; }
    }
    float obd0 = __shfl_xor(bd0, 1); int obj0 = __shfl_xor(bj0, 1);
    float obd1 = __shfl_xor(bd1, 1); int obj1 = __shfl_xor(bj1, 1);
    if (half == 0) {
        if (obd0 < bd0) { bd0 = obd0; bj0 = obj0; }
        if (obd1 < bd1) { bd1 = obd1; bj1 = obj1; }
        asn[p0] = bj0; asn[p1] = bj1;
        atomicAdd(&bins[bj0], 1);
        atomicAdd(&bins[bj1], 1);
    }
    __syncthreads();
    hist[c * 256 + tid] = bins[tid];
}

// ---------- per-cluster prefix over 256 chunks ----------------------
__global__ __launch_bounds__(256) void scan_chunks(const int* __restrict__ hist,
        int* __restrict__ chunkbase, int* __restrict__ totals) {
    __shared__ int a[256];
    int j = blockIdx.x, c = threadIdx.x;
    a[c] = hist[(size_t)c * 256 + j];
    __syncthreads();
    for (int d = 1; d < 256; d <<= 1) {
        int v = a[c];
        int u = (c >= d) ? a[c - d] : 0;
        __syncthreads();
        a[c] = v + u;
        __syncthreads();
    }
    chunkbase[(size_t)c * 256 + j] = (c == 0) ? 0 : a[c - 1];
    if (c == 255) totals[j] = a[255];
}

// ---------- scatter: parallel cbase scan + stable rank --------------
__global__ __launch_bounds__(256) void scatter_v5(const int* __restrict__ asn,
        const int* __restrict__ chunkbase, const int* __restrict__ totals,
        int* __restrict__ perm) {
    __shared__ int cb[256];
    __shared__ int al[256];
    int c = blockIdx.x, tid = threadIdx.x;
    cb[tid] = totals[tid];
    al[tid] = asn[c * 256 + tid];
    __syncthreads();
    for (int d = 1; d < 256; d <<= 1) {
        int v = cb[tid];
        int u = (tid >= d) ? cb[tid - d] : 0;
        __syncthreads();
        cb[tid] = v + u;
        __syncthreads();
    }
    int my = al[tid];
    int base = (my == 0) ? 0 : cb[my - 1];
    int r = 0;
    for (int i = 0; i < tid; i++) r += (al[i] == my) ? 1 : 0;
    perm[base + chunkbase[(size_t)c * 256 + my] + r] = c * 256 + tid;
}

// ---------- ordered sum + update + cc (parallel cbase scan) ---------
#define STILE 128
__global__ __launch_bounds__(256) void sumk_v4(const float* __restrict__ pts,
        const int* __restrict__ perm, const int* __restrict__ totals,
        float* __restrict__ cent, float* __restrict__ cc) {
    __shared__ int cb[256];
    __shared__ float buf[2][STILE][32];
    int j = blockIdx.x, tid = threadIdx.x;
    cb[tid] = totals[tid];
    __syncthreads();
    for (int d = 1; d < 256; d <<= 1) {
        int v = cb[tid];
        int u = (tid >= d) ? cb[tid - d] : 0;
        __syncthreads();
        cb[tid] = v + u;
        __syncthreads();
    }
    int base = (j == 0) ? 0 : cb[j - 1];
    int n = totals[j];
    int t = tid & 31, r0 = tid >> 5;
    for (int r = r0; r < STILE; r += 8) {
        if (r < n) buf[0][r][t] = pts[(size_t)perm[base + r] * 32 + t];
    }
    __syncthreads();
    float s = 0.f;
    int b = 0;
    for (int i0 = 0; i0 < n; i0 += STILE, b ^= 1) {
        int nx = i0 + STILE;
        if (nx < n) {
            for (int r = r0; r < STILE; r += 8) {
                int g = nx + r;
                if (g < n) buf[b ^ 1][r][t] = pts[(size_t)perm[base + g] * 32 + t];
            }
        }
        if (tid < 32) {
            int m = n - i0; if (m > STILE) m = STILE;
            int i = 0;
            for (; i + 4 <= m; i += 4) {
                s = fadd(s, buf[b][i][tid]);
                s = fadd(s, buf[b][i + 1][tid]);
                s = fadd(s, buf[b][i + 2][tid]);
                s = fadd(s, buf[b][i + 3][tid]);
            }
            for (; i < m; i++) s = fadd(s, buf[b][i][tid]);
        }
        __syncthreads();
    }
    if (tid < 32) {
        float v;
        if (n > 0) {
            v = __fdiv_rn(s, (float)n);
            cent[(size_t)j * 32 + tid] = v;
        } else {
            v = cent[(size_t)j * 32 + tid];
        }
        float e = fmul(v, v);
        e = fadd(e, __shfl_xor(e, 16));
        e = fadd(e, __shfl_xor(e, 8));
        e = fadd(e, __shfl_xor(e, 4));
        e = fadd(e, __shfl_xor(e, 2));
        e = fadd(e, __shfl_xor(e, 1));
        if (tid == 0) cc[j] = e;
    }
}

// ---------- key assign + L1: 2 pts/thread x half clusters (R11) -----
__global__ __launch_bounds__(256) void kdist2_half(const float* __restrict__ pts,
        const float* __restrict__ cent, const float* __restrict__ cc,
        float* __restrict__ kd) {
    __shared__ float sc[8192];
    __shared__ float scc[256];
    int tid = threadIdx.x, c = blockIdx.x;
    {
        const float4* c4 = (const float4*)cent;
        float4* s4 = (float4*)sc;
        for (int i = tid; i < 2048; i += 256) s4[i] = c4[i];
    }
    scc[tid] = cc[tid];
    __syncthreads();
    int pl = tid >> 1, half = tid & 1;
    int p0 = c * 256 + pl * 2, p1 = p0 + 1;
    float x0[32], x1[32];
    {
        const float4* pp0 = (const float4*)(pts + (size_t)p0 * 32);
        const float4* pp1 = (const float4*)(pts + (size_t)p1 * 32);
        #pragma unroll
        for (int t = 0; t < 8; t++) {
            float4 f = pp0[t];
            x0[4*t] = f.x; x0[4*t+1] = f.y; x0[4*t+2] = f.z; x0[4*t+3] = f.w;
            float4 g = pp1[t];
            x1[4*t] = g.x; x1[4*t+1] = g.y; x1[4*t+2] = g.z; x1[4*t+3] = g.w;
        }
    }
    float xp0, xp1;
    {
        float e[32];
        #pragma unroll
        for (int t = 0; t < 32; t++) e[t] = fmul(x0[t], x0[t]);
        xp0 = sum32_np(e);
        #pragma unroll
        for (int t = 0; t < 32; t++) e[t] = fmul(x1[t], x1[t]);
        xp1 = sum32_np(e);
    }
    float bd0 = 3.4e38f, bd1 = 3.4e38f;
    int bj0 = 0, bj1 = 0;
    int jbase = half * 128;
    for (int jj = 0; jj < 128; jj++) {
        int j = jbase + jj;
        const float4* cj = (const float4*)(sc + j * 32);
        float g0 = 0.f, g1 = 0.f;
        #pragma unroll
        for (int t = 0; t < 8; t++) {
            float4 w = cj[t];
            g0 = __builtin_fmaf(x0[4*t],   w.x, g0);
            g0 = __builtin_fmaf(x0[4*t+1], w.y, g0);
            g0 = __builtin_fmaf(x0[4*t+2], w.z, g0);
            g0 = __builtin_fmaf(x0[4*t+3], w.w, g0);
            g1 = __builtin_fmaf(x1[4*t],   w.x, g1);
            g1 = __builtin_fmaf(x1[4*t+1], w.y, g1);
            g1 = __builtin_fmaf(x1[4*t+2], w.z, g1);
            g1 = __builtin_fmaf(x1[4*t+3], w.w, g1);
        }
        float sj = scc[j];
        float d0 = fadd(fsub(xp0, fmul(2.f, g0)), sj);
        float d1 = fadd(fsub(xp1, fmul(2.f, g1)), sj);
        if (d0 < bd0) { bd0 = d0; bj0 = j; }
        if (d1 < bd1) { bd1 = d1; bj1 = j; }
    }
    float obd0 = __shfl_xor(bd0, 1); int obj0 = __shfl_xor(bj0, 1);
    float obd1 = __shfl_xor(bd1, 1); int obj1 = __shfl_xor(bj1, 1);
    if (half == 0) {
        if (obd0 < bd0) { bd0 = obd0; bj0 = obj0; }
        if (obd1 < bd1) { bd1 = obd1; bj1 = obj1; }
        {
            const float* cb = &sc[bj0 * 32];
            float e[32];
            #pragma unroll
            for (int t = 0; t < 32; t++) e[t] = fabsf(fsub(cb[t], x0[t]));
            kd[p0] = sum32_np(e);
        }
        {
            const float* cb = &sc[bj1 * 32];
            float e[32];
            #pragma unroll
            for (int t = 0; t < 32; t++) e[t] = fabsf(fsub(cb[t], x1[t]));
            kd[p1] = sum32_np(e);
        }
    }
}

// ---------- top-256 via radix select (exact stable set) + gather ----
__global__ __launch_bounds__(256) void topk_v2(const float* __restrict__ kd,
        const float* __restrict__ k_t, const float* __restrict__ v_t,
        float* __restrict__ ksel, float* __restrict__ vsel) {
    __shared__ unsigned uv[4096];
    __shared__ int hist[256];
    __shared__ unsigned s_prefix;
    __shared__ int s_rem;
    __shared__ int sc1[256];
    __shared__ int out_src[256];
    int bh = blockIdx.x, tid = threadIdx.x;
    for (int i = tid; i < 4096; i += 256) uv[i] = __float_as_uint(kd[bh * 4096 + i]);
    if (tid == 0) { s_prefix = 0u; s_rem = 256; }
    out_src[tid] = 0;
    __syncthreads();
    for (int pass = 0; pass < 4; pass++) {
        int shift = 24 - 8 * pass;
        hist[tid] = 0;
        __syncthreads();
        unsigned pfx = s_prefix;
        for (int i = tid; i < 4096; i += 256) {
            unsigned u = uv[i];
            bool in = (pass == 0) || ((u >> (shift + 8)) == (pfx >> (shift + 8)));
            if (in) atomicAdd(&hist[(u >> shift) & 255], 1);
        }
        __syncthreads();
        if (tid == 0) {
            int rem = s_rem, cum = 0, b;
            for (b = 255; b >= 0; b--) {
                if (cum + hist[b] >= rem) break;
                cum += hist[b];
            }
            s_rem = rem - cum;
            s_prefix = s_prefix | ((unsigned)b << shift);
        }
        __syncthreads();
    }
    unsigned T = s_prefix;
    int r = s_rem;
    int base_i = tid * 16;
    int ec = 0;
    for (int q = 0; q < 16; q++) ec += (uv[base_i + q] == T) ? 1 : 0;
    sc1[tid] = ec;
    __syncthreads();
    for (int d = 1; d < 256; d <<= 1) {
        int t0 = sc1[tid];
        int u0 = (tid >= d) ? sc1[tid - d] : 0;
        __syncthreads();
        sc1[tid] = t0 + u0;
        __syncthreads();
    }
    int erank = (tid == 0) ? 0 : sc1[tid - 1];
    __syncthreads();
    bool incl[16];
    int ic = 0;
    for (int q = 0; q < 16; q++) {
        unsigned u = uv[base_i + q];
        bool inc;
        if (u > T) inc = true;
        else if (u == T) { inc = (erank < r); erank++; }
        else inc = false;
        incl[q] = inc;
        ic += inc ? 1 : 0;
    }
    sc1[tid] = ic;
    __syncthreads();
    for (int d = 1; d < 256; d <<= 1) {
        int t0 = sc1[tid];
        int u0 = (tid >= d) ? sc1[tid - d] : 0;
        __syncthreads();
        sc1[tid] = t0 + u0;
        __syncthreads();
    }
    int pos = (tid == 0) ? 0 : sc1[tid - 1];
    for (int q = 0; q < 16; q++) {
        if (incl[q]) out_src[pos++] = base_i + q;
    }
    __syncthreads();
    for (int e = tid; e < 256 * 32; e += 256) {
        int jj = e >> 5, t = e & 31;
        int src = out_src[jj];
        ksel[(size_t)bh * 8192 + e] = k_t[((size_t)bh * 4096 + src) * 32 + t];
        vsel[(size_t)bh * 8192 + e] = v_t[((size_t)bh * 4096 + src) * 32 + t];
    }
}

// ---------- attention v3b: 2 q/thread, padded halves (R13: 63 µs) ---
#define HPAD 4112
__global__ __launch_bounds__(256) void attn_v3b(const float* __restrict__ q_t,
        const float* __restrict__ ksel, const float* __restrict__ vsel,
        float* __restrict__ out) {
    __shared__ float sk[2 * HPAD];
    __shared__ float sv[2 * HPAD];
    int bh = blockIdx.y, tid = threadIdx.x;
    {
        const float4* gk = (const float4*)(ksel + (size_t)bh * 8192);
        const float4* gv = (const float4*)(vsel + (size_t)bh * 8192);
        for (int i = tid; i < 2048; i += 256) {
            int h = i >> 10, idx = i & 1023;
            ((float4*)(sk + h * HPAD))[idx] = gk[i];
            ((float4*)(sv + h * HPAD))[idx] = gv[i];
        }
    }
    __syncthreads();
    int ql = tid >> 1, slice = tid & 1;
    int p0 = bh * 4096 + blockIdx.x * 256 + ql * 2;
    float q0[32], q1[32];
    {
        const float4* qp0 = (const float4*)(q_t + (size_t)p0 * 32);
        const float4* qp1 = (const float4*)(q_t + (size_t)(p0 + 1) * 32);
        #pragma unroll
        for (int t = 0; t < 8; t++) {
            float4 f = qp0[t];
            q0[4*t] = f.x; q0[4*t+1] = f.y; q0[4*t+2] = f.z; q0[4*t+3] = f.w;
            float4 g = qp1[t];
            q1[4*t] = g.x; q1[4*t+1] = g.y; q1[4*t+2] = g.z; q1[4*t+3] = g.w;
        }
    }
    float o0[32], o1[32];
    #pragma unroll
    for (int t = 0; t < 32; t++) { o0[t] = 0.f; o1[t] = 0.f; }
    float ls0 = 0.f, ls1 = 0.f;
    const float4* k4 = (const float4*)(sk + slice * HPAD);
    const float4* v4 = (const float4*)(sv + slice * HPAD);
    for (int j = 0; j < 128; j++) {
        float a0 = 0.f, b0 = 0.f, c0 = 0.f, d0 = 0.f;
        float a1 = 0.f, b1 = 0.f, c1 = 0.f, d1 = 0.f;
        #pragma unroll
        for (int t = 0; t < 8; t++) {
            float4 kf = k4[j * 8 + t];
            a0 += q0[4*t]   * kf.x; b0 += q0[4*t+1] * kf.y;
            c0 += q0[4*t+2] * kf.z; d0 += q0[4*t+3] * kf.w;
            a1 += q1[4*t]   * kf.x; b1 += q1[4*t+1] * kf.y;
            c1 += q1[4*t+2] * kf.z; d1 += q1[4*t+3] * kf.w;
        }
        float s0 = (a0 + b0) + (c0 + d0);
        float s1 = (a1 + b1) + (c1 + d1);
        float w0 = __expf(s0 - 1.0f);
        float w1 = __expf(s1 - 1.0f);
        ls0 += w0; ls1 += w1;
        #pragma unroll
        for (int t = 0; t < 8; t++) {
            float4 vf = v4[j * 8 + t];
            o0[4*t]   += w0 * vf.x; o0[4*t+1] += w0 * vf.y;
            o0[4*t+2] += w0 * vf.z; o0[4*t+3] += w0 * vf.w;
            o1[4*t]   += w1 * vf.x; o1[4*t+1] += w1 * vf.y;
            o1[4*t+2] += w1 * vf.z; o1[4*t+3] += w1 * vf.w;
        }
    }
    #pragma unroll
    for (int t = 0; t < 32; t++) {
        o0[t] += __shfl_xor(o0[t], 1);
        o1[t] += __shfl_xor(o1[t], 1);
    }
    ls0 += __shfl_xor(ls0, 1);
    ls1 += __shfl_xor(ls1, 1);
    if (slice == 0) {
        float inv0 = 1.f / ls0, inv1 = 1.f / ls1;
        float4* op0 = (float4*)(out + (size_t)p0 * 32);
        float4* op1 = (float4*)(out + (size_t)(p0 + 1) * 32);
        #pragma unroll
        for (int t = 0; t < 8; t++) {
            op0[t] = make_float4(o0[4*t]*inv0, o0[4*t+1]*inv0, o0[4*t+2]*inv0, o0[4*t+3]*inv0);
            op1[t] = make_float4(o1[4*t]*inv1, o1[4*t+1]*inv1, o1[4*t+2]*inv1, o1[4*t+3]*inv1);
        }
    }
}

// ---------- unfold (bh,L,32) -> (b,256,L) ---------------------------
__global__ __launch_bounds__(256) void unfold_kernel(const float* __restrict__ att,
        float* __restrict__ Fo) {
    __shared__ float tbuf[32][65];
    int bh = blockIdx.y, l0 = blockIdx.x * 64;
    int b = bh >> 3, h = bh & 7;
    int tid = threadIdx.x;
    #pragma unroll
    for (int r = 0; r < 8; r++) {
        int e = r * 256 + tid;
        int l = e >> 5, d = e & 31;
        tbuf[d][l] = att[((size_t)bh * 4096 + l0 + l) * 32 + d];
    }
    __syncthreads();
    #pragma unroll
    for (int r = 0; r < 8; r++) {
        int e = r * 256 + tid;
        int d = e >> 6, l = e & 63;
        Fo[((size_t)b * 256 + h * 32 + d) * LSEQ + l0 + l] = tbuf[d][l];
    }
}

// ---------- final LN + scale + residual (numpy orders) --------------
__global__ __launch_bounds__(64) void lnres_np(const float* __restrict__ x,
        const float* __restrict__ g, const float* __restrict__ bt,
        const float* __restrict__ gs, const float* __restrict__ qsrc,
        float* __restrict__ y) {
    int gid = blockIdx.x * 64 + threadIdx.x;
    int b = gid >> 12, l = gid & 4095;
    const float* xb = x + (size_t)b * CDIM * LSEQ + l;
    float s = 0.f;
    #pragma unroll 8
    for (int c = 0; c < 256; c++) s = fadd(s, xb[(size_t)c * LSEQ]);
    float mean = __fdiv_rn(s, 256.f);
    float s2 = 0.f;
    #pragma unroll 8
    for (int c = 0; c < 256; c++) {
        float d = fsub(xb[(size_t)c * LSEQ], mean);
        s2 = fadd(s2, fmul(d, d));
    }
    float var = __fdiv_rn(s2, 256.f);
    float den = fadd(__fsqrt_rn(var), 1e-6f);
    float scale = gs[0];
    const float* qb = qsrc + (size_t)b * CDIM * LSEQ + l;
    float* yb = y + (size_t)b * CDIM * LSEQ + l;
    #pragma unroll 4
    for (int c = 0; c < 256; c++) {
        float d = fsub(xb[(size_t)c * LSEQ], mean);
        float r = fadd(__fdiv_rn(fmul(g[c], d), den), bt[c]);
        yb[(size_t)c * LSEQ] = fadd(fmul(scale, r), qb[(size_t)c * LSEQ]);
    }
}

// ==================================================================
extern "C" void kernel_launch(void* const* d_in, const int* in_sizes, int n_in,
                              void* d_out, int out_size, void* d_ws, size_t ws_size,
                              hipStream_t stream) {
    const float* qsrc   = (const float*)d_in[0];
    const float* ctx    = (const float*)d_in[1];
    const float* w_q    = (const float*)d_in[2];
    const float* w_kv   = (const float*)d_in[3];
    const float* w_out  = (const float*)d_in[4];
    const float* g_ctx  = (const float*)d_in[5];
    const float* b_ctx  = (const float*)d_in[6];
    const float* g_q    = (const float*)d_in[7];
    const float* b_q    = (const float*)d_in[8];
    const float* g_out  = (const float*)d_in[9];
    const float* b_out  = (const float*)d_in[10];
    const float* gs     = (const float*)d_in[11];

    char* base = (char*)d_ws;
    const size_t MB = 1024 * 1024;
    float* yln   = (float*)base;               // [0,8) LN out; later att
    float* att   = (float*)base;
    float* kvbuf = (float*)(base + 8 * MB);    // [8,24) kv conv; later y32 [8,16)
    float* y32   = (float*)(base + 8 * MB);
    float* qbuf  = (float*)(base + 24 * MB);   // [24,32) q conv; later Fo
    float* Fo    = (float*)(base + 24 * MB);
    float* q_t   = (float*)(base + 32 * MB);   // [32,40)
    float* k_t   = (float*)(base + 40 * MB);   // [40,48)
    float* v_t   = (float*)(base + 48 * MB);   // [48,56)
    char* SM = base + 56 * MB;
    float* xx_q      = (float*)(SM + 0);            // 256 KB
    float* cent      = (float*)(SM + 512 * 1024);   // 32 KB
    float* cc        = (float*)(SM + 576 * 1024);   // 1 KB
    int*   totals    = (int*)  (SM + 640 * 1024);   // 1 KB
    int*   asn       = (int*)  (SM + 704 * 1024);   // 256 KB
    int*   hist      = (int*)  (SM + 960 * 1024);   // 256 KB
    int*   chunkbase = (int*)  (SM + 1472 * 1024);  // 256 KB
    int*   perm      = (int*)  (SM + 1984 * 1024);  // 256 KB
    float* kd        = (float*)(SM + 2240 * 1024);  // 256 KB
    float* ksel      = (float*)(SM + 2496 * 1024);  // 512 KB
    float* vsel      = (float*)(SM + 3008 * 1024);  // 512 KB

    // context branch
    ln_np<<<128, 64, 0, stream>>>(ctx, g_ctx, b_ctx, yln);
    conv_sw<<<dim3(32, 32, 2), 256, 0, stream>>>(w_kv, 0, yln, kvbuf, 512);
    fold_np<<<256, 256, 0, stream>>>(kvbuf, 512, 0, 1, k_t, nullptr, nullptr, nullptr);
    fold_np<<<256, 256, 0, stream>>>(kvbuf, 512, 256, 0, v_t, nullptr, nullptr, nullptr);
    // query branch (fold also emits xx and initial cent/cc)
    ln_np<<<128, 64, 0, stream>>>(qsrc, g_q, b_q, yln);
    conv_sw<<<dim3(32, 16, 2), 256, 0, stream>>>(w_q, 0, yln, qbuf, 256);
    fold_np<<<256, 256, 0, stream>>>(qbuf, 256, 0, 1, q_t, xx_q, cent, cc);

    for (int it = 0; it < 10; it++) {
        assign2_half<<<256, 256, 0, stream>>>(q_t, xx_q, cent, cc, asn, hist);
        scan_chunks<<<256, 256, 0, stream>>>(hist, chunkbase, totals);
        scatter_v5<<<256, 256, 0, stream>>>(asn, chunkbase, totals, perm);
        sumk_v4<<<256, 256, 0, stream>>>(q_t, perm, totals, cent, cc);
    }

    kdist2_half<<<256, 256, 0, stream>>>(k_t, cent, cc, kd);
    topk_v2<<<16, 256, 0, stream>>>(kd, k_t, v_t, ksel, vsel);
    attn_v3b<<<dim3(16, 16), 256, 0, stream>>>(q_t, ksel, vsel, att);
    unfold_kernel<<<dim3(64, 16), 256, 0, stream>>>(att, Fo);
    conv_sw<<<dim3(32, 16, 2), 256, 0, stream>>>(w_out, 0, Fo, y32, 256);
    lnres_np<<<128, 64, 0, stream>>>(y32, g_out, b_out, gs, qsrc, (float*)d_out);
}

// Round 16
// 977.947 us; speedup vs baseline: 1.1646x; 1.0655x over previous
//
#include <hip/hip_runtime.h>
#include <math.h>

#define CDIM 256
#define LSEQ 4096
#define NBH 16
#define NPTS 65536
#define KC 256

__device__ __forceinline__ float fadd(float a, float b){ return __fadd_rn(a,b); }
__device__ __forceinline__ float fmul(float a, float b){ return __fmul_rn(a,b); }
__device__ __forceinline__ float fsub(float a, float b){ return __fsub_rn(a,b); }

// numpy contiguous n=32 float32 sum, AVX-512 npyv path (verified R5)
__device__ __forceinline__ float sum32_np(const float* e){
    float l[16];
    #pragma unroll
    for (int j = 0; j < 16; j++) l[j] = fadd(e[j], e[j + 16]);
    float t3[8];
    #pragma unroll
    for (int j = 0; j < 8; j++) t3[j] = fadd(l[j], l[j + 8]);
    float t6[4];
    #pragma unroll
    for (int j = 0; j < 4; j++) t6[j] = fadd(t3[j], t3[j + 4]);
    return fadd(fadd(t6[0], t6[2]), fadd(t6[1], t6[3]));
}

// ---------- LayerNorm, numpy semantics (sequential over c) ----------
__global__ __launch_bounds__(64) void ln_np(const float* __restrict__ x,
        const float* __restrict__ g, const float* __restrict__ bt,
        float* __restrict__ y) {
    int gid = blockIdx.x * 64 + threadIdx.x;
    int b = gid >> 12, l = gid & 4095;
    const float* xb = x + (size_t)b * CDIM * LSEQ + l;
    float s = 0.f;
    #pragma unroll 8
    for (int c = 0; c < 256; c++) s = fadd(s, xb[(size_t)c * LSEQ]);
    float mean = __fdiv_rn(s, 256.f);
    float s2 = 0.f;
    #pragma unroll 8
    for (int c = 0; c < 256; c++) {
        float d = fsub(xb[(size_t)c * LSEQ], mean);
        s2 = fadd(s2, fmul(d, d));
    }
    float var = __fdiv_rn(s2, 256.f);
    float den = fadd(__fsqrt_rn(var), 1e-6f);
    float* yb = y + (size_t)b * CDIM * LSEQ + l;
    #pragma unroll 4
    for (int c = 0; c < 256; c++) {
        float d = fsub(xb[(size_t)c * LSEQ], mean);
        yb[(size_t)c * LSEQ] = fadd(__fdiv_rn(fmul(g[c], d), den), bt[c]);
    }
}

// ---------- conv1x1, SOP semantics, NL l-positions per thread (R11) -
template<int COT, int NL>
__global__ __launch_bounds__(256) void conv_nl(const float* __restrict__ W, int wrow0,
        const float* __restrict__ X, float* __restrict__ Y, int nrows) {
    __shared__ float ws[COT * 256];
    int tid = threadIdx.x;
    int l0 = blockIdx.x * (256 * NL) + tid;
    int o0 = blockIdx.y * COT;
    int b = blockIdx.z;
    {
        const float4* wb4 = (const float4*)(W + (size_t)(wrow0 + o0) * CDIM);
        float4* ws4 = (float4*)ws;
        for (int i = tid; i < COT * 64; i += 256) ws4[i] = wb4[i];
    }
    __syncthreads();
    const float* xb = X + (size_t)b * CDIM * LSEQ;
    float acc[COT][NL];
    #pragma unroll
    for (int oo = 0; oo < COT; oo++)
        #pragma unroll
        for (int i = 0; i < NL; i++) acc[oo][i] = 0.f;
    const float4* ws4 = (const float4*)ws;
    for (int c = 0; c < 256; c += 4) {
        float xv[NL][4];
        #pragma unroll
        for (int i = 0; i < NL; i++) {
            #pragma unroll
            for (int k = 0; k < 4; k++)
                xv[i][k] = xb[(size_t)(c + k) * LSEQ + l0 + i * 256];
        }
        #pragma unroll
        for (int oo = 0; oo < COT; oo++) {
            float4 w = ws4[(oo * 256 + c) >> 2];
            #pragma unroll
            for (int i = 0; i < NL; i++) {
                acc[oo][i] = fadd(acc[oo][i], fmul(w.x, xv[i][0]));
                acc[oo][i] = fadd(acc[oo][i], fmul(w.y, xv[i][1]));
                acc[oo][i] = fadd(acc[oo][i], fmul(w.z, xv[i][2]));
                acc[oo][i] = fadd(acc[oo][i], fmul(w.w, xv[i][3]));
            }
        }
    }
    #pragma unroll
    for (int oo = 0; oo < COT; oo++)
        #pragma unroll
        for (int i = 0; i < NL; i++)
            Y[((size_t)b * nrows + o0 + oo) * LSEQ + l0 + i * 256] = acc[oo][i];
}

// ---------- fold (+ l2norm, + xx out, + cent/cc init) ---------------
__global__ __launch_bounds__(256) void fold_np(const float* __restrict__ src,
        int srcRows, int row0, int donorm, float* __restrict__ dst,
        float* __restrict__ xxout, float* __restrict__ centout,
        float* __restrict__ ccout) {
    int p = blockIdx.x * 256 + threadIdx.x;
    int bh = p >> 12, l = p & 4095;
    int b = bh >> 3, h = bh & 7;
    const float* sp = src + ((size_t)b * srcRows + row0 + h * 32) * LSEQ + l;
    float x[32];
    #pragma unroll
    for (int t = 0; t < 32; t++) x[t] = sp[(size_t)t * LSEQ];
    float4* dp4 = (float4*)(dst + (size_t)p * 32);
    if (donorm) {
        float ss = 0.f;
        #pragma unroll
        for (int t = 0; t < 32; t++) ss = fadd(ss, fmul(x[t], x[t]));
        float n = __fsqrt_rn(ss);
        float den = fmaxf(n, 1e-12f);
        #pragma unroll
        for (int t = 0; t < 32; t++) x[t] = __fdiv_rn(x[t], den);
    }
    #pragma unroll
    for (int t = 0; t < 8; t++)
        dp4[t] = make_float4(x[4*t], x[4*t+1], x[4*t+2], x[4*t+3]);
    if (xxout) {
        float e[32];
        #pragma unroll
        for (int t = 0; t < 32; t++) e[t] = fmul(x[t], x[t]);
        float xv = sum32_np(e);
        xxout[p] = xv;
        if (centout && p < KC) {
            float4* cp4 = (float4*)(centout + (size_t)p * 32);
            #pragma unroll
            for (int t = 0; t < 8; t++)
                cp4[t] = make_float4(x[4*t], x[4*t+1], x[4*t+2], x[4*t+3]);
            ccout[p] = xv;
        }
    }
}

// ---------- argmin+hist: 4 pts/thread x quarter clusters ------------
// 256 blocks x 256 thr; thread (pg,quarter) handles points pg*4+0..3,
// clusters quarter*64..+63. Merge xor1,xor2 strict < (verified R12/13)
// == sequential argmin 0..255 bit-exact.
__global__ __launch_bounds__(256) void assign4p(const float* __restrict__ pts,
        const float* __restrict__ xx, const float* __restrict__ cent,
        const float* __restrict__ cc, int* __restrict__ asn, int* __restrict__ hist) {
    __shared__ float sc[8192];
    __shared__ float scc[256];
    __shared__ int bins[256];
    int tid = threadIdx.x, c = blockIdx.x;
    {
        const float4* c4 = (const float4*)cent;
        float4* s4 = (float4*)sc;
        for (int i = tid; i < 2048; i += 256) s4[i] = c4[i];
    }
    scc[tid] = cc[tid];
    bins[tid] = 0;
    __syncthreads();
    int pg = tid >> 2, quarter = tid & 3;
    int pb = c * 256 + pg * 4;
    float x[4][32];
    float xp[4];
    #pragma unroll
    for (int i = 0; i < 4; i++) {
        const float4* pp = (const float4*)(pts + (size_t)(pb + i) * 32);
        #pragma unroll
        for (int t = 0; t < 8; t++) {
            float4 f = pp[t];
            x[i][4*t] = f.x; x[i][4*t+1] = f.y; x[i][4*t+2] = f.z; x[i][4*t+3] = f.w;
        }
        xp[i] = xx[pb + i];
    }
    float bd[4] = {3.4e38f, 3.4e38f, 3.4e38f, 3.4e38f};
    int bj[4] = {0, 0, 0, 0};
    int jbase = quarter * 64;
    for (int jj = 0; jj < 64; jj++) {
        int j = jbase + jj;
        const float4* cj = (const float4*)(sc + j * 32);
        float w[32];
        #pragma unroll
        for (int t = 0; t < 8; t++) {
            float4 f = cj[t];
            w[4*t] = f.x; w[4*t+1] = f.y; w[4*t+2] = f.z; w[4*t+3] = f.w;
        }
        float sj = scc[j];
        #pragma unroll
        for (int i = 0; i < 4; i++) {
            float g = 0.f;
            #pragma unroll
            for (int t = 0; t < 32; t++) g = __builtin_fmaf(x[i][t], w[t], g);
            float d = fadd(fsub(xp[i], fmul(2.f, g)), sj);
            if (d < bd[i]) { bd[i] = d; bj[i] = j; }
        }
    }
    // merge quarters: xor1 then xor2, strict <
    #pragma unroll
    for (int i = 0; i < 4; i++) {
        float ob; int oj;
        ob = __shfl_xor(bd[i], 1); oj = __shfl_xor(bj[i], 1);
        if (ob < bd[i]) { bd[i] = ob; bj[i] = oj; }
        ob = __shfl_xor(bd[i], 2); oj = __shfl_xor(bj[i], 2);
        if (ob < bd[i]) { bd[i] = ob; bj[i] = oj; }
    }
    if (quarter == 0) {
        #pragma unroll
        for (int i = 0; i < 4; i++) {
            asn[pb + i] = bj[i];
            atomicAdd(&bins[bj[i]], 1);
        }
    }
    __syncthreads();
    hist[c * 256 + tid] = bins[tid];
}

// ---------- per-cluster prefix over 256 chunks ----------------------
__global__ __launch_bounds__(256) void scan_chunks(const int* __restrict__ hist,
        int* __restrict__ chunkbase, int* __restrict__ totals) {
    __shared__ int a[256];
    int j = blockIdx.x, c = threadIdx.x;
    a[c] = hist[(size_t)c * 256 + j];
    __syncthreads();
    for (int d = 1; d < 256; d <<= 1) {
        int v = a[c];
        int u = (c >= d) ? a[c - d] : 0;
        __syncthreads();
        a[c] = v + u;
        __syncthreads();
    }
    chunkbase[(size_t)c * 256 + j] = (c == 0) ? 0 : a[c - 1];
    if (c == 255) totals[j] = a[255];
}

// ---------- scatter: parallel cbase scan + stable rank --------------
__global__ __launch_bounds__(256) void scatter_v5(const int* __restrict__ asn,
        const int* __restrict__ chunkbase, const int* __restrict__ totals,
        int* __restrict__ perm) {
    __shared__ int cb[256];
    __shared__ int al[256];
    int c = blockIdx.x, tid = threadIdx.x;
    cb[tid] = totals[tid];
    al[tid] = asn[c * 256 + tid];
    __syncthreads();
    for (int d = 1; d < 256; d <<= 1) {
        int v = cb[tid];
        int u = (tid >= d) ? cb[tid - d] : 0;
        __syncthreads();
        cb[tid] = v + u;
        __syncthreads();
    }
    int my = al[tid];
    int base = (my == 0) ? 0 : cb[my - 1];
    int r = 0;
    for (int i = 0; i < tid; i++) r += (al[i] == my) ? 1 : 0;
    perm[base + chunkbase[(size_t)c * 256 + my] + r] = c * 256 + tid;
}

// ---------- ordered sum + update + cc (parallel cbase scan) ---------
#define STILE 128
__global__ __launch_bounds__(256) void sumk_v4(const float* __restrict__ pts,
        const int* __restrict__ perm, const int* __restrict__ totals,
        float* __restrict__ cent, float* __restrict__ cc) {
    __shared__ int cb[256];
    __shared__ float buf[2][STILE][32];
    int j = blockIdx.x, tid = threadIdx.x;
    cb[tid] = totals[tid];
    __syncthreads();
    for (int d = 1; d < 256; d <<= 1) {
        int v = cb[tid];
        int u = (tid >= d) ? cb[tid - d] : 0;
        __syncthreads();
        cb[tid] = v + u;
        __syncthreads();
    }
    int base = (j == 0) ? 0 : cb[j - 1];
    int n = totals[j];
    int t = tid & 31, r0 = tid >> 5;
    for (int r = r0; r < STILE; r += 8) {
        if (r < n) buf[0][r][t] = pts[(size_t)perm[base + r] * 32 + t];
    }
    __syncthreads();
    float s = 0.f;
    int b = 0;
    for (int i0 = 0; i0 < n; i0 += STILE, b ^= 1) {
        int nx = i0 + STILE;
        if (nx < n) {
            for (int r = r0; r < STILE; r += 8) {
                int g = nx + r;
                if (g < n) buf[b ^ 1][r][t] = pts[(size_t)perm[base + g] * 32 + t];
            }
        }
        if (tid < 32) {
            int m = n - i0; if (m > STILE) m = STILE;
            int i = 0;
            for (; i + 4 <= m; i += 4) {
                s = fadd(s, buf[b][i][tid]);
                s = fadd(s, buf[b][i + 1][tid]);
                s = fadd(s, buf[b][i + 2][tid]);
                s = fadd(s, buf[b][i + 3][tid]);
            }
            for (; i < m; i++) s = fadd(s, buf[b][i][tid]);
        }
        __syncthreads();
    }
    if (tid < 32) {
        float v;
        if (n > 0) {
            v = __fdiv_rn(s, (float)n);
            cent[(size_t)j * 32 + tid] = v;
        } else {
            v = cent[(size_t)j * 32 + tid];
        }
        float e = fmul(v, v);
        e = fadd(e, __shfl_xor(e, 16));
        e = fadd(e, __shfl_xor(e, 8));
        e = fadd(e, __shfl_xor(e, 4));
        e = fadd(e, __shfl_xor(e, 2));
        e = fadd(e, __shfl_xor(e, 1));
        if (tid == 0) cc[j] = e;
    }
}

// ---------- key assign + L1: 4 pts/thread x quarter clusters --------
__global__ __launch_bounds__(256) void kdist4p(const float* __restrict__ pts,
        const float* __restrict__ cent, const float* __restrict__ cc,
        float* __restrict__ kd) {
    __shared__ float sc[8192];
    __shared__ float scc[256];
    int tid = threadIdx.x, c = blockIdx.x;
    {
        const float4* c4 = (const float4*)cent;
        float4* s4 = (float4*)sc;
        for (int i = tid; i < 2048; i += 256) s4[i] = c4[i];
    }
    scc[tid] = cc[tid];
    __syncthreads();
    int pg = tid >> 2, quarter = tid & 3;
    int pb = c * 256 + pg * 4;
    float x[4][32];
    float xp[4];
    #pragma unroll
    for (int i = 0; i < 4; i++) {
        const float4* pp = (const float4*)(pts + (size_t)(pb + i) * 32);
        #pragma unroll
        for (int t = 0; t < 8; t++) {
            float4 f = pp[t];
            x[i][4*t] = f.x; x[i][4*t+1] = f.y; x[i][4*t+2] = f.z; x[i][4*t+3] = f.w;
        }
        float e[32];
        #pragma unroll
        for (int t = 0; t < 32; t++) e[t] = fmul(x[i][t], x[i][t]);
        xp[i] = sum32_np(e);   // identical bits to fold's xx
    }
    float bd[4] = {3.4e38f, 3.4e38f, 3.4e38f, 3.4e38f};
    int bj[4] = {0, 0, 0, 0};
    int jbase = quarter * 64;
    for (int jj = 0; jj < 64; jj++) {
        int j = jbase + jj;
        const float4* cj = (const float4*)(sc + j * 32);
        float w[32];
        #pragma unroll
        for (int t = 0; t < 8; t++) {
            float4 f = cj[t];
            w[4*t] = f.x; w[4*t+1] = f.y; w[4*t+2] = f.z; w[4*t+3] = f.w;
        }
        float sj = scc[j];
        #pragma unroll
        for (int i = 0; i < 4; i++) {
            float g = 0.f;
            #pragma unroll
            for (int t = 0; t < 32; t++) g = __builtin_fmaf(x[i][t], w[t], g);
            float d = fadd(fsub(xp[i], fmul(2.f, g)), sj);
            if (d < bd[i]) { bd[i] = d; bj[i] = j; }
        }
    }
    #pragma unroll
    for (int i = 0; i < 4; i++) {
        float ob; int oj;
        ob = __shfl_xor(bd[i], 1); oj = __shfl_xor(bj[i], 1);
        if (ob < bd[i]) { bd[i] = ob; bj[i] = oj; }
        ob = __shfl_xor(bd[i], 2); oj = __shfl_xor(bj[i], 2);
        if (ob < bd[i]) { bd[i] = ob; bj[i] = oj; }
    }
    if (quarter == 0) {
        #pragma unroll
        for (int i = 0; i < 4; i++) {
            const float* cb = &sc[bj[i] * 32];
            float e[32];
            #pragma unroll
            for (int t = 0; t < 32; t++) e[t] = fabsf(fsub(cb[t], x[i][t]));
            kd[pb + i] = sum32_np(e);
        }
    }
}

// ---------- top-256 via radix select (exact stable set) + gather ----
__global__ __launch_bounds__(256) void topk_v2(const float* __restrict__ kd,
        const float* __restrict__ k_t, const float* __restrict__ v_t,
        float* __restrict__ ksel, float* __restrict__ vsel) {
    __shared__ unsigned uv[4096];
    __shared__ int hist[256];
    __shared__ unsigned s_prefix;
    __shared__ int s_rem;
    __shared__ int sc1[256];
    __shared__ int out_src[256];
    int bh = blockIdx.x, tid = threadIdx.x;
    for (int i = tid; i < 4096; i += 256) uv[i] = __float_as_uint(kd[bh * 4096 + i]);
    if (tid == 0) { s_prefix = 0u; s_rem = 256; }
    out_src[tid] = 0;
    __syncthreads();
    for (int pass = 0; pass < 4; pass++) {
        int shift = 24 - 8 * pass;
        hist[tid] = 0;
        __syncthreads();
        unsigned pfx = s_prefix;
        for (int i = tid; i < 4096; i += 256) {
            unsigned u = uv[i];
            bool in = (pass == 0) || ((u >> (shift + 8)) == (pfx >> (shift + 8)));
            if (in) atomicAdd(&hist[(u >> shift) & 255], 1);
        }
        __syncthreads();
        if (tid == 0) {
            int rem = s_rem, cum = 0, b;
            for (b = 255; b >= 0; b--) {
                if (cum + hist[b] >= rem) break;
                cum += hist[b];
            }
            s_rem = rem - cum;
            s_prefix = s_prefix | ((unsigned)b << shift);
        }
        __syncthreads();
    }
    unsigned T = s_prefix;
    int r = s_rem;
    int base_i = tid * 16;
    int ec = 0;
    for (int q = 0; q < 16; q++) ec += (uv[base_i + q] == T) ? 1 : 0;
    sc1[tid] = ec;
    __syncthreads();
    for (int d = 1; d < 256; d <<= 1) {
        int t0 = sc1[tid];
        int u0 = (tid >= d) ? sc1[tid - d] : 0;
        __syncthreads();
        sc1[tid] = t0 + u0;
        __syncthreads();
    }
    int erank = (tid == 0) ? 0 : sc1[tid - 1];
    __syncthreads();
    bool incl[16];
    int ic = 0;
    for (int q = 0; q < 16; q++) {
        unsigned u = uv[base_i + q];
        bool inc;
        if (u > T) inc = true;
        else if (u == T) { inc = (erank < r); erank++; }
        else inc = false;
        incl[q] = inc;
        ic += inc ? 1 : 0;
    }
    sc1[tid] = ic;
    __syncthreads();
    for (int d = 1; d < 256; d <<= 1) {
        int t0 = sc1[tid];
        int u0 = (tid >= d) ? sc1[tid - d] : 0;
        __syncthreads();
        sc1[tid] = t0 + u0;
        __syncthreads();
    }
    int pos = (tid == 0) ? 0 : sc1[tid - 1];
    for (int q = 0; q < 16; q++) {
        if (incl[q]) out_src[pos++] = base_i + q;
    }
    __syncthreads();
    for (int e = tid; e < 256 * 32; e += 256) {
        int jj = e >> 5, t = e & 31;
        int src = out_src[jj];
        ksel[(size_t)bh * 8192 + e] = k_t[((size_t)bh * 4096 + src) * 32 + t];
        vsel[(size_t)bh * 8192 + e] = v_t[((size_t)bh * 4096 + src) * 32 + t];
    }
}

// ---------- attention v3b: 2 q/thread, padded halves (63 µs) --------
#define HPAD 4112
__global__ __launch_bounds__(256) void attn_v3b(const float* __restrict__ q_t,
        const float* __restrict__ ksel, const float* __restrict__ vsel,
        float* __restrict__ out) {
    __shared__ float sk[2 * HPAD];
    __shared__ float sv[2 * HPAD];
    int bh = blockIdx.y, tid = threadIdx.x;
    {
        const float4* gk = (const float4*)(ksel + (size_t)bh * 8192);
        const float4* gv = (const float4*)(vsel + (size_t)bh * 8192);
        for (int i = tid; i < 2048; i += 256) {
            int h = i >> 10, idx = i & 1023;
            ((float4*)(sk + h * HPAD))[idx] = gk[i];
            ((float4*)(sv + h * HPAD))[idx] = gv[i];
        }
    }
    __syncthreads();
    int ql = tid >> 1, slice = tid & 1;
    int p0 = bh * 4096 + blockIdx.x * 256 + ql * 2;
    float q0[32], q1[32];
    {
        const float4* qp0 = (const float4*)(q_t + (size_t)p0 * 32);
        const float4* qp1 = (const float4*)(q_t + (size_t)(p0 + 1) * 32);
        #pragma unroll
        for (int t = 0; t < 8; t++) {
            float4 f = qp0[t];
            q0[4*t] = f.x; q0[4*t+1] = f.y; q0[4*t+2] = f.z; q0[4*t+3] = f.w;
            float4 g = qp1[t];
            q1[4*t] = g.x; q1[4*t+1] = g.y; q1[4*t+2] = g.z; q1[4*t+3] = g.w;
        }
    }
    float o0[32], o1[32];
    #pragma unroll
    for (int t = 0; t < 32; t++) { o0[t] = 0.f; o1[t] = 0.f; }
    float ls0 = 0.f, ls1 = 0.f;
    const float4* k4 = (const float4*)(sk + slice * HPAD);
    const float4* v4 = (const float4*)(sv + slice * HPAD);
    for (int j = 0; j < 128; j++) {
        float a0 = 0.f, b0 = 0.f, c0 = 0.f, d0 = 0.f;
        float a1 = 0.f, b1 = 0.f, c1 = 0.f, d1 = 0.f;
        #pragma unroll
        for (int t = 0; t < 8; t++) {
            float4 kf = k4[j * 8 + t];
            a0 += q0[4*t]   * kf.x; b0 += q0[4*t+1] * kf.y;
            c0 += q0[4*t+2] * kf.z; d0 += q0[4*t+3] * kf.w;
            a1 += q1[4*t]   * kf.x; b1 += q1[4*t+1] * kf.y;
            c1 += q1[4*t+2] * kf.z; d1 += q1[4*t+3] * kf.w;
        }
        float s0 = (a0 + b0) + (c0 + d0);
        float s1 = (a1 + b1) + (c1 + d1);
        float w0 = __expf(s0 - 1.0f);
        float w1 = __expf(s1 - 1.0f);
        ls0 += w0; ls1 += w1;
        #pragma unroll
        for (int t = 0; t < 8; t++) {
            float4 vf = v4[j * 8 + t];
            o0[4*t]   += w0 * vf.x; o0[4*t+1] += w0 * vf.y;
            o0[4*t+2] += w0 * vf.z; o0[4*t+3] += w0 * vf.w;
            o1[4*t]   += w1 * vf.x; o1[4*t+1] += w1 * vf.y;
            o1[4*t+2] += w1 * vf.z; o1[4*t+3] += w1 * vf.w;
        }
    }
    #pragma unroll
    for (int t = 0; t < 32; t++) {
        o0[t] += __shfl_xor(o0[t], 1);
        o1[t] += __shfl_xor(o1[t], 1);
    }
    ls0 += __shfl_xor(ls0, 1);
    ls1 += __shfl_xor(ls1, 1);
    if (slice == 0) {
        float inv0 = 1.f / ls0, inv1 = 1.f / ls1;
        float4* op0 = (float4*)(out + (size_t)p0 * 32);
        float4* op1 = (float4*)(out + (size_t)(p0 + 1) * 32);
        #pragma unroll
        for (int t = 0; t < 8; t++) {
            op0[t] = make_float4(o0[4*t]*inv0, o0[4*t+1]*inv0, o0[4*t+2]*inv0, o0[4*t+3]*inv0);
            op1[t] = make_float4(o1[4*t]*inv1, o1[4*t+1]*inv1, o1[4*t+2]*inv1, o1[4*t+3]*inv1);
        }
    }
}

// ---------- unfold (bh,L,32) -> (b,256,L) ---------------------------
__global__ __launch_bounds__(256) void unfold_kernel(const float* __restrict__ att,
        float* __restrict__ Fo) {
    __shared__ float tbuf[32][65];
    int bh = blockIdx.y, l0 = blockIdx.x * 64;
    int b = bh >> 3, h = bh & 7;
    int tid = threadIdx.x;
    #pragma unroll
    for (int r = 0; r < 8; r++) {
        int e = r * 256 + tid;
        int l = e >> 5, d = e & 31;
        tbuf[d][l] = att[((size_t)bh * 4096 + l0 + l) * 32 + d];
    }
    __syncthreads();
    #pragma unroll
    for (int r = 0; r < 8; r++) {
        int e = r * 256 + tid;
        int d = e >> 6, l = e & 63;
        Fo[((size_t)b * 256 + h * 32 + d) * LSEQ + l0 + l] = tbuf[d][l];
    }
}

// ---------- final LN + scale + residual (numpy orders) --------------
__global__ __launch_bounds__(64) void lnres_np(const float* __restrict__ x,
        const float* __restrict__ g, const float* __restrict__ bt,
        const float* __restrict__ gs, const float* __restrict__ qsrc,
        float* __restrict__ y) {
    int gid = blockIdx.x * 64 + threadIdx.x;
    int b = gid >> 12, l = gid & 4095;
    const float* xb = x + (size_t)b * CDIM * LSEQ + l;
    float s = 0.f;
    #pragma unroll 8
    for (int c = 0; c < 256; c++) s = fadd(s, xb[(size_t)c * LSEQ]);
    float mean = __fdiv_rn(s, 256.f);
    float s2 = 0.f;
    #pragma unroll 8
    for (int c = 0; c < 256; c++) {
        float d = fsub(xb[(size_t)c * LSEQ], mean);
        s2 = fadd(s2, fmul(d, d));
    }
    float var = __fdiv_rn(s2, 256.f);
    float den = fadd(__fsqrt_rn(var), 1e-6f);
    float scale = gs[0];
    const float* qb = qsrc + (size_t)b * CDIM * LSEQ + l;
    float* yb = y + (size_t)b * CDIM * LSEQ + l;
    #pragma unroll 4
    for (int c = 0; c < 256; c++) {
        float d = fsub(xb[(size_t)c * LSEQ], mean);
        float r = fadd(__fdiv_rn(fmul(g[c], d), den), bt[c]);
        yb[(size_t)c * LSEQ] = fadd(fmul(scale, r), qb[(size_t)c * LSEQ]);
    }
}

// ==================================================================
extern "C" void kernel_launch(void* const* d_in, const int* in_sizes, int n_in,
                              void* d_out, int out_size, void* d_ws, size_t ws_size,
                              hipStream_t stream) {
    const float* qsrc   = (const float*)d_in[0];
    const float* ctx    = (const float*)d_in[1];
    const float* w_q    = (const float*)d_in[2];
    const float* w_kv   = (const float*)d_in[3];
    const float* w_out  = (const float*)d_in[4];
    const float* g_ctx  = (const float*)d_in[5];
    const float* b_ctx  = (const float*)d_in[6];
    const float* g_q    = (const float*)d_in[7];
    const float* b_q    = (const float*)d_in[8];
    const float* g_out  = (const float*)d_in[9];
    const float* b_out  = (const float*)d_in[10];
    const float* gs     = (const float*)d_in[11];

    char* base = (char*)d_ws;
    const size_t MB = 1024 * 1024;
    float* yln   = (float*)base;               // [0,8) LN out; later att
    float* att   = (float*)base;
    float* kvbuf = (float*)(base + 8 * MB);    // [8,24) kv conv; later y32 [8,16)
    float* y32   = (float*)(base + 8 * MB);
    float* qbuf  = (float*)(base + 24 * MB);   // [24,32) q conv; later Fo
    float* Fo    = (float*)(base + 24 * MB);
    float* q_t   = (float*)(base + 32 * MB);   // [32,40)
    float* k_t   = (float*)(base + 40 * MB);   // [40,48)
    float* v_t   = (float*)(base + 48 * MB);   // [48,56)
    char* SM = base + 56 * MB;
    float* xx_q      = (float*)(SM + 0);            // 256 KB
    float* cent      = (float*)(SM + 512 * 1024);   // 32 KB
    float* cc        = (float*)(SM + 576 * 1024);   // 1 KB
    int*   totals    = (int*)  (SM + 640 * 1024);   // 1 KB
    int*   asn       = (int*)  (SM + 704 * 1024);   // 256 KB
    int*   hist      = (int*)  (SM + 960 * 1024);   // 256 KB
    int*   chunkbase = (int*)  (SM + 1472 * 1024);  // 256 KB
    int*   perm      = (int*)  (SM + 1984 * 1024);  // 256 KB
    float* kd        = (float*)(SM + 2240 * 1024);  // 256 KB
    float* ksel      = (float*)(SM + 2496 * 1024);  // 512 KB
    float* vsel      = (float*)(SM + 3008 * 1024);  // 512 KB

    // context branch
    ln_np<<<128, 64, 0, stream>>>(ctx, g_ctx, b_ctx, yln);
    conv_nl<16, 2><<<dim3(8, 32, 2), 256, 0, stream>>>(w_kv, 0, yln, kvbuf, 512);
    fold_np<<<256, 256, 0, stream>>>(kvbuf, 512, 0, 1, k_t, nullptr, nullptr, nullptr);
    fold_np<<<256, 256, 0, stream>>>(kvbuf, 512, 256, 0, v_t, nullptr, nullptr, nullptr);
    // query branch (fold also emits xx and initial cent/cc)
    ln_np<<<128, 64, 0, stream>>>(qsrc, g_q, b_q, yln);
    conv_nl<8, 2><<<dim3(8, 32, 2), 256, 0, stream>>>(w_q, 0, yln, qbuf, 256);
    fold_np<<<256, 256, 0, stream>>>(qbuf, 256, 0, 1, q_t, xx_q, cent, cc);

    for (int it = 0; it < 10; it++) {
        assign4p<<<256, 256, 0, stream>>>(q_t, xx_q, cent, cc, asn, hist);
        scan_chunks<<<256, 256, 0, stream>>>(hist, chunkbase, totals);
        scatter_v5<<<256, 256, 0, stream>>>(asn, chunkbase, totals, perm);
        sumk_v4<<<256, 256, 0, stream>>>(q_t, perm, totals, cent, cc);
    }

    kdist4p<<<256, 256, 0, stream>>>(k_t, cent, cc, kd);
    topk_v2<<<16, 256, 0, stream>>>(kd, k_t, v_t, ksel, vsel);
    attn_v3b<<<dim3(16, 16), 256, 0, stream>>>(q_t, ksel, vsel, att);
    unfold_kernel<<<dim3(64, 16), 256, 0, stream>>>(att, Fo);
    conv_nl<8, 2><<<dim3(8, 32, 2), 256, 0, stream>>>(w_out, 0, Fo, y32, 256);
    lnres_np<<<128, 64, 0, stream>>>(y32, g_out, b_out, gs, qsrc, (float*)d_out);
}

// Round 17
// 969.293 us; speedup vs baseline: 1.1750x; 1.0089x over previous
//
#include <hip/hip_runtime.h>
#include <math.h>

#define CDIM 256
#define LSEQ 4096
#define NBH 16
#define NPTS 65536
#define KC 256

__device__ __forceinline__ float fadd(float a, float b){ return __fadd_rn(a,b); }
__device__ __forceinline__ float fmul(float a, float b){ return __fmul_rn(a,b); }
__device__ __forceinline__ float fsub(float a, float b){ return __fsub_rn(a,b); }

// numpy contiguous n=32 float32 sum, AVX-512 npyv path (verified R5)
__device__ __forceinline__ float sum32_np(const float* e){
    float l[16];
    #pragma unroll
    for (int j = 0; j < 16; j++) l[j] = fadd(e[j], e[j + 16]);
    float t3[8];
    #pragma unroll
    for (int j = 0; j < 8; j++) t3[j] = fadd(l[j], l[j + 8]);
    float t6[4];
    #pragma unroll
    for (int j = 0; j < 4; j++) t6[j] = fadd(t3[j], t3[j + 4]);
    return fadd(fadd(t6[0], t6[2]), fadd(t6[1], t6[3]));
}

// ---------- both LayerNorms, one launch (numpy exact per position) --
// grid 256 x 64 thr: gid<8192 -> tensor0 (ctx), else tensor1 (qsrc)
__global__ __launch_bounds__(64) void ln2_np(
        const float* __restrict__ x0, const float* __restrict__ g0,
        const float* __restrict__ bt0, float* __restrict__ y0,
        const float* __restrict__ x1, const float* __restrict__ g1,
        const float* __restrict__ bt1, float* __restrict__ y1) {
    int gid = blockIdx.x * 64 + threadIdx.x;
    int which = gid >> 13;               // wave-uniform (64 | 8192)
    int r = gid & 8191;
    int b = r >> 12, l = r & 4095;
    const float* x  = which ? x1 : x0;
    const float* g  = which ? g1 : g0;
    const float* bt = which ? bt1 : bt0;
    float* y        = which ? y1 : y0;
    const float* xb = x + (size_t)b * CDIM * LSEQ + l;
    float s = 0.f;
    #pragma unroll 8
    for (int c = 0; c < 256; c++) s = fadd(s, xb[(size_t)c * LSEQ]);
    float mean = __fdiv_rn(s, 256.f);
    float s2 = 0.f;
    #pragma unroll 8
    for (int c = 0; c < 256; c++) {
        float d = fsub(xb[(size_t)c * LSEQ], mean);
        s2 = fadd(s2, fmul(d, d));
    }
    float var = __fdiv_rn(s2, 256.f);
    float den = fadd(__fsqrt_rn(var), 1e-6f);
    float* yb = y + (size_t)b * CDIM * LSEQ + l;
    #pragma unroll 4
    for (int c = 0; c < 256; c++) {
        float d = fsub(xb[(size_t)c * LSEQ], mean);
        yb[(size_t)c * LSEQ] = fadd(__fdiv_rn(fmul(g[c], d), den), bt[c]);
    }
}

// ---------- conv1x1, SOP exact (decision path: k, q) ----------------
template<int COT, int NL>
__global__ __launch_bounds__(256) void conv_nl(const float* __restrict__ W, int row0,
        const float* __restrict__ X, float* __restrict__ Y, int nrows) {
    __shared__ float ws[COT * 256];
    int tid = threadIdx.x;
    int l0 = blockIdx.x * (256 * NL) + tid;
    int o0 = blockIdx.y * COT;
    int b = blockIdx.z;
    {
        const float4* wb4 = (const float4*)(W + (size_t)(row0 + o0) * CDIM);
        float4* ws4 = (float4*)ws;
        for (int i = tid; i < COT * 64; i += 256) ws4[i] = wb4[i];
    }
    __syncthreads();
    const float* xb = X + (size_t)b * CDIM * LSEQ;
    float acc[COT][NL];
    #pragma unroll
    for (int oo = 0; oo < COT; oo++)
        #pragma unroll
        for (int i = 0; i < NL; i++) acc[oo][i] = 0.f;
    const float4* ws4 = (const float4*)ws;
    for (int c = 0; c < 256; c += 4) {
        float xv[NL][4];
        #pragma unroll
        for (int i = 0; i < NL; i++) {
            #pragma unroll
            for (int k = 0; k < 4; k++)
                xv[i][k] = xb[(size_t)(c + k) * LSEQ + l0 + i * 256];
        }
        #pragma unroll
        for (int oo = 0; oo < COT; oo++) {
            float4 w = ws4[(oo * 256 + c) >> 2];
            #pragma unroll
            for (int i = 0; i < NL; i++) {
                acc[oo][i] = fadd(acc[oo][i], fmul(w.x, xv[i][0]));
                acc[oo][i] = fadd(acc[oo][i], fmul(w.y, xv[i][1]));
                acc[oo][i] = fadd(acc[oo][i], fmul(w.z, xv[i][2]));
                acc[oo][i] = fadd(acc[oo][i], fmul(w.w, xv[i][3]));
            }
        }
    }
    #pragma unroll
    for (int oo = 0; oo < COT; oo++)
        #pragma unroll
        for (int i = 0; i < NL; i++)
            Y[((size_t)b * nrows + row0 + o0 + oo) * LSEQ + l0 + i * 256] = acc[oo][i];
}

// ---------- conv1x1, FMA (value path: v, out) -----------------------
template<int COT, int NL>
__global__ __launch_bounds__(256) void conv_fma(const float* __restrict__ W, int row0,
        const float* __restrict__ X, float* __restrict__ Y, int nrows) {
    __shared__ float ws[COT * 256];
    int tid = threadIdx.x;
    int l0 = blockIdx.x * (256 * NL) + tid;
    int o0 = blockIdx.y * COT;
    int b = blockIdx.z;
    {
        const float4* wb4 = (const float4*)(W + (size_t)(row0 + o0) * CDIM);
        float4* ws4 = (float4*)ws;
        for (int i = tid; i < COT * 64; i += 256) ws4[i] = wb4[i];
    }
    __syncthreads();
    const float* xb = X + (size_t)b * CDIM * LSEQ;
    float acc[COT][NL];
    #pragma unroll
    for (int oo = 0; oo < COT; oo++)
        #pragma unroll
        for (int i = 0; i < NL; i++) acc[oo][i] = 0.f;
    const float4* ws4 = (const float4*)ws;
    for (int c = 0; c < 256; c += 4) {
        float xv[NL][4];
        #pragma unroll
        for (int i = 0; i < NL; i++) {
            #pragma unroll
            for (int k = 0; k < 4; k++)
                xv[i][k] = xb[(size_t)(c + k) * LSEQ + l0 + i * 256];
        }
        #pragma unroll
        for (int oo = 0; oo < COT; oo++) {
            float4 w = ws4[(oo * 256 + c) >> 2];
            #pragma unroll
            for (int i = 0; i < NL; i++) {
                acc[oo][i] = __builtin_fmaf(w.x, xv[i][0], acc[oo][i]);
                acc[oo][i] = __builtin_fmaf(w.y, xv[i][1], acc[oo][i]);
                acc[oo][i] = __builtin_fmaf(w.z, xv[i][2], acc[oo][i]);
                acc[oo][i] = __builtin_fmaf(w.w, xv[i][3], acc[oo][i]);
            }
        }
    }
    #pragma unroll
    for (int oo = 0; oo < COT; oo++)
        #pragma unroll
        for (int i = 0; i < NL; i++)
            Y[((size_t)b * nrows + row0 + o0 + oo) * LSEQ + l0 + i * 256] = acc[oo][i];
}

// ---------- fold x3 (k norm, v plain, q norm+xx+cent/cc) ------------
__device__ __forceinline__ void fold_body(const float* __restrict__ src,
        int srcRows, int row0, int donorm, float* __restrict__ dst,
        float* __restrict__ xxout, float* __restrict__ centout,
        float* __restrict__ ccout, int p) {
    int bh = p >> 12, l = p & 4095;
    int b = bh >> 3, h = bh & 7;
    const float* sp = src + ((size_t)b * srcRows + row0 + h * 32) * LSEQ + l;
    float x[32];
    #pragma unroll
    for (int t = 0; t < 32; t++) x[t] = sp[(size_t)t * LSEQ];
    float4* dp4 = (float4*)(dst + (size_t)p * 32);
    if (donorm) {
        float ss = 0.f;
        #pragma unroll
        for (int t = 0; t < 32; t++) ss = fadd(ss, fmul(x[t], x[t]));
        float n = __fsqrt_rn(ss);
        float den = fmaxf(n, 1e-12f);
        #pragma unroll
        for (int t = 0; t < 32; t++) x[t] = __fdiv_rn(x[t], den);
    }
    #pragma unroll
    for (int t = 0; t < 8; t++)
        dp4[t] = make_float4(x[4*t], x[4*t+1], x[4*t+2], x[4*t+3]);
    if (xxout) {
        float e[32];
        #pragma unroll
        for (int t = 0; t < 32; t++) e[t] = fmul(x[t], x[t]);
        float xv = sum32_np(e);
        xxout[p] = xv;
        if (centout && p < KC) {
            float4* cp4 = (float4*)(centout + (size_t)p * 32);
            #pragma unroll
            for (int t = 0; t < 8; t++)
                cp4[t] = make_float4(x[4*t], x[4*t+1], x[4*t+2], x[4*t+3]);
            ccout[p] = xv;
        }
    }
}

__global__ __launch_bounds__(256) void fold3_np(const float* __restrict__ kvbuf,
        const float* __restrict__ qbuf, float* __restrict__ k_t,
        float* __restrict__ v_t, float* __restrict__ q_t,
        float* __restrict__ xx, float* __restrict__ cent, float* __restrict__ cc) {
    int blk = blockIdx.x, tid = threadIdx.x;
    if (blk < 256) {
        fold_body(kvbuf, 512, 0, 1, k_t, nullptr, nullptr, nullptr, blk * 256 + tid);
    } else if (blk < 512) {
        fold_body(kvbuf, 512, 256, 0, v_t, nullptr, nullptr, nullptr, (blk - 256) * 256 + tid);
    } else {
        fold_body(qbuf, 256, 0, 1, q_t, xx, cent, cc, (blk - 512) * 256 + tid);
    }
}

// ---------- argmin+hist: 4 pts/thread x quarter clusters (R16) ------
__global__ __launch_bounds__(256) void assign4p(const float* __restrict__ pts,
        const float* __restrict__ xx, const float* __restrict__ cent,
        const float* __restrict__ cc, int* __restrict__ asn, int* __restrict__ hist) {
    __shared__ float sc[8192];
    __shared__ float scc[256];
    __shared__ int bins[256];
    int tid = threadIdx.x, c = blockIdx.x;
    {
        const float4* c4 = (const float4*)cent;
        float4* s4 = (float4*)sc;
        for (int i = tid; i < 2048; i += 256) s4[i] = c4[i];
    }
    scc[tid] = cc[tid];
    bins[tid] = 0;
    __syncthreads();
    int pg = tid >> 2, quarter = tid & 3;
    int pb = c * 256 + pg * 4;
    float x[4][32];
    float xp[4];
    #pragma unroll
    for (int i = 0; i < 4; i++) {
        const float4* pp = (const float4*)(pts + (size_t)(pb + i) * 32);
        #pragma unroll
        for (int t = 0; t < 8; t++) {
            float4 f = pp[t];
            x[i][4*t] = f.x; x[i][4*t+1] = f.y; x[i][4*t+2] = f.z; x[i][4*t+3] = f.w;
        }
        xp[i] = xx[pb + i];
    }
    float bd[4] = {3.4e38f, 3.4e38f, 3.4e38f, 3.4e38f};
    int bj[4] = {0, 0, 0, 0};
    int jbase = quarter * 64;
    for (int jj = 0; jj < 64; jj++) {
        int j = jbase + jj;
        const float4* cj = (const float4*)(sc + j * 32);
        float w[32];
        #pragma unroll
        for (int t = 0; t < 8; t++) {
            float4 f = cj[t];
            w[4*t] = f.x; w[4*t+1] = f.y; w[4*t+2] = f.z; w[4*t+3] = f.w;
        }
        float sj = scc[j];
        #pragma unroll
        for (int i = 0; i < 4; i++) {
            float g = 0.f;
            #pragma unroll
            for (int t = 0; t < 32; t++) g = __builtin_fmaf(x[i][t], w[t], g);
            float d = fadd(fsub(xp[i], fmul(2.f, g)), sj);
            if (d < bd[i]) { bd[i] = d; bj[i] = j; }
        }
    }
    #pragma unroll
    for (int i = 0; i < 4; i++) {
        float ob; int oj;
        ob = __shfl_xor(bd[i], 1); oj = __shfl_xor(bj[i], 1);
        if (ob < bd[i]) { bd[i] = ob; bj[i] = oj; }
        ob = __shfl_xor(bd[i], 2); oj = __shfl_xor(bj[i], 2);
        if (ob < bd[i]) { bd[i] = ob; bj[i] = oj; }
    }
    if (quarter == 0) {
        #pragma unroll
        for (int i = 0; i < 4; i++) {
            asn[pb + i] = bj[i];
            atomicAdd(&bins[bj[i]], 1);
        }
    }
    __syncthreads();
    hist[c * 256 + tid] = bins[tid];
}

// ---------- per-cluster prefix over 256 chunks ----------------------
__global__ __launch_bounds__(256) void scan_chunks(const int* __restrict__ hist,
        int* __restrict__ chunkbase, int* __restrict__ totals) {
    __shared__ int a[256];
    int j = blockIdx.x, c = threadIdx.x;
    a[c] = hist[(size_t)c * 256 + j];
    __syncthreads();
    for (int d = 1; d < 256; d <<= 1) {
        int v = a[c];
        int u = (c >= d) ? a[c - d] : 0;
        __syncthreads();
        a[c] = v + u;
        __syncthreads();
    }
    chunkbase[(size_t)c * 256 + j] = (c == 0) ? 0 : a[c - 1];
    if (c == 255) totals[j] = a[255];
}

// ---------- scatter: parallel cbase scan + stable rank --------------
__global__ __launch_bounds__(256) void scatter_v5(const int* __restrict__ asn,
        const int* __restrict__ chunkbase, const int* __restrict__ totals,
        int* __restrict__ perm) {
    __shared__ int cb[256];
    __shared__ int al[256];
    int c = blockIdx.x, tid = threadIdx.x;
    cb[tid] = totals[tid];
    al[tid] = asn[c * 256 + tid];
    __syncthreads();
    for (int d = 1; d < 256; d <<= 1) {
        int v = cb[tid];
        int u = (tid >= d) ? cb[tid - d] : 0;
        __syncthreads();
        cb[tid] = v + u;
        __syncthreads();
    }
    int my = al[tid];
    int base = (my == 0) ? 0 : cb[my - 1];
    int r = 0;
    for (int i = 0; i < tid; i++) r += (al[i] == my) ? 1 : 0;
    perm[base + chunkbase[(size_t)c * 256 + my] + r] = c * 256 + tid;
}

// ---------- ordered sum + update + cc (parallel cbase scan) ---------
#define STILE 128
__global__ __launch_bounds__(256) void sumk_v4(const float* __restrict__ pts,
        const int* __restrict__ perm, const int* __restrict__ totals,
        float* __restrict__ cent, float* __restrict__ cc) {
    __shared__ int cb[256];
    __shared__ float buf[2][STILE][32];
    int j = blockIdx.x, tid = threadIdx.x;
    cb[tid] = totals[tid];
    __syncthreads();
    for (int d = 1; d < 256; d <<= 1) {
        int v = cb[tid];
        int u = (tid >= d) ? cb[tid - d] : 0;
        __syncthreads();
        cb[tid] = v + u;
        __syncthreads();
    }
    int base = (j == 0) ? 0 : cb[j - 1];
    int n = totals[j];
    int t = tid & 31, r0 = tid >> 5;
    for (int r = r0; r < STILE; r += 8) {
        if (r < n) buf[0][r][t] = pts[(size_t)perm[base + r] * 32 + t];
    }
    __syncthreads();
    float s = 0.f;
    int b = 0;
    for (int i0 = 0; i0 < n; i0 += STILE, b ^= 1) {
        int nx = i0 + STILE;
        if (nx < n) {
            for (int r = r0; r < STILE; r += 8) {
                int g = nx + r;
                if (g < n) buf[b ^ 1][r][t] = pts[(size_t)perm[base + g] * 32 + t];
            }
        }
        if (tid < 32) {
            int m = n - i0; if (m > STILE) m = STILE;
            int i = 0;
            for (; i + 4 <= m; i += 4) {
                s = fadd(s, buf[b][i][tid]);
                s = fadd(s, buf[b][i + 1][tid]);
                s = fadd(s, buf[b][i + 2][tid]);
                s = fadd(s, buf[b][i + 3][tid]);
            }
            for (; i < m; i++) s = fadd(s, buf[b][i][tid]);
        }
        __syncthreads();
    }
    if (tid < 32) {
        float v;
        if (n > 0) {
            v = __fdiv_rn(s, (float)n);
            cent[(size_t)j * 32 + tid] = v;
        } else {
            v = cent[(size_t)j * 32 + tid];
        }
        float e = fmul(v, v);
        e = fadd(e, __shfl_xor(e, 16));
        e = fadd(e, __shfl_xor(e, 8));
        e = fadd(e, __shfl_xor(e, 4));
        e = fadd(e, __shfl_xor(e, 2));
        e = fadd(e, __shfl_xor(e, 1));
        if (tid == 0) cc[j] = e;
    }
}

// ---------- key assign + L1: 4 pts/thread x quarter clusters --------
__global__ __launch_bounds__(256) void kdist4p(const float* __restrict__ pts,
        const float* __restrict__ cent, const float* __restrict__ cc,
        float* __restrict__ kd) {
    __shared__ float sc[8192];
    __shared__ float scc[256];
    int tid = threadIdx.x, c = blockIdx.x;
    {
        const float4* c4 = (const float4*)cent;
        float4* s4 = (float4*)sc;
        for (int i = tid; i < 2048; i += 256) s4[i] = c4[i];
    }
    scc[tid] = cc[tid];
    __syncthreads();
    int pg = tid >> 2, quarter = tid & 3;
    int pb = c * 256 + pg * 4;
    float x[4][32];
    float xp[4];
    #pragma unroll
    for (int i = 0; i < 4; i++) {
        const float4* pp = (const float4*)(pts + (size_t)(pb + i) * 32);
        #pragma unroll
        for (int t = 0; t < 8; t++) {
            float4 f = pp[t];
            x[i][4*t] = f.x; x[i][4*t+1] = f.y; x[i][4*t+2] = f.z; x[i][4*t+3] = f.w;
        }
        float e[32];
        #pragma unroll
        for (int t = 0; t < 32; t++) e[t] = fmul(x[i][t], x[i][t]);
        xp[i] = sum32_np(e);
    }
    float bd[4] = {3.4e38f, 3.4e38f, 3.4e38f, 3.4e38f};
    int bj[4] = {0, 0, 0, 0};
    int jbase = quarter * 64;
    for (int jj = 0; jj < 64; jj++) {
        int j = jbase + jj;
        const float4* cj = (const float4*)(sc + j * 32);
        float w[32];
        #pragma unroll
        for (int t = 0; t < 8; t++) {
            float4 f = cj[t];
            w[4*t] = f.x; w[4*t+1] = f.y; w[4*t+2] = f.z; w[4*t+3] = f.w;
        }
        float sj = scc[j];
        #pragma unroll
        for (int i = 0; i < 4; i++) {
            float g = 0.f;
            #pragma unroll
            for (int t = 0; t < 32; t++) g = __builtin_fmaf(x[i][t], w[t], g);
            float d = fadd(fsub(xp[i], fmul(2.f, g)), sj);
            if (d < bd[i]) { bd[i] = d; bj[i] = j; }
        }
    }
    #pragma unroll
    for (int i = 0; i < 4; i++) {
        float ob; int oj;
        ob = __shfl_xor(bd[i], 1); oj = __shfl_xor(bj[i], 1);
        if (ob < bd[i]) { bd[i] = ob; bj[i] = oj; }
        ob = __shfl_xor(bd[i], 2); oj = __shfl_xor(bj[i], 2);
        if (ob < bd[i]) { bd[i] = ob; bj[i] = oj; }
    }
    if (quarter == 0) {
        #pragma unroll
        for (int i = 0; i < 4; i++) {
            const float* cb = &sc[bj[i] * 32];
            float e[32];
            #pragma unroll
            for (int t = 0; t < 32; t++) e[t] = fabsf(fsub(cb[t], x[i][t]));
            kd[pb + i] = sum32_np(e);
        }
    }
}

// ---------- top-256 via radix select (exact stable set) + gather ----
__global__ __launch_bounds__(256) void topk_v2(const float* __restrict__ kd,
        const float* __restrict__ k_t, const float* __restrict__ v_t,
        float* __restrict__ ksel, float* __restrict__ vsel) {
    __shared__ unsigned uv[4096];
    __shared__ int hist[256];
    __shared__ unsigned s_prefix;
    __shared__ int s_rem;
    __shared__ int sc1[256];
    __shared__ int out_src[256];
    int bh = blockIdx.x, tid = threadIdx.x;
    for (int i = tid; i < 4096; i += 256) uv[i] = __float_as_uint(kd[bh * 4096 + i]);
    if (tid == 0) { s_prefix = 0u; s_rem = 256; }
    out_src[tid] = 0;
    __syncthreads();
    for (int pass = 0; pass < 4; pass++) {
        int shift = 24 - 8 * pass;
        hist[tid] = 0;
        __syncthreads();
        unsigned pfx = s_prefix;
        for (int i = tid; i < 4096; i += 256) {
            unsigned u = uv[i];
            bool in = (pass == 0) || ((u >> (shift + 8)) == (pfx >> (shift + 8)));
            if (in) atomicAdd(&hist[(u >> shift) & 255], 1);
        }
        __syncthreads();
        if (tid == 0) {
            int rem = s_rem, cum = 0, b;
            for (b = 255; b >= 0; b--) {
                if (cum + hist[b] >= rem) break;
                cum += hist[b];
            }
            s_rem = rem - cum;
            s_prefix = s_prefix | ((unsigned)b << shift);
        }
        __syncthreads();
    }
    unsigned T = s_prefix;
    int r = s_rem;
    int base_i = tid * 16;
    int ec = 0;
    for (int q = 0; q < 16; q++) ec += (uv[base_i + q] == T) ? 1 : 0;
    sc1[tid] = ec;
    __syncthreads();
    for (int d = 1; d < 256; d <<= 1) {
        int t0 = sc1[tid];
        int u0 = (tid >= d) ? sc1[tid - d] : 0;
        __syncthreads();
        sc1[tid] = t0 + u0;
        __syncthreads();
    }
    int erank = (tid == 0) ? 0 : sc1[tid - 1];
    __syncthreads();
    bool incl[16];
    int ic = 0;
    for (int q = 0; q < 16; q++) {
        unsigned u = uv[base_i + q];
        bool inc;
        if (u > T) inc = true;
        else if (u == T) { inc = (erank < r); erank++; }
        else inc = false;
        incl[q] = inc;
        ic += inc ? 1 : 0;
    }
    sc1[tid] = ic;
    __syncthreads();
    for (int d = 1; d < 256; d <<= 1) {
        int t0 = sc1[tid];
        int u0 = (tid >= d) ? sc1[tid - d] : 0;
        __syncthreads();
        sc1[tid] = t0 + u0;
        __syncthreads();
    }
    int pos = (tid == 0) ? 0 : sc1[tid - 1];
    for (int q = 0; q < 16; q++) {
        if (incl[q]) out_src[pos++] = base_i + q;
    }
    __syncthreads();
    for (int e = tid; e < 256 * 32; e += 256) {
        int jj = e >> 5, t = e & 31;
        int src = out_src[jj];
        ksel[(size_t)bh * 8192 + e] = k_t[((size_t)bh * 4096 + src) * 32 + t];
        vsel[(size_t)bh * 8192 + e] = v_t[((size_t)bh * 4096 + src) * 32 + t];
    }
}

// ---------- attention v3c: 512 thr, 4-lane (slice x dhalf) split ----
// value path only: re-association safe. lanes: bit0=slice(key half),
// bit1=dh(dim half). score: half-dots combined via shfl_xor(2);
// output halves combined via shfl_xor(1).
#define HPAD 4112
__global__ __launch_bounds__(512) void attn_v3c(const float* __restrict__ q_t,
        const float* __restrict__ ksel, const float* __restrict__ vsel,
        float* __restrict__ out) {
    __shared__ float sk[2 * HPAD];
    __shared__ float sv[2 * HPAD];
    int bh = blockIdx.y, tid = threadIdx.x;
    {
        const float4* gk = (const float4*)(ksel + (size_t)bh * 8192);
        const float4* gv = (const float4*)(vsel + (size_t)bh * 8192);
        for (int i = tid; i < 2048; i += 512) {
            int h = i >> 10, idx = i & 1023;
            ((float4*)(sk + h * HPAD))[idx] = gk[i];
            ((float4*)(sv + h * HPAD))[idx] = gv[i];
        }
    }
    __syncthreads();
    int grp = tid >> 2;
    int slice = tid & 1;
    int dh = (tid >> 1) & 1;
    int p0 = bh * 4096 + blockIdx.x * 256 + grp * 2;
    float q0[16], q1[16];
    {
        const float4* qp0 = (const float4*)(q_t + (size_t)p0 * 32 + dh * 16);
        const float4* qp1 = (const float4*)(q_t + (size_t)(p0 + 1) * 32 + dh * 16);
        #pragma unroll
        for (int t = 0; t < 4; t++) {
            float4 f = qp0[t];
            q0[4*t] = f.x; q0[4*t+1] = f.y; q0[4*t+2] = f.z; q0[4*t+3] = f.w;
            float4 g = qp1[t];
            q1[4*t] = g.x; q1[4*t+1] = g.y; q1[4*t+2] = g.z; q1[4*t+3] = g.w;
        }
    }
    float o0[16], o1[16];
    #pragma unroll
    for (int t = 0; t < 16; t++) { o0[t] = 0.f; o1[t] = 0.f; }
    float ls0 = 0.f, ls1 = 0.f;
    const float* kb = sk + slice * HPAD + dh * 16;
    const float* vb = sv + slice * HPAD + dh * 16;
    for (int j = 0; j < 128; j++) {
        float a0 = 0.f, b0 = 0.f, c0 = 0.f, d0 = 0.f;
        float a1 = 0.f, b1 = 0.f, c1 = 0.f, d1 = 0.f;
        #pragma unroll
        for (int t = 0; t < 4; t++) {
            float4 kf = *(const float4*)(kb + j * 32 + t * 4);
            a0 += q0[4*t]   * kf.x; b0 += q0[4*t+1] * kf.y;
            c0 += q0[4*t+2] * kf.z; d0 += q0[4*t+3] * kf.w;
            a1 += q1[4*t]   * kf.x; b1 += q1[4*t+1] * kf.y;
            c1 += q1[4*t+2] * kf.z; d1 += q1[4*t+3] * kf.w;
        }
        float ps0 = (a0 + b0) + (c0 + d0);
        float ps1 = (a1 + b1) + (c1 + d1);
        ps0 += __shfl_xor(ps0, 2);      // combine dim halves
        ps1 += __shfl_xor(ps1, 2);
        float w0 = __expf(ps0 - 1.0f);  // s <= 1 (unit vectors)
        float w1 = __expf(ps1 - 1.0f);
        ls0 += w0; ls1 += w1;
        #pragma unroll
        for (int t = 0; t < 4; t++) {
            float4 vf = *(const float4*)(vb + j * 32 + t * 4);
            o0[4*t]   += w0 * vf.x; o0[4*t+1] += w0 * vf.y;
            o0[4*t+2] += w0 * vf.z; o0[4*t+3] += w0 * vf.w;
            o1[4*t]   += w1 * vf.x; o1[4*t+1] += w1 * vf.y;
            o1[4*t+2] += w1 * vf.z; o1[4*t+3] += w1 * vf.w;
        }
    }
    // combine key-half slices
    #pragma unroll
    for (int t = 0; t < 16; t++) {
        o0[t] += __shfl_xor(o0[t], 1);
        o1[t] += __shfl_xor(o1[t], 1);
    }
    ls0 += __shfl_xor(ls0, 1);
    ls1 += __shfl_xor(ls1, 1);
    if (slice == 0) {
        float inv0 = 1.f / ls0, inv1 = 1.f / ls1;
        float4* op0 = (float4*)(out + (size_t)p0 * 32 + dh * 16);
        float4* op1 = (float4*)(out + (size_t)(p0 + 1) * 32 + dh * 16);
        #pragma unroll
        for (int t = 0; t < 4; t++) {
            op0[t] = make_float4(o0[4*t]*inv0, o0[4*t+1]*inv0, o0[4*t+2]*inv0, o0[4*t+3]*inv0);
            op1[t] = make_float4(o1[4*t]*inv1, o1[4*t+1]*inv1, o1[4*t+2]*inv1, o1[4*t+3]*inv1);
        }
    }
}

// ---------- unfold (bh,L,32) -> (b,256,L) ---------------------------
__global__ __launch_bounds__(256) void unfold_kernel(const float* __restrict__ att,
        float* __restrict__ Fo) {
    __shared__ float tbuf[32][65];
    int bh = blockIdx.y, l0 = blockIdx.x * 64;
    int b = bh >> 3, h = bh & 7;
    int tid = threadIdx.x;
    #pragma unroll
    for (int r = 0; r < 8; r++) {
        int e = r * 256 + tid;
        int l = e >> 5, d = e & 31;
        tbuf[d][l] = att[((size_t)bh * 4096 + l0 + l) * 32 + d];
    }
    __syncthreads();
    #pragma unroll
    for (int r = 0; r < 8; r++) {
        int e = r * 256 + tid;
        int d = e >> 6, l = e & 63;
        Fo[((size_t)b * 256 + h * 32 + d) * LSEQ + l0 + l] = tbuf[d][l];
    }
}

// ---------- final LN + scale + residual (numpy orders) --------------
__global__ __launch_bounds__(64) void lnres_np(const float* __restrict__ x,
        const float* __restrict__ g, const float* __restrict__ bt,
        const float* __restrict__ gs, const float* __restrict__ qsrc,
        float* __restrict__ y) {
    int gid = blockIdx.x * 64 + threadIdx.x;
    int b = gid >> 12, l = gid & 4095;
    const float* xb = x + (size_t)b * CDIM * LSEQ + l;
    float s = 0.f;
    #pragma unroll 8
    for (int c = 0; c < 256; c++) s = fadd(s, xb[(size_t)c * LSEQ]);
    float mean = __fdiv_rn(s, 256.f);
    float s2 = 0.f;
    #pragma unroll 8
    for (int c = 0; c < 256; c++) {
        float d = fsub(xb[(size_t)c * LSEQ], mean);
        s2 = fadd(s2, fmul(d, d));
    }
    float var = __fdiv_rn(s2, 256.f);
    float den = fadd(__fsqrt_rn(var), 1e-6f);
    float scale = gs[0];
    const float* qb = qsrc + (size_t)b * CDIM * LSEQ + l;
    float* yb = y + (size_t)b * CDIM * LSEQ + l;
    #pragma unroll 4
    for (int c = 0; c < 256; c++) {
        float d = fsub(xb[(size_t)c * LSEQ], mean);
        float r = fadd(__fdiv_rn(fmul(g[c], d), den), bt[c]);
        yb[(size_t)c * LSEQ] = fadd(fmul(scale, r), qb[(size_t)c * LSEQ]);
    }
}

// ==================================================================
extern "C" void kernel_launch(void* const* d_in, const int* in_sizes, int n_in,
                              void* d_out, int out_size, void* d_ws, size_t ws_size,
                              hipStream_t stream) {
    const float* qsrc   = (const float*)d_in[0];
    const float* ctx    = (const float*)d_in[1];
    const float* w_q    = (const float*)d_in[2];
    const float* w_kv   = (const float*)d_in[3];
    const float* w_out  = (const float*)d_in[4];
    const float* g_ctx  = (const float*)d_in[5];
    const float* b_ctx  = (const float*)d_in[6];
    const float* g_q    = (const float*)d_in[7];
    const float* b_q    = (const float*)d_in[8];
    const float* g_out  = (const float*)d_in[9];
    const float* b_out  = (const float*)d_in[10];
    const float* gs     = (const float*)d_in[11];

    char* base = (char*)d_ws;
    const size_t MB = 1024 * 1024;
    float* yln   = (float*)base;               // [0,8) ctx LN; later att
    float* att   = (float*)base;
    float* kvbuf = (float*)(base + 8 * MB);    // [8,24) kv conv; later y32 [8,16)
    float* y32   = (float*)(base + 8 * MB);
    float* qbuf  = (float*)(base + 24 * MB);   // [24,32) q conv; later Fo
    float* Fo    = (float*)(base + 24 * MB);
    float* q_t   = (float*)(base + 32 * MB);   // [32,40)
    float* k_t   = (float*)(base + 40 * MB);   // [40,48)
    float* v_t   = (float*)(base + 48 * MB);   // [48,56)
    char* SM = base + 56 * MB;
    float* xx_q      = (float*)(SM + 0);            // 256 KB
    float* cent      = (float*)(SM + 512 * 1024);   // 32 KB
    float* cc        = (float*)(SM + 576 * 1024);   // 1 KB
    int*   totals    = (int*)  (SM + 640 * 1024);   // 1 KB
    int*   asn       = (int*)  (SM + 704 * 1024);   // 256 KB
    int*   hist      = (int*)  (SM + 960 * 1024);   // 256 KB
    int*   chunkbase = (int*)  (SM + 1472 * 1024);  // 256 KB
    int*   perm      = (int*)  (SM + 1984 * 1024);  // 256 KB
    float* kd        = (float*)(SM + 2240 * 1024);  // 256 KB
    float* ksel      = (float*)(SM + 2496 * 1024);  // 512 KB
    float* vsel      = (float*)(SM + 3008 * 1024);  // 512 KB
    float* yln_q     = (float*)(base + 60 * MB);    // [60,68) q LN out

    // both LNs in one launch
    ln2_np<<<256, 64, 0, stream>>>(ctx, g_ctx, b_ctx, yln,
                                   qsrc, g_q, b_q, yln_q);
    // k rows exact SOP; v rows FMA (value path)
    conv_nl<16, 2><<<dim3(8, 16, 2), 256, 0, stream>>>(w_kv, 0, yln, kvbuf, 512);
    conv_fma<16, 2><<<dim3(8, 16, 2), 256, 0, stream>>>(w_kv, 256, yln, kvbuf, 512);
    // q conv exact SOP
    conv_nl<8, 2><<<dim3(8, 32, 2), 256, 0, stream>>>(w_q, 0, yln_q, qbuf, 256);
    // all three folds in one launch (q fold emits xx + cent/cc)
    fold3_np<<<768, 256, 0, stream>>>(kvbuf, qbuf, k_t, v_t, q_t, xx_q, cent, cc);

    for (int it = 0; it < 10; it++) {
        assign4p<<<256, 256, 0, stream>>>(q_t, xx_q, cent, cc, asn, hist);
        scan_chunks<<<256, 256, 0, stream>>>(hist, chunkbase, totals);
        scatter_v5<<<256, 256, 0, stream>>>(asn, chunkbase, totals, perm);
        sumk_v4<<<256, 256, 0, stream>>>(q_t, perm, totals, cent, cc);
    }

    kdist4p<<<256, 256, 0, stream>>>(k_t, cent, cc, kd);
    topk_v2<<<16, 256, 0, stream>>>(kd, k_t, v_t, ksel, vsel);
    attn_v3c<<<dim3(16, 16), 512, 0, stream>>>(q_t, ksel, vsel, att);
    unfold_kernel<<<dim3(64, 16), 256, 0, stream>>>(att, Fo);
    conv_fma<8, 2><<<dim3(8, 32, 2), 256, 0, stream>>>(w_out, 0, Fo, y32, 256);
    lnres_np<<<128, 64, 0, stream>>>(y32, g_out, b_out, gs, qsrc, (float*)d_out);
}

// Round 18
// 962.496 us; speedup vs baseline: 1.1833x; 1.0071x over previous
//
#include <hip/hip_runtime.h>
#include <math.h>

#define CDIM 256
#define LSEQ 4096
#define NBH 16
#define NPTS 65536
#define KC 256

__device__ __forceinline__ float fadd(float a, float b){ return __fadd_rn(a,b); }
__device__ __forceinline__ float fmul(float a, float b){ return __fmul_rn(a,b); }
__device__ __forceinline__ float fsub(float a, float b){ return __fsub_rn(a,b); }

// numpy contiguous n=32 float32 sum, AVX-512 npyv path (verified R5)
__device__ __forceinline__ float sum32_np(const float* e){
    float l[16];
    #pragma unroll
    for (int j = 0; j < 16; j++) l[j] = fadd(e[j], e[j + 16]);
    float t3[8];
    #pragma unroll
    for (int j = 0; j < 8; j++) t3[j] = fadd(l[j], l[j + 8]);
    float t6[4];
    #pragma unroll
    for (int j = 0; j < 4; j++) t6[j] = fadd(t3[j], t3[j + 4]);
    return fadd(fadd(t6[0], t6[2]), fadd(t6[1], t6[3]));
}

// ---------- both LayerNorms, one launch (numpy exact per position) --
__global__ __launch_bounds__(64) void ln2_np(
        const float* __restrict__ x0, const float* __restrict__ g0,
        const float* __restrict__ bt0, float* __restrict__ y0,
        const float* __restrict__ x1, const float* __restrict__ g1,
        const float* __restrict__ bt1, float* __restrict__ y1) {
    int gid = blockIdx.x * 64 + threadIdx.x;
    int which = gid >> 13;
    int r = gid & 8191;
    int b = r >> 12, l = r & 4095;
    const float* x  = which ? x1 : x0;
    const float* g  = which ? g1 : g0;
    const float* bt = which ? bt1 : bt0;
    float* y        = which ? y1 : y0;
    const float* xb = x + (size_t)b * CDIM * LSEQ + l;
    float s = 0.f;
    #pragma unroll 8
    for (int c = 0; c < 256; c++) s = fadd(s, xb[(size_t)c * LSEQ]);
    float mean = __fdiv_rn(s, 256.f);
    float s2 = 0.f;
    #pragma unroll 8
    for (int c = 0; c < 256; c++) {
        float d = fsub(xb[(size_t)c * LSEQ], mean);
        s2 = fadd(s2, fmul(d, d));
    }
    float var = __fdiv_rn(s2, 256.f);
    float den = fadd(__fsqrt_rn(var), 1e-6f);
    float* yb = y + (size_t)b * CDIM * LSEQ + l;
    #pragma unroll 4
    for (int c = 0; c < 256; c++) {
        float d = fsub(xb[(size_t)c * LSEQ], mean);
        yb[(size_t)c * LSEQ] = fadd(__fdiv_rn(fmul(g[c], d), den), bt[c]);
    }
}

// ---------- conv1x1, SOP exact (decision path: k, q) ----------------
template<int COT, int NL>
__global__ __launch_bounds__(256) void conv_nl(const float* __restrict__ W, int row0,
        const float* __restrict__ X, float* __restrict__ Y, int nrows) {
    __shared__ float ws[COT * 256];
    int tid = threadIdx.x;
    int l0 = blockIdx.x * (256 * NL) + tid;
    int o0 = blockIdx.y * COT;
    int b = blockIdx.z;
    {
        const float4* wb4 = (const float4*)(W + (size_t)(row0 + o0) * CDIM);
        float4* ws4 = (float4*)ws;
        for (int i = tid; i < COT * 64; i += 256) ws4[i] = wb4[i];
    }
    __syncthreads();
    const float* xb = X + (size_t)b * CDIM * LSEQ;
    float acc[COT][NL];
    #pragma unroll
    for (int oo = 0; oo < COT; oo++)
        #pragma unroll
        for (int i = 0; i < NL; i++) acc[oo][i] = 0.f;
    const float4* ws4 = (const float4*)ws;
    for (int c = 0; c < 256; c += 4) {
        float xv[NL][4];
        #pragma unroll
        for (int i = 0; i < NL; i++) {
            #pragma unroll
            for (int k = 0; k < 4; k++)
                xv[i][k] = xb[(size_t)(c + k) * LSEQ + l0 + i * 256];
        }
        #pragma unroll
        for (int oo = 0; oo < COT; oo++) {
            float4 w = ws4[(oo * 256 + c) >> 2];
            #pragma unroll
            for (int i = 0; i < NL; i++) {
                acc[oo][i] = fadd(acc[oo][i], fmul(w.x, xv[i][0]));
                acc[oo][i] = fadd(acc[oo][i], fmul(w.y, xv[i][1]));
                acc[oo][i] = fadd(acc[oo][i], fmul(w.z, xv[i][2]));
                acc[oo][i] = fadd(acc[oo][i], fmul(w.w, xv[i][3]));
            }
        }
    }
    #pragma unroll
    for (int oo = 0; oo < COT; oo++)
        #pragma unroll
        for (int i = 0; i < NL; i++)
            Y[((size_t)b * nrows + row0 + o0 + oo) * LSEQ + l0 + i * 256] = acc[oo][i];
}

// ---------- conv1x1, FMA (value path: v, out) -----------------------
template<int COT, int NL>
__global__ __launch_bounds__(256) void conv_fma(const float* __restrict__ W, int row0,
        const float* __restrict__ X, float* __restrict__ Y, int nrows) {
    __shared__ float ws[COT * 256];
    int tid = threadIdx.x;
    int l0 = blockIdx.x * (256 * NL) + tid;
    int o0 = blockIdx.y * COT;
    int b = blockIdx.z;
    {
        const float4* wb4 = (const float4*)(W + (size_t)(row0 + o0) * CDIM);
        float4* ws4 = (float4*)ws;
        for (int i = tid; i < COT * 64; i += 256) ws4[i] = wb4[i];
    }
    __syncthreads();
    const float* xb = X + (size_t)b * CDIM * LSEQ;
    float acc[COT][NL];
    #pragma unroll
    for (int oo = 0; oo < COT; oo++)
        #pragma unroll
        for (int i = 0; i < NL; i++) acc[oo][i] = 0.f;
    const float4* ws4 = (const float4*)ws;
    for (int c = 0; c < 256; c += 4) {
        float xv[NL][4];
        #pragma unroll
        for (int i = 0; i < NL; i++) {
            #pragma unroll
            for (int k = 0; k < 4; k++)
                xv[i][k] = xb[(size_t)(c + k) * LSEQ + l0 + i * 256];
        }
        #pragma unroll
        for (int oo = 0; oo < COT; oo++) {
            float4 w = ws4[(oo * 256 + c) >> 2];
            #pragma unroll
            for (int i = 0; i < NL; i++) {
                acc[oo][i] = __builtin_fmaf(w.x, xv[i][0], acc[oo][i]);
                acc[oo][i] = __builtin_fmaf(w.y, xv[i][1], acc[oo][i]);
                acc[oo][i] = __builtin_fmaf(w.z, xv[i][2], acc[oo][i]);
                acc[oo][i] = __builtin_fmaf(w.w, xv[i][3], acc[oo][i]);
            }
        }
    }
    #pragma unroll
    for (int oo = 0; oo < COT; oo++)
        #pragma unroll
        for (int i = 0; i < NL; i++)
            Y[((size_t)b * nrows + row0 + o0 + oo) * LSEQ + l0 + i * 256] = acc[oo][i];
}

// ---------- fold x3 (k norm, v plain, q norm+xx+cent/cc) ------------
__device__ __forceinline__ void fold_body(const float* __restrict__ src,
        int srcRows, int row0, int donorm, float* __restrict__ dst,
        float* __restrict__ xxout, float* __restrict__ centout,
        float* __restrict__ ccout, int p) {
    int bh = p >> 12, l = p & 4095;
    int b = bh >> 3, h = bh & 7;
    const float* sp = src + ((size_t)b * srcRows + row0 + h * 32) * LSEQ + l;
    float x[32];
    #pragma unroll
    for (int t = 0; t < 32; t++) x[t] = sp[(size_t)t * LSEQ];
    float4* dp4 = (float4*)(dst + (size_t)p * 32);
    if (donorm) {
        float ss = 0.f;
        #pragma unroll
        for (int t = 0; t < 32; t++) ss = fadd(ss, fmul(x[t], x[t]));
        float n = __fsqrt_rn(ss);
        float den = fmaxf(n, 1e-12f);
        #pragma unroll
        for (int t = 0; t < 32; t++) x[t] = __fdiv_rn(x[t], den);
    }
    #pragma unroll
    for (int t = 0; t < 8; t++)
        dp4[t] = make_float4(x[4*t], x[4*t+1], x[4*t+2], x[4*t+3]);
    if (xxout) {
        float e[32];
        #pragma unroll
        for (int t = 0; t < 32; t++) e[t] = fmul(x[t], x[t]);
        float xv = sum32_np(e);
        xxout[p] = xv;
        if (centout && p < KC) {
            float4* cp4 = (float4*)(centout + (size_t)p * 32);
            #pragma unroll
            for (int t = 0; t < 8; t++)
                cp4[t] = make_float4(x[4*t], x[4*t+1], x[4*t+2], x[4*t+3]);
            ccout[p] = xv;
        }
    }
}

__global__ __launch_bounds__(256) void fold3_np(const float* __restrict__ kvbuf,
        const float* __restrict__ qbuf, float* __restrict__ k_t,
        float* __restrict__ v_t, float* __restrict__ q_t,
        float* __restrict__ xx, float* __restrict__ cent, float* __restrict__ cc) {
    int blk = blockIdx.x, tid = threadIdx.x;
    if (blk < 256) {
        fold_body(kvbuf, 512, 0, 1, k_t, nullptr, nullptr, nullptr, blk * 256 + tid);
    } else if (blk < 512) {
        fold_body(kvbuf, 512, 256, 0, v_t, nullptr, nullptr, nullptr, (blk - 256) * 256 + tid);
    } else {
        fold_body(qbuf, 256, 0, 1, q_t, xx, cent, cc, (blk - 512) * 256 + tid);
    }
}

// ---------- argmin+hist: 4 pts/thread x quarter clusters (R16) ------
__global__ __launch_bounds__(256) void assign4p(const float* __restrict__ pts,
        const float* __restrict__ xx, const float* __restrict__ cent,
        const float* __restrict__ cc, int* __restrict__ asn, int* __restrict__ hist) {
    __shared__ float sc[8192];
    __shared__ float scc[256];
    __shared__ int bins[256];
    int tid = threadIdx.x, c = blockIdx.x;
    {
        const float4* c4 = (const float4*)cent;
        float4* s4 = (float4*)sc;
        for (int i = tid; i < 2048; i += 256) s4[i] = c4[i];
    }
    scc[tid] = cc[tid];
    bins[tid] = 0;
    __syncthreads();
    int pg = tid >> 2, quarter = tid & 3;
    int pb = c * 256 + pg * 4;
    float x[4][32];
    float xp[4];
    #pragma unroll
    for (int i = 0; i < 4; i++) {
        const float4* pp = (const float4*)(pts + (size_t)(pb + i) * 32);
        #pragma unroll
        for (int t = 0; t < 8; t++) {
            float4 f = pp[t];
            x[i][4*t] = f.x; x[i][4*t+1] = f.y; x[i][4*t+2] = f.z; x[i][4*t+3] = f.w;
        }
        xp[i] = xx[pb + i];
    }
    float bd[4] = {3.4e38f, 3.4e38f, 3.4e38f, 3.4e38f};
    int bj[4] = {0, 0, 0, 0};
    int jbase = quarter * 64;
    for (int jj = 0; jj < 64; jj++) {
        int j = jbase + jj;
        const float4* cj = (const float4*)(sc + j * 32);
        float w[32];
        #pragma unroll
        for (int t = 0; t < 8; t++) {
            float4 f = cj[t];
            w[4*t] = f.x; w[4*t+1] = f.y; w[4*t+2] = f.z; w[4*t+3] = f.w;
        }
        float sj = scc[j];
        #pragma unroll
        for (int i = 0; i < 4; i++) {
            float g = 0.f;
            #pragma unroll
            for (int t = 0; t < 32; t++) g = __builtin_fmaf(x[i][t], w[t], g);
            float d = fadd(fsub(xp[i], fmul(2.f, g)), sj);
            if (d < bd[i]) { bd[i] = d; bj[i] = j; }
        }
    }
    #pragma unroll
    for (int i = 0; i < 4; i++) {
        float ob; int oj;
        ob = __shfl_xor(bd[i], 1); oj = __shfl_xor(bj[i], 1);
        if (ob < bd[i]) { bd[i] = ob; bj[i] = oj; }
        ob = __shfl_xor(bd[i], 2); oj = __shfl_xor(bj[i], 2);
        if (ob < bd[i]) { bd[i] = ob; bj[i] = oj; }
    }
    if (quarter == 0) {
        #pragma unroll
        for (int i = 0; i < 4; i++) {
            asn[pb + i] = bj[i];
            atomicAdd(&bins[bj[i]], 1);
        }
    }
    __syncthreads();
    hist[c * 256 + tid] = bins[tid];
}

// ---------- per-cluster prefix over 256 chunks ----------------------
__global__ __launch_bounds__(256) void scan_chunks(const int* __restrict__ hist,
        int* __restrict__ chunkbase, int* __restrict__ totals) {
    __shared__ int a[256];
    int j = blockIdx.x, c = threadIdx.x;
    a[c] = hist[(size_t)c * 256 + j];
    __syncthreads();
    for (int d = 1; d < 256; d <<= 1) {
        int v = a[c];
        int u = (c >= d) ? a[c - d] : 0;
        __syncthreads();
        a[c] = v + u;
        __syncthreads();
    }
    chunkbase[(size_t)c * 256 + j] = (c == 0) ? 0 : a[c - 1];
    if (c == 255) totals[j] = a[255];
}

// ---------- scatter: parallel cbase scan + stable rank --------------
__global__ __launch_bounds__(256) void scatter_v5(const int* __restrict__ asn,
        const int* __restrict__ chunkbase, const int* __restrict__ totals,
        int* __restrict__ perm) {
    __shared__ int cb[256];
    __shared__ int al[256];
    int c = blockIdx.x, tid = threadIdx.x;
    cb[tid] = totals[tid];
    al[tid] = asn[c * 256 + tid];
    __syncthreads();
    for (int d = 1; d < 256; d <<= 1) {
        int v = cb[tid];
        int u = (tid >= d) ? cb[tid - d] : 0;
        __syncthreads();
        cb[tid] = v + u;
        __syncthreads();
    }
    int my = al[tid];
    int base = (my == 0) ? 0 : cb[my - 1];
    int r = 0;
    for (int i = 0; i < tid; i++) r += (al[i] == my) ? 1 : 0;
    perm[base + chunkbase[(size_t)c * 256 + my] + r] = c * 256 + tid;
}

// ---------- ordered sum + update + cc (parallel cbase scan) ---------
#define STILE 128
__global__ __launch_bounds__(256) void sumk_v4(const float* __restrict__ pts,
        const int* __restrict__ perm, const int* __restrict__ totals,
        float* __restrict__ cent, float* __restrict__ cc) {
    __shared__ int cb[256];
    __shared__ float buf[2][STILE][32];
    int j = blockIdx.x, tid = threadIdx.x;
    cb[tid] = totals[tid];
    __syncthreads();
    for (int d = 1; d < 256; d <<= 1) {
        int v = cb[tid];
        int u = (tid >= d) ? cb[tid - d] : 0;
        __syncthreads();
        cb[tid] = v + u;
        __syncthreads();
    }
    int base = (j == 0) ? 0 : cb[j - 1];
    int n = totals[j];
    int t = tid & 31, r0 = tid >> 5;
    for (int r = r0; r < STILE; r += 8) {
        if (r < n) buf[0][r][t] = pts[(size_t)perm[base + r] * 32 + t];
    }
    __syncthreads();
    float s = 0.f;
    int b = 0;
    for (int i0 = 0; i0 < n; i0 += STILE, b ^= 1) {
        int nx = i0 + STILE;
        if (nx < n) {
            for (int r = r0; r < STILE; r += 8) {
                int g = nx + r;
                if (g < n) buf[b ^ 1][r][t] = pts[(size_t)perm[base + g] * 32 + t];
            }
        }
        if (tid < 32) {
            int m = n - i0; if (m > STILE) m = STILE;
            int i = 0;
            for (; i + 4 <= m; i += 4) {
                s = fadd(s, buf[b][i][tid]);
                s = fadd(s, buf[b][i + 1][tid]);
                s = fadd(s, buf[b][i + 2][tid]);
                s = fadd(s, buf[b][i + 3][tid]);
            }
            for (; i < m; i++) s = fadd(s, buf[b][i][tid]);
        }
        __syncthreads();
    }
    if (tid < 32) {
        float v;
        if (n > 0) {
            v = __fdiv_rn(s, (float)n);
            cent[(size_t)j * 32 + tid] = v;
        } else {
            v = cent[(size_t)j * 32 + tid];
        }
        float e = fmul(v, v);
        e = fadd(e, __shfl_xor(e, 16));
        e = fadd(e, __shfl_xor(e, 8));
        e = fadd(e, __shfl_xor(e, 4));
        e = fadd(e, __shfl_xor(e, 2));
        e = fadd(e, __shfl_xor(e, 1));
        if (tid == 0) cc[j] = e;
    }
}

// ---------- key assign + L1: 4 pts/thread x quarter clusters --------
__global__ __launch_bounds__(256) void kdist4p(const float* __restrict__ pts,
        const float* __restrict__ cent, const float* __restrict__ cc,
        float* __restrict__ kd) {
    __shared__ float sc[8192];
    __shared__ float scc[256];
    int tid = threadIdx.x, c = blockIdx.x;
    {
        const float4* c4 = (const float4*)cent;
        float4* s4 = (float4*)sc;
        for (int i = tid; i < 2048; i += 256) s4[i] = c4[i];
    }
    scc[tid] = cc[tid];
    __syncthreads();
    int pg = tid >> 2, quarter = tid & 3;
    int pb = c * 256 + pg * 4;
    float x[4][32];
    float xp[4];
    #pragma unroll
    for (int i = 0; i < 4; i++) {
        const float4* pp = (const float4*)(pts + (size_t)(pb + i) * 32);
        #pragma unroll
        for (int t = 0; t < 8; t++) {
            float4 f = pp[t];
            x[i][4*t] = f.x; x[i][4*t+1] = f.y; x[i][4*t+2] = f.z; x[i][4*t+3] = f.w;
        }
        float e[32];
        #pragma unroll
        for (int t = 0; t < 32; t++) e[t] = fmul(x[i][t], x[i][t]);
        xp[i] = sum32_np(e);
    }
    float bd[4] = {3.4e38f, 3.4e38f, 3.4e38f, 3.4e38f};
    int bj[4] = {0, 0, 0, 0};
    int jbase = quarter * 64;
    for (int jj = 0; jj < 64; jj++) {
        int j = jbase + jj;
        const float4* cj = (const float4*)(sc + j * 32);
        float w[32];
        #pragma unroll
        for (int t = 0; t < 8; t++) {
            float4 f = cj[t];
            w[4*t] = f.x; w[4*t+1] = f.y; w[4*t+2] = f.z; w[4*t+3] = f.w;
        }
        float sj = scc[j];
        #pragma unroll
        for (int i = 0; i < 4; i++) {
            float g = 0.f;
            #pragma unroll
            for (int t = 0; t < 32; t++) g = __builtin_fmaf(x[i][t], w[t], g);
            float d = fadd(fsub(xp[i], fmul(2.f, g)), sj);
            if (d < bd[i]) { bd[i] = d; bj[i] = j; }
        }
    }
    #pragma unroll
    for (int i = 0; i < 4; i++) {
        float ob; int oj;
        ob = __shfl_xor(bd[i], 1); oj = __shfl_xor(bj[i], 1);
        if (ob < bd[i]) { bd[i] = ob; bj[i] = oj; }
        ob = __shfl_xor(bd[i], 2); oj = __shfl_xor(bj[i], 2);
        if (ob < bd[i]) { bd[i] = ob; bj[i] = oj; }
    }
    if (quarter == 0) {
        #pragma unroll
        for (int i = 0; i < 4; i++) {
            const float* cb = &sc[bj[i] * 32];
            float e[32];
            #pragma unroll
            for (int t = 0; t < 32; t++) e[t] = fabsf(fsub(cb[t], x[i][t]));
            kd[pb + i] = sum32_np(e);
        }
    }
}

// ---------- top-256 via radix select (exact stable set) + gather ----
__global__ __launch_bounds__(256) void topk_v2(const float* __restrict__ kd,
        const float* __restrict__ k_t, const float* __restrict__ v_t,
        float* __restrict__ ksel, float* __restrict__ vsel) {
    __shared__ unsigned uv[4096];
    __shared__ int hist[256];
    __shared__ unsigned s_prefix;
    __shared__ int s_rem;
    __shared__ int sc1[256];
    __shared__ int out_src[256];
    int bh = blockIdx.x, tid = threadIdx.x;
    for (int i = tid; i < 4096; i += 256) uv[i] = __float_as_uint(kd[bh * 4096 + i]);
    if (tid == 0) { s_prefix = 0u; s_rem = 256; }
    out_src[tid] = 0;
    __syncthreads();
    for (int pass = 0; pass < 4; pass++) {
        int shift = 24 - 8 * pass;
        hist[tid] = 0;
        __syncthreads();
        unsigned pfx = s_prefix;
        for (int i = tid; i < 4096; i += 256) {
            unsigned u = uv[i];
            bool in = (pass == 0) || ((u >> (shift + 8)) == (pfx >> (shift + 8)));
            if (in) atomicAdd(&hist[(u >> shift) & 255], 1);
        }
        __syncthreads();
        if (tid == 0) {
            int rem = s_rem, cum = 0, b;
            for (b = 255; b >= 0; b--) {
                if (cum + hist[b] >= rem) break;
                cum += hist[b];
            }
            s_rem = rem - cum;
            s_prefix = s_prefix | ((unsigned)b << shift);
        }
        __syncthreads();
    }
    unsigned T = s_prefix;
    int r = s_rem;
    int base_i = tid * 16;
    int ec = 0;
    for (int q = 0; q < 16; q++) ec += (uv[base_i + q] == T) ? 1 : 0;
    sc1[tid] = ec;
    __syncthreads();
    for (int d = 1; d < 256; d <<= 1) {
        int t0 = sc1[tid];
        int u0 = (tid >= d) ? sc1[tid - d] : 0;
        __syncthreads();
        sc1[tid] = t0 + u0;
        __syncthreads();
    }
    int erank = (tid == 0) ? 0 : sc1[tid - 1];
    __syncthreads();
    bool incl[16];
    int ic = 0;
    for (int q = 0; q < 16; q++) {
        unsigned u = uv[base_i + q];
        bool inc;
        if (u > T) inc = true;
        else if (u == T) { inc = (erank < r); erank++; }
        else inc = false;
        incl[q] = inc;
        ic += inc ? 1 : 0;
    }
    sc1[tid] = ic;
    __syncthreads();
    for (int d = 1; d < 256; d <<= 1) {
        int t0 = sc1[tid];
        int u0 = (tid >= d) ? sc1[tid - d] : 0;
        __syncthreads();
        sc1[tid] = t0 + u0;
        __syncthreads();
    }
    int pos = (tid == 0) ? 0 : sc1[tid - 1];
    for (int q = 0; q < 16; q++) {
        if (incl[q]) out_src[pos++] = base_i + q;
    }
    __syncthreads();
    for (int e = tid; e < 256 * 32; e += 256) {
        int jj = e >> 5, t = e & 31;
        int src = out_src[jj];
        ksel[(size_t)bh * 8192 + e] = k_t[((size_t)bh * 4096 + src) * 32 + t];
        vsel[(size_t)bh * 8192 + e] = v_t[((size_t)bh * 4096 + src) * 32 + t];
    }
}

// ---------- attention v3d: 4 queries per lane-quad ------------------
// 256 thr x 256 blocks; lane quad: slice=key half (bit0), dh=dim half
// (bit1). Each lane: 4 queries x 16-dim fragment. 1024 LDS reads/query
// (half of v3b). Value path: re-association safe.
#define HPAD 4112
__global__ __launch_bounds__(256) void attn_v3d(const float* __restrict__ q_t,
        const float* __restrict__ ksel, const float* __restrict__ vsel,
        float* __restrict__ out) {
    __shared__ float sk[2 * HPAD];
    __shared__ float sv[2 * HPAD];
    int bh = blockIdx.y, tid = threadIdx.x;
    {
        const float4* gk = (const float4*)(ksel + (size_t)bh * 8192);
        const float4* gv = (const float4*)(vsel + (size_t)bh * 8192);
        for (int i = tid; i < 2048; i += 256) {
            int h = i >> 10, idx = i & 1023;
            ((float4*)(sk + h * HPAD))[idx] = gk[i];
            ((float4*)(sv + h * HPAD))[idx] = gv[i];
        }
    }
    __syncthreads();
    int grp = tid >> 2;
    int slice = tid & 1;
    int dh = (tid >> 1) & 1;
    int p0 = bh * 4096 + blockIdx.x * 256 + grp * 4;
    float q[4][16];
    #pragma unroll
    for (int i = 0; i < 4; i++) {
        const float4* qp = (const float4*)(q_t + (size_t)(p0 + i) * 32 + dh * 16);
        #pragma unroll
        for (int t = 0; t < 4; t++) {
            float4 f = qp[t];
            q[i][4*t] = f.x; q[i][4*t+1] = f.y; q[i][4*t+2] = f.z; q[i][4*t+3] = f.w;
        }
    }
    float o[4][16];
    #pragma unroll
    for (int i = 0; i < 4; i++)
        #pragma unroll
        for (int t = 0; t < 16; t++) o[i][t] = 0.f;
    float ls[4] = {0.f, 0.f, 0.f, 0.f};
    const float* kb = sk + slice * HPAD + dh * 16;
    const float* vb = sv + slice * HPAD + dh * 16;
    for (int j = 0; j < 128; j++) {
        float kf[16];
        #pragma unroll
        for (int t = 0; t < 4; t++) {
            float4 f = *(const float4*)(kb + j * 32 + t * 4);
            kf[4*t] = f.x; kf[4*t+1] = f.y; kf[4*t+2] = f.z; kf[4*t+3] = f.w;
        }
        float ps[4];
        #pragma unroll
        for (int i = 0; i < 4; i++) {
            float a = 0.f, b2 = 0.f, c2 = 0.f, d2 = 0.f;
            #pragma unroll
            for (int t = 0; t < 4; t++) {
                a  += q[i][4*t]   * kf[4*t];
                b2 += q[i][4*t+1] * kf[4*t+1];
                c2 += q[i][4*t+2] * kf[4*t+2];
                d2 += q[i][4*t+3] * kf[4*t+3];
            }
            ps[i] = (a + b2) + (c2 + d2);
        }
        #pragma unroll
        for (int i = 0; i < 4; i++) ps[i] += __shfl_xor(ps[i], 2);  // dim halves
        float w[4];
        #pragma unroll
        for (int i = 0; i < 4; i++) {
            w[i] = __expf(ps[i] - 1.0f);   // s <= 1 (unit vectors)
            ls[i] += w[i];
        }
        float vf[16];
        #pragma unroll
        for (int t = 0; t < 4; t++) {
            float4 f = *(const float4*)(vb + j * 32 + t * 4);
            vf[4*t] = f.x; vf[4*t+1] = f.y; vf[4*t+2] = f.z; vf[4*t+3] = f.w;
        }
        #pragma unroll
        for (int i = 0; i < 4; i++)
            #pragma unroll
            for (int t = 0; t < 16; t++) o[i][t] += w[i] * vf[t];
    }
    // combine key-half slices
    #pragma unroll
    for (int i = 0; i < 4; i++) {
        #pragma unroll
        for (int t = 0; t < 16; t++) o[i][t] += __shfl_xor(o[i][t], 1);
        ls[i] += __shfl_xor(ls[i], 1);
    }
    if (slice == 0) {
        #pragma unroll
        for (int i = 0; i < 4; i++) {
            float inv = 1.f / ls[i];
            float4* op = (float4*)(out + (size_t)(p0 + i) * 32 + dh * 16);
            #pragma unroll
            for (int t = 0; t < 4; t++)
                op[t] = make_float4(o[i][4*t]*inv, o[i][4*t+1]*inv,
                                    o[i][4*t+2]*inv, o[i][4*t+3]*inv);
        }
    }
}

// ---------- unfold (bh,L,32) -> (b,256,L) ---------------------------
__global__ __launch_bounds__(256) void unfold_kernel(const float* __restrict__ att,
        float* __restrict__ Fo) {
    __shared__ float tbuf[32][65];
    int bh = blockIdx.y, l0 = blockIdx.x * 64;
    int b = bh >> 3, h = bh & 7;
    int tid = threadIdx.x;
    #pragma unroll
    for (int r = 0; r < 8; r++) {
        int e = r * 256 + tid;
        int l = e >> 5, d = e & 31;
        tbuf[d][l] = att[((size_t)bh * 4096 + l0 + l) * 32 + d];
    }
    __syncthreads();
    #pragma unroll
    for (int r = 0; r < 8; r++) {
        int e = r * 256 + tid;
        int d = e >> 6, l = e & 63;
        Fo[((size_t)b * 256 + h * 32 + d) * LSEQ + l0 + l] = tbuf[d][l];
    }
}

// ---------- final LN + scale + residual (numpy orders) --------------
__global__ __launch_bounds__(64) void lnres_np(const float* __restrict__ x,
        const float* __restrict__ g, const float* __restrict__ bt,
        const float* __restrict__ gs, const float* __restrict__ qsrc,
        float* __restrict__ y) {
    int gid = blockIdx.x * 64 + threadIdx.x;
    int b = gid >> 12, l = gid & 4095;
    const float* xb = x + (size_t)b * CDIM * LSEQ + l;
    float s = 0.f;
    #pragma unroll 8
    for (int c = 0; c < 256; c++) s = fadd(s, xb[(size_t)c * LSEQ]);
    float mean = __fdiv_rn(s, 256.f);
    float s2 = 0.f;
    #pragma unroll 8
    for (int c = 0; c < 256; c++) {
        float d = fsub(xb[(size_t)c * LSEQ], mean);
        s2 = fadd(s2, fmul(d, d));
    }
    float var = __fdiv_rn(s2, 256.f);
    float den = fadd(__fsqrt_rn(var), 1e-6f);
    float scale = gs[0];
    const float* qb = qsrc + (size_t)b * CDIM * LSEQ + l;
    float* yb = y + (size_t)b * CDIM * LSEQ + l;
    #pragma unroll 4
    for (int c = 0; c < 256; c++) {
        float d = fsub(xb[(size_t)c * LSEQ], mean);
        float r = fadd(__fdiv_rn(fmul(g[c], d), den), bt[c]);
        yb[(size_t)c * LSEQ] = fadd(fmul(scale, r), qb[(size_t)c * LSEQ]);
    }
}

// ==================================================================
extern "C" void kernel_launch(void* const* d_in, const int* in_sizes, int n_in,
                              void* d_out, int out_size, void* d_ws, size_t ws_size,
                              hipStream_t stream) {
    const float* qsrc   = (const float*)d_in[0];
    const float* ctx    = (const float*)d_in[1];
    const float* w_q    = (const float*)d_in[2];
    const float* w_kv   = (const float*)d_in[3];
    const float* w_out  = (const float*)d_in[4];
    const float* g_ctx  = (const float*)d_in[5];
    const float* b_ctx  = (const float*)d_in[6];
    const float* g_q    = (const float*)d_in[7];
    const float* b_q    = (const float*)d_in[8];
    const float* g_out  = (const float*)d_in[9];
    const float* b_out  = (const float*)d_in[10];
    const float* gs     = (const float*)d_in[11];

    char* base = (char*)d_ws;
    const size_t MB = 1024 * 1024;
    float* yln   = (float*)base;               // [0,8) ctx LN; later att
    float* att   = (float*)base;
    float* kvbuf = (float*)(base + 8 * MB);    // [8,24) kv conv; later y32 [8,16)
    float* y32   = (float*)(base + 8 * MB);
    float* qbuf  = (float*)(base + 24 * MB);   // [24,32) q conv; later Fo
    float* Fo    = (float*)(base + 24 * MB);
    float* q_t   = (float*)(base + 32 * MB);   // [32,40)
    float* k_t   = (float*)(base + 40 * MB);   // [40,48)
    float* v_t   = (float*)(base + 48 * MB);   // [48,56)
    char* SM = base + 56 * MB;
    float* xx_q      = (float*)(SM + 0);            // 256 KB
    float* cent      = (float*)(SM + 512 * 1024);   // 32 KB
    float* cc        = (float*)(SM + 576 * 1024);   // 1 KB
    int*   totals    = (int*)  (SM + 640 * 1024);   // 1 KB
    int*   asn       = (int*)  (SM + 704 * 1024);   // 256 KB
    int*   hist      = (int*)  (SM + 960 * 1024);   // 256 KB
    int*   chunkbase = (int*)  (SM + 1472 * 1024);  // 256 KB
    int*   perm      = (int*)  (SM + 1984 * 1024);  // 256 KB
    float* kd        = (float*)(SM + 2240 * 1024);  // 256 KB
    float* ksel      = (float*)(SM + 2496 * 1024);  // 512 KB
    float* vsel      = (float*)(SM + 3008 * 1024);  // 512 KB
    float* yln_q     = (float*)(base + 60 * MB);    // [60,68) q LN out

    ln2_np<<<256, 64, 0, stream>>>(ctx, g_ctx, b_ctx, yln,
                                   qsrc, g_q, b_q, yln_q);
    conv_nl<16, 2><<<dim3(8, 16, 2), 256, 0, stream>>>(w_kv, 0, yln, kvbuf, 512);
    conv_fma<16, 2><<<dim3(8, 16, 2), 256, 0, stream>>>(w_kv, 256, yln, kvbuf, 512);
    conv_nl<8, 2><<<dim3(8, 32, 2), 256, 0, stream>>>(w_q, 0, yln_q, qbuf, 256);
    fold3_np<<<768, 256, 0, stream>>>(kvbuf, qbuf, k_t, v_t, q_t, xx_q, cent, cc);

    for (int it = 0; it < 10; it++) {
        assign4p<<<256, 256, 0, stream>>>(q_t, xx_q, cent, cc, asn, hist);
        scan_chunks<<<256, 256, 0, stream>>>(hist, chunkbase, totals);
        scatter_v5<<<256, 256, 0, stream>>>(asn, chunkbase, totals, perm);
        sumk_v4<<<256, 256, 0, stream>>>(q_t, perm, totals, cent, cc);
    }

    kdist4p<<<256, 256, 0, stream>>>(k_t, cent, cc, kd);
    topk_v2<<<16, 256, 0, stream>>>(kd, k_t, v_t, ksel, vsel);
    attn_v3d<<<dim3(16, 16), 256, 0, stream>>>(q_t, ksel, vsel, att);
    unfold_kernel<<<dim3(64, 16), 256, 0, stream>>>(att, Fo);
    conv_fma<8, 2><<<dim3(8, 32, 2), 256, 0, stream>>>(w_out, 0, Fo, y32, 256);
    lnres_np<<<128, 64, 0, stream>>>(y32, g_out, b_out, gs, qsrc, (float*)d_out);
}

// Round 19
// 941.494 us; speedup vs baseline: 1.2097x; 1.0223x over previous
//
#include <hip/hip_runtime.h>
#include <math.h>

#define CDIM 256
#define LSEQ 4096
#define NBH 16
#define NPTS 65536
#define KC 256

__device__ __forceinline__ float fadd(float a, float b){ return __fadd_rn(a,b); }
__device__ __forceinline__ float fmul(float a, float b){ return __fmul_rn(a,b); }
__device__ __forceinline__ float fsub(float a, float b){ return __fsub_rn(a,b); }

// numpy contiguous n=32 float32 sum, AVX-512 npyv path (verified R5)
__device__ __forceinline__ float sum32_np(const float* e){
    float l[16];
    #pragma unroll
    for (int j = 0; j < 16; j++) l[j] = fadd(e[j], e[j + 16]);
    float t3[8];
    #pragma unroll
    for (int j = 0; j < 8; j++) t3[j] = fadd(l[j], l[j + 8]);
    float t6[4];
    #pragma unroll
    for (int j = 0; j < 4; j++) t6[j] = fadd(t3[j], t3[j + 4]);
    return fadd(fadd(t6[0], t6[2]), fadd(t6[1], t6[3]));
}

// ---------- both LayerNorms, one launch (numpy exact per position) --
__global__ __launch_bounds__(64) void ln2_np(
        const float* __restrict__ x0, const float* __restrict__ g0,
        const float* __restrict__ bt0, float* __restrict__ y0,
        const float* __restrict__ x1, const float* __restrict__ g1,
        const float* __restrict__ bt1, float* __restrict__ y1) {
    int gid = blockIdx.x * 64 + threadIdx.x;
    int which = gid >> 13;
    int r = gid & 8191;
    int b = r >> 12, l = r & 4095;
    const float* x  = which ? x1 : x0;
    const float* g  = which ? g1 : g0;
    const float* bt = which ? bt1 : bt0;
    float* y        = which ? y1 : y0;
    const float* xb = x + (size_t)b * CDIM * LSEQ + l;
    float s = 0.f;
    #pragma unroll 8
    for (int c = 0; c < 256; c++) s = fadd(s, xb[(size_t)c * LSEQ]);
    float mean = __fdiv_rn(s, 256.f);
    float s2 = 0.f;
    #pragma unroll 8
    for (int c = 0; c < 256; c++) {
        float d = fsub(xb[(size_t)c * LSEQ], mean);
        s2 = fadd(s2, fmul(d, d));
    }
    float var = __fdiv_rn(s2, 256.f);
    float den = fadd(__fsqrt_rn(var), 1e-6f);
    float* yb = y + (size_t)b * CDIM * LSEQ + l;
    #pragma unroll 4
    for (int c = 0; c < 256; c++) {
        float d = fsub(xb[(size_t)c * LSEQ], mean);
        yb[(size_t)c * LSEQ] = fadd(__fdiv_rn(fmul(g[c], d), den), bt[c]);
    }
}

// ---------- conv kv: COT=8, NL=4 (float4), k rows SOP / v rows FMA --
// grid (4, 64, 2): blockIdx.y<32 -> k (exact SOP), else v (FMA, value).
__global__ __launch_bounds__(256) void conv_kv(const float* __restrict__ W,
        const float* __restrict__ X, float* __restrict__ Y) {
    __shared__ float ws[8 * 256];
    int tid = threadIdx.x;
    int l0 = blockIdx.x * 1024 + tid * 4;
    int o0 = blockIdx.y * 8;
    int b = blockIdx.z;
    {
        const float4* wb4 = (const float4*)(W + (size_t)o0 * CDIM);
        float4* ws4 = (float4*)ws;
        for (int i = tid; i < 8 * 64; i += 256) ws4[i] = wb4[i];
    }
    __syncthreads();
    const float* xb = X + (size_t)b * CDIM * LSEQ;
    float acc[8][4];
    #pragma unroll
    for (int oo = 0; oo < 8; oo++)
        #pragma unroll
        for (int i = 0; i < 4; i++) acc[oo][i] = 0.f;
    const float4* ws4 = (const float4*)ws;
    if (blockIdx.y < 32) {   // k rows: exact SOP, c ascending
        for (int c = 0; c < 256; c += 4) {
            float4 x0q = *(const float4*)(xb + (size_t)(c + 0) * LSEQ + l0);
            float4 x1q = *(const float4*)(xb + (size_t)(c + 1) * LSEQ + l0);
            float4 x2q = *(const float4*)(xb + (size_t)(c + 2) * LSEQ + l0);
            float4 x3q = *(const float4*)(xb + (size_t)(c + 3) * LSEQ + l0);
            #pragma unroll
            for (int oo = 0; oo < 8; oo++) {
                float4 w = ws4[(oo * 256 + c) >> 2];
                acc[oo][0] = fadd(acc[oo][0], fmul(w.x, x0q.x));
                acc[oo][0] = fadd(acc[oo][0], fmul(w.y, x1q.x));
                acc[oo][0] = fadd(acc[oo][0], fmul(w.z, x2q.x));
                acc[oo][0] = fadd(acc[oo][0], fmul(w.w, x3q.x));
                acc[oo][1] = fadd(acc[oo][1], fmul(w.x, x0q.y));
                acc[oo][1] = fadd(acc[oo][1], fmul(w.y, x1q.y));
                acc[oo][1] = fadd(acc[oo][1], fmul(w.z, x2q.y));
                acc[oo][1] = fadd(acc[oo][1], fmul(w.w, x3q.y));
                acc[oo][2] = fadd(acc[oo][2], fmul(w.x, x0q.z));
                acc[oo][2] = fadd(acc[oo][2], fmul(w.y, x1q.z));
                acc[oo][2] = fadd(acc[oo][2], fmul(w.z, x2q.z));
                acc[oo][2] = fadd(acc[oo][2], fmul(w.w, x3q.z));
                acc[oo][3] = fadd(acc[oo][3], fmul(w.x, x0q.w));
                acc[oo][3] = fadd(acc[oo][3], fmul(w.y, x1q.w));
                acc[oo][3] = fadd(acc[oo][3], fmul(w.z, x2q.w));
                acc[oo][3] = fadd(acc[oo][3], fmul(w.w, x3q.w));
            }
        }
    } else {                 // v rows: FMA (value path)
        for (int c = 0; c < 256; c += 4) {
            float4 x0q = *(const float4*)(xb + (size_t)(c + 0) * LSEQ + l0);
            float4 x1q = *(const float4*)(xb + (size_t)(c + 1) * LSEQ + l0);
            float4 x2q = *(const float4*)(xb + (size_t)(c + 2) * LSEQ + l0);
            float4 x3q = *(const float4*)(xb + (size_t)(c + 3) * LSEQ + l0);
            #pragma unroll
            for (int oo = 0; oo < 8; oo++) {
                float4 w = ws4[(oo * 256 + c) >> 2];
                acc[oo][0] = __builtin_fmaf(w.x, x0q.x, acc[oo][0]);
                acc[oo][0] = __builtin_fmaf(w.y, x1q.x, acc[oo][0]);
                acc[oo][0] = __builtin_fmaf(w.z, x2q.x, acc[oo][0]);
                acc[oo][0] = __builtin_fmaf(w.w, x3q.x, acc[oo][0]);
                acc[oo][1] = __builtin_fmaf(w.x, x0q.y, acc[oo][1]);
                acc[oo][1] = __builtin_fmaf(w.y, x1q.y, acc[oo][1]);
                acc[oo][1] = __builtin_fmaf(w.z, x2q.y, acc[oo][1]);
                acc[oo][1] = __builtin_fmaf(w.w, x3q.y, acc[oo][1]);
                acc[oo][2] = __builtin_fmaf(w.x, x0q.z, acc[oo][2]);
                acc[oo][2] = __builtin_fmaf(w.y, x1q.z, acc[oo][2]);
                acc[oo][2] = __builtin_fmaf(w.z, x2q.z, acc[oo][2]);
                acc[oo][2] = __builtin_fmaf(w.w, x3q.z, acc[oo][2]);
                acc[oo][3] = __builtin_fmaf(w.x, x0q.w, acc[oo][3]);
                acc[oo][3] = __builtin_fmaf(w.y, x1q.w, acc[oo][3]);
                acc[oo][3] = __builtin_fmaf(w.z, x2q.w, acc[oo][3]);
                acc[oo][3] = __builtin_fmaf(w.w, x3q.w, acc[oo][3]);
            }
        }
    }
    #pragma unroll
    for (int oo = 0; oo < 8; oo++)
        *(float4*)(Y + ((size_t)b * 512 + o0 + oo) * LSEQ + l0) =
            make_float4(acc[oo][0], acc[oo][1], acc[oo][2], acc[oo][3]);
}

// ---------- conv 256-row: COT=8, NL=4; EXACT -> SOP else FMA --------
template<bool EXACT>
__global__ __launch_bounds__(256) void conv_q8(const float* __restrict__ W,
        const float* __restrict__ X, float* __restrict__ Y) {
    __shared__ float ws[8 * 256];
    int tid = threadIdx.x;
    int l0 = blockIdx.x * 1024 + tid * 4;
    int o0 = blockIdx.y * 8;
    int b = blockIdx.z;
    {
        const float4* wb4 = (const float4*)(W + (size_t)o0 * CDIM);
        float4* ws4 = (float4*)ws;
        for (int i = tid; i < 8 * 64; i += 256) ws4[i] = wb4[i];
    }
    __syncthreads();
    const float* xb = X + (size_t)b * CDIM * LSEQ;
    float acc[8][4];
    #pragma unroll
    for (int oo = 0; oo < 8; oo++)
        #pragma unroll
        for (int i = 0; i < 4; i++) acc[oo][i] = 0.f;
    const float4* ws4 = (const float4*)ws;
    for (int c = 0; c < 256; c += 4) {
        float4 x0q = *(const float4*)(xb + (size_t)(c + 0) * LSEQ + l0);
        float4 x1q = *(const float4*)(xb + (size_t)(c + 1) * LSEQ + l0);
        float4 x2q = *(const float4*)(xb + (size_t)(c + 2) * LSEQ + l0);
        float4 x3q = *(const float4*)(xb + (size_t)(c + 3) * LSEQ + l0);
        #pragma unroll
        for (int oo = 0; oo < 8; oo++) {
            float4 w = ws4[(oo * 256 + c) >> 2];
            if (EXACT) {
                acc[oo][0] = fadd(acc[oo][0], fmul(w.x, x0q.x));
                acc[oo][0] = fadd(acc[oo][0], fmul(w.y, x1q.x));
                acc[oo][0] = fadd(acc[oo][0], fmul(w.z, x2q.x));
                acc[oo][0] = fadd(acc[oo][0], fmul(w.w, x3q.x));
                acc[oo][1] = fadd(acc[oo][1], fmul(w.x, x0q.y));
                acc[oo][1] = fadd(acc[oo][1], fmul(w.y, x1q.y));
                acc[oo][1] = fadd(acc[oo][1], fmul(w.z, x2q.y));
                acc[oo][1] = fadd(acc[oo][1], fmul(w.w, x3q.y));
                acc[oo][2] = fadd(acc[oo][2], fmul(w.x, x0q.z));
                acc[oo][2] = fadd(acc[oo][2], fmul(w.y, x1q.z));
                acc[oo][2] = fadd(acc[oo][2], fmul(w.z, x2q.z));
                acc[oo][2] = fadd(acc[oo][2], fmul(w.w, x3q.z));
                acc[oo][3] = fadd(acc[oo][3], fmul(w.x, x0q.w));
                acc[oo][3] = fadd(acc[oo][3], fmul(w.y, x1q.w));
                acc[oo][3] = fadd(acc[oo][3], fmul(w.z, x2q.w));
                acc[oo][3] = fadd(acc[oo][3], fmul(w.w, x3q.w));
            } else {
                acc[oo][0] = __builtin_fmaf(w.x, x0q.x, acc[oo][0]);
                acc[oo][0] = __builtin_fmaf(w.y, x1q.x, acc[oo][0]);
                acc[oo][0] = __builtin_fmaf(w.z, x2q.x, acc[oo][0]);
                acc[oo][0] = __builtin_fmaf(w.w, x3q.x, acc[oo][0]);
                acc[oo][1] = __builtin_fmaf(w.x, x0q.y, acc[oo][1]);
                acc[oo][1] = __builtin_fmaf(w.y, x1q.y, acc[oo][1]);
                acc[oo][1] = __builtin_fmaf(w.z, x2q.y, acc[oo][1]);
                acc[oo][1] = __builtin_fmaf(w.w, x3q.y, acc[oo][1]);
                acc[oo][2] = __builtin_fmaf(w.x, x0q.z, acc[oo][2]);
                acc[oo][2] = __builtin_fmaf(w.y, x1q.z, acc[oo][2]);
                acc[oo][2] = __builtin_fmaf(w.z, x2q.z, acc[oo][2]);
                acc[oo][2] = __builtin_fmaf(w.w, x3q.z, acc[oo][2]);
                acc[oo][3] = __builtin_fmaf(w.x, x0q.w, acc[oo][3]);
                acc[oo][3] = __builtin_fmaf(w.y, x1q.w, acc[oo][3]);
                acc[oo][3] = __builtin_fmaf(w.z, x2q.w, acc[oo][3]);
                acc[oo][3] = __builtin_fmaf(w.w, x3q.w, acc[oo][3]);
            }
        }
    }
    #pragma unroll
    for (int oo = 0; oo < 8; oo++)
        *(float4*)(Y + ((size_t)b * 256 + o0 + oo) * LSEQ + l0) =
            make_float4(acc[oo][0], acc[oo][1], acc[oo][2], acc[oo][3]);
}

// ---------- fold x3 (k norm, v plain, q norm+xx+cent/cc) ------------
__device__ __forceinline__ void fold_body(const float* __restrict__ src,
        int srcRows, int row0, int donorm, float* __restrict__ dst,
        float* __restrict__ xxout, float* __restrict__ centout,
        float* __restrict__ ccout, int p) {
    int bh = p >> 12, l = p & 4095;
    int b = bh >> 3, h = bh & 7;
    const float* sp = src + ((size_t)b * srcRows + row0 + h * 32) * LSEQ + l;
    float x[32];
    #pragma unroll
    for (int t = 0; t < 32; t++) x[t] = sp[(size_t)t * LSEQ];
    float4* dp4 = (float4*)(dst + (size_t)p * 32);
    if (donorm) {
        float ss = 0.f;
        #pragma unroll
        for (int t = 0; t < 32; t++) ss = fadd(ss, fmul(x[t], x[t]));
        float n = __fsqrt_rn(ss);
        float den = fmaxf(n, 1e-12f);
        #pragma unroll
        for (int t = 0; t < 32; t++) x[t] = __fdiv_rn(x[t], den);
    }
    #pragma unroll
    for (int t = 0; t < 8; t++)
        dp4[t] = make_float4(x[4*t], x[4*t+1], x[4*t+2], x[4*t+3]);
    if (xxout) {
        float e[32];
        #pragma unroll
        for (int t = 0; t < 32; t++) e[t] = fmul(x[t], x[t]);
        float xv = sum32_np(e);
        xxout[p] = xv;
        if (centout && p < KC) {
            float4* cp4 = (float4*)(centout + (size_t)p * 32);
            #pragma unroll
            for (int t = 0; t < 8; t++)
                cp4[t] = make_float4(x[4*t], x[4*t+1], x[4*t+2], x[4*t+3]);
            ccout[p] = xv;
        }
    }
}

__global__ __launch_bounds__(256) void fold3_np(const float* __restrict__ kvbuf,
        const float* __restrict__ qbuf, float* __restrict__ k_t,
        float* __restrict__ v_t, float* __restrict__ q_t,
        float* __restrict__ xx, float* __restrict__ cent, float* __restrict__ cc) {
    int blk = blockIdx.x, tid = threadIdx.x;
    if (blk < 256) {
        fold_body(kvbuf, 512, 0, 1, k_t, nullptr, nullptr, nullptr, blk * 256 + tid);
    } else if (blk < 512) {
        fold_body(kvbuf, 512, 256, 0, v_t, nullptr, nullptr, nullptr, (blk - 256) * 256 + tid);
    } else {
        fold_body(qbuf, 256, 0, 1, q_t, xx, cent, cc, (blk - 512) * 256 + tid);
    }
}

// ---------- argmin+hist: 4 pts/thread x quarter clusters (R16) ------
__global__ __launch_bounds__(256) void assign4p(const float* __restrict__ pts,
        const float* __restrict__ xx, const float* __restrict__ cent,
        const float* __restrict__ cc, int* __restrict__ asn, int* __restrict__ hist) {
    __shared__ float sc[8192];
    __shared__ float scc[256];
    __shared__ int bins[256];
    int tid = threadIdx.x, c = blockIdx.x;
    {
        const float4* c4 = (const float4*)cent;
        float4* s4 = (float4*)sc;
        for (int i = tid; i < 2048; i += 256) s4[i] = c4[i];
    }
    scc[tid] = cc[tid];
    bins[tid] = 0;
    __syncthreads();
    int pg = tid >> 2, quarter = tid & 3;
    int pb = c * 256 + pg * 4;
    float x[4][32];
    float xp[4];
    #pragma unroll
    for (int i = 0; i < 4; i++) {
        const float4* pp = (const float4*)(pts + (size_t)(pb + i) * 32);
        #pragma unroll
        for (int t = 0; t < 8; t++) {
            float4 f = pp[t];
            x[i][4*t] = f.x; x[i][4*t+1] = f.y; x[i][4*t+2] = f.z; x[i][4*t+3] = f.w;
        }
        xp[i] = xx[pb + i];
    }
    float bd[4] = {3.4e38f, 3.4e38f, 3.4e38f, 3.4e38f};
    int bj[4] = {0, 0, 0, 0};
    int jbase = quarter * 64;
    for (int jj = 0; jj < 64; jj++) {
        int j = jbase + jj;
        const float4* cj = (const float4*)(sc + j * 32);
        float w[32];
        #pragma unroll
        for (int t = 0; t < 8; t++) {
            float4 f = cj[t];
            w[4*t] = f.x; w[4*t+1] = f.y; w[4*t+2] = f.z; w[4*t+3] = f.w;
        }
        float sj = scc[j];
        #pragma unroll
        for (int i = 0; i < 4; i++) {
            float g = 0.f;
            #pragma unroll
            for (int t = 0; t < 32; t++) g = __builtin_fmaf(x[i][t], w[t], g);
            float d = fadd(fsub(xp[i], fmul(2.f, g)), sj);
            if (d < bd[i]) { bd[i] = d; bj[i] = j; }
        }
    }
    #pragma unroll
    for (int i = 0; i < 4; i++) {
        float ob; int oj;
        ob = __shfl_xor(bd[i], 1); oj = __shfl_xor(bj[i], 1);
        if (ob < bd[i]) { bd[i] = ob; bj[i] = oj; }
        ob = __shfl_xor(bd[i], 2); oj = __shfl_xor(bj[i], 2);
        if (ob < bd[i]) { bd[i] = ob; bj[i] = oj; }
    }
    if (quarter == 0) {
        #pragma unroll
        for (int i = 0; i < 4; i++) {
            asn[pb + i] = bj[i];
            atomicAdd(&bins[bj[i]], 1);
        }
    }
    __syncthreads();
    hist[c * 256 + tid] = bins[tid];
}

// ---------- per-cluster prefix over 256 chunks ----------------------
__global__ __launch_bounds__(256) void scan_chunks(const int* __restrict__ hist,
        int* __restrict__ chunkbase, int* __restrict__ totals) {
    __shared__ int a[256];
    int j = blockIdx.x, c = threadIdx.x;
    a[c] = hist[(size_t)c * 256 + j];
    __syncthreads();
    for (int d = 1; d < 256; d <<= 1) {
        int v = a[c];
        int u = (c >= d) ? a[c - d] : 0;
        __syncthreads();
        a[c] = v + u;
        __syncthreads();
    }
    chunkbase[(size_t)c * 256 + j] = (c == 0) ? 0 : a[c - 1];
    if (c == 255) totals[j] = a[255];
}

// ---------- scatter: parallel cbase scan + stable rank --------------
__global__ __launch_bounds__(256) void scatter_v5(const int* __restrict__ asn,
        const int* __restrict__ chunkbase, const int* __restrict__ totals,
        int* __restrict__ perm) {
    __shared__ int cb[256];
    __shared__ int al[256];
    int c = blockIdx.x, tid = threadIdx.x;
    cb[tid] = totals[tid];
    al[tid] = asn[c * 256 + tid];
    __syncthreads();
    for (int d = 1; d < 256; d <<= 1) {
        int v = cb[tid];
        int u = (tid >= d) ? cb[tid - d] : 0;
        __syncthreads();
        cb[tid] = v + u;
        __syncthreads();
    }
    int my = al[tid];
    int base = (my == 0) ? 0 : cb[my - 1];
    int r = 0;
    for (int i = 0; i < tid; i++) r += (al[i] == my) ? 1 : 0;
    perm[base + chunkbase[(size_t)c * 256 + my] + r] = c * 256 + tid;
}

// ---------- ordered sum + update + cc (parallel cbase scan) ---------
#define STILE 128
__global__ __launch_bounds__(256) void sumk_v4(const float* __restrict__ pts,
        const int* __restrict__ perm, const int* __restrict__ totals,
        float* __restrict__ cent, float* __restrict__ cc) {
    __shared__ int cb[256];
    __shared__ float buf[2][STILE][32];
    int j = blockIdx.x, tid = threadIdx.x;
    cb[tid] = totals[tid];
    __syncthreads();
    for (int d = 1; d < 256; d <<= 1) {
        int v = cb[tid];
        int u = (tid >= d) ? cb[tid - d] : 0;
        __syncthreads();
        cb[tid] = v + u;
        __syncthreads();
    }
    int base = (j == 0) ? 0 : cb[j - 1];
    int n = totals[j];
    int t = tid & 31, r0 = tid >> 5;
    for (int r = r0; r < STILE; r += 8) {
        if (r < n) buf[0][r][t] = pts[(size_t)perm[base + r] * 32 + t];
    }
    __syncthreads();
    float s = 0.f;
    int b = 0;
    for (int i0 = 0; i0 < n; i0 += STILE, b ^= 1) {
        int nx = i0 + STILE;
        if (nx < n) {
            for (int r = r0; r < STILE; r += 8) {
                int g = nx + r;
                if (g < n) buf[b ^ 1][r][t] = pts[(size_t)perm[base + g] * 32 + t];
            }
        }
        if (tid < 32) {
            int m = n - i0; if (m > STILE) m = STILE;
            int i = 0;
            for (; i + 4 <= m; i += 4) {
                s = fadd(s, buf[b][i][tid]);
                s = fadd(s, buf[b][i + 1][tid]);
                s = fadd(s, buf[b][i + 2][tid]);
                s = fadd(s, buf[b][i + 3][tid]);
            }
            for (; i < m; i++) s = fadd(s, buf[b][i][tid]);
        }
        __syncthreads();
    }
    if (tid < 32) {
        float v;
        if (n > 0) {
            v = __fdiv_rn(s, (float)n);
            cent[(size_t)j * 32 + tid] = v;
        } else {
            v = cent[(size_t)j * 32 + tid];
        }
        float e = fmul(v, v);
        e = fadd(e, __shfl_xor(e, 16));
        e = fadd(e, __shfl_xor(e, 8));
        e = fadd(e, __shfl_xor(e, 4));
        e = fadd(e, __shfl_xor(e, 2));
        e = fadd(e, __shfl_xor(e, 1));
        if (tid == 0) cc[j] = e;
    }
}

// ---------- key assign + L1: 4 pts/thread x quarter clusters --------
__global__ __launch_bounds__(256) void kdist4p(const float* __restrict__ pts,
        const float* __restrict__ cent, const float* __restrict__ cc,
        float* __restrict__ kd) {
    __shared__ float sc[8192];
    __shared__ float scc[256];
    int tid = threadIdx.x, c = blockIdx.x;
    {
        const float4* c4 = (const float4*)cent;
        float4* s4 = (float4*)sc;
        for (int i = tid; i < 2048; i += 256) s4[i] = c4[i];
    }
    scc[tid] = cc[tid];
    __syncthreads();
    int pg = tid >> 2, quarter = tid & 3;
    int pb = c * 256 + pg * 4;
    float x[4][32];
    float xp[4];
    #pragma unroll
    for (int i = 0; i < 4; i++) {
        const float4* pp = (const float4*)(pts + (size_t)(pb + i) * 32);
        #pragma unroll
        for (int t = 0; t < 8; t++) {
            float4 f = pp[t];
            x[i][4*t] = f.x; x[i][4*t+1] = f.y; x[i][4*t+2] = f.z; x[i][4*t+3] = f.w;
        }
        float e[32];
        #pragma unroll
        for (int t = 0; t < 32; t++) e[t] = fmul(x[i][t], x[i][t]);
        xp[i] = sum32_np(e);
    }
    float bd[4] = {3.4e38f, 3.4e38f, 3.4e38f, 3.4e38f};
    int bj[4] = {0, 0, 0, 0};
    int jbase = quarter * 64;
    for (int jj = 0; jj < 64; jj++) {
        int j = jbase + jj;
        const float4* cj = (const float4*)(sc + j * 32);
        float w[32];
        #pragma unroll
        for (int t = 0; t < 8; t++) {
            float4 f = cj[t];
            w[4*t] = f.x; w[4*t+1] = f.y; w[4*t+2] = f.z; w[4*t+3] = f.w;
        }
        float sj = scc[j];
        #pragma unroll
        for (int i = 0; i < 4; i++) {
            float g = 0.f;
            #pragma unroll
            for (int t = 0; t < 32; t++) g = __builtin_fmaf(x[i][t], w[t], g);
            float d = fadd(fsub(xp[i], fmul(2.f, g)), sj);
            if (d < bd[i]) { bd[i] = d; bj[i] = j; }
        }
    }
    #pragma unroll
    for (int i = 0; i < 4; i++) {
        float ob; int oj;
        ob = __shfl_xor(bd[i], 1); oj = __shfl_xor(bj[i], 1);
        if (ob < bd[i]) { bd[i] = ob; bj[i] = oj; }
        ob = __shfl_xor(bd[i], 2); oj = __shfl_xor(bj[i], 2);
        if (ob < bd[i]) { bd[i] = ob; bj[i] = oj; }
    }
    if (quarter == 0) {
        #pragma unroll
        for (int i = 0; i < 4; i++) {
            const float* cb = &sc[bj[i] * 32];
            float e[32];
            #pragma unroll
            for (int t = 0; t < 32; t++) e[t] = fabsf(fsub(cb[t], x[i][t]));
            kd[pb + i] = sum32_np(e);
        }
    }
}

// ---------- top-256 via radix select (exact stable set) + gather ----
__global__ __launch_bounds__(256) void topk_v2(const float* __restrict__ kd,
        const float* __restrict__ k_t, const float* __restrict__ v_t,
        float* __restrict__ ksel, float* __restrict__ vsel) {
    __shared__ unsigned uv[4096];
    __shared__ int hist[256];
    __shared__ unsigned s_prefix;
    __shared__ int s_rem;
    __shared__ int sc1[256];
    __shared__ int out_src[256];
    int bh = blockIdx.x, tid = threadIdx.x;
    for (int i = tid; i < 4096; i += 256) uv[i] = __float_as_uint(kd[bh * 4096 + i]);
    if (tid == 0) { s_prefix = 0u; s_rem = 256; }
    out_src[tid] = 0;
    __syncthreads();
    for (int pass = 0; pass < 4; pass++) {
        int shift = 24 - 8 * pass;
        hist[tid] = 0;
        __syncthreads();
        unsigned pfx = s_prefix;
        for (int i = tid; i < 4096; i += 256) {
            unsigned u = uv[i];
            bool in = (pass == 0) || ((u >> (shift + 8)) == (pfx >> (shift + 8)));
            if (in) atomicAdd(&hist[(u >> shift) & 255], 1);
        }
        __syncthreads();
        if (tid == 0) {
            int rem = s_rem, cum = 0, b;
            for (b = 255; b >= 0; b--) {
                if (cum + hist[b] >= rem) break;
                cum += hist[b];
            }
            s_rem = rem - cum;
            s_prefix = s_prefix | ((unsigned)b << shift);
        }
        __syncthreads();
    }
    unsigned T = s_prefix;
    int r = s_rem;
    int base_i = tid * 16;
    int ec = 0;
    for (int q = 0; q < 16; q++) ec += (uv[base_i + q] == T) ? 1 : 0;
    sc1[tid] = ec;
    __syncthreads();
    for (int d = 1; d < 256; d <<= 1) {
        int t0 = sc1[tid];
        int u0 = (tid >= d) ? sc1[tid - d] : 0;
        __syncthreads();
        sc1[tid] = t0 + u0;
        __syncthreads();
    }
    int erank = (tid == 0) ? 0 : sc1[tid - 1];
    __syncthreads();
    bool incl[16];
    int ic = 0;
    for (int q = 0; q < 16; q++) {
        unsigned u = uv[base_i + q];
        bool inc;
        if (u > T) inc = true;
        else if (u == T) { inc = (erank < r); erank++; }
        else inc = false;
        incl[q] = inc;
        ic += inc ? 1 : 0;
    }
    sc1[tid] = ic;
    __syncthreads();
    for (int d = 1; d < 256; d <<= 1) {
        int t0 = sc1[tid];
        int u0 = (tid >= d) ? sc1[tid - d] : 0;
        __syncthreads();
        sc1[tid] = t0 + u0;
        __syncthreads();
    }
    int pos = (tid == 0) ? 0 : sc1[tid - 1];
    for (int q = 0; q < 16; q++) {
        if (incl[q]) out_src[pos++] = base_i + q;
    }
    __syncthreads();
    for (int e = tid; e < 256 * 32; e += 256) {
        int jj = e >> 5, t = e & 31;
        int src = out_src[jj];
        ksel[(size_t)bh * 8192 + e] = k_t[((size_t)bh * 4096 + src) * 32 + t];
        vsel[(size_t)bh * 8192 + e] = v_t[((size_t)bh * 4096 + src) * 32 + t];
    }
}

// ---------- attention v3d: 4 queries per lane-quad (R18) ------------
#define HPAD 4112
__global__ __launch_bounds__(256) void attn_v3d(const float* __restrict__ q_t,
        const float* __restrict__ ksel, const float* __restrict__ vsel,
        float* __restrict__ out) {
    __shared__ float sk[2 * HPAD];
    __shared__ float sv[2 * HPAD];
    int bh = blockIdx.y, tid = threadIdx.x;
    {
        const float4* gk = (const float4*)(ksel + (size_t)bh * 8192);
        const float4* gv = (const float4*)(vsel + (size_t)bh * 8192);
        for (int i = tid; i < 2048; i += 256) {
            int h = i >> 10, idx = i & 1023;
            ((float4*)(sk + h * HPAD))[idx] = gk[i];
            ((float4*)(sv + h * HPAD))[idx] = gv[i];
        }
    }
    __syncthreads();
    int grp = tid >> 2;
    int slice = tid & 1;
    int dh = (tid >> 1) & 1;
    int p0 = bh * 4096 + blockIdx.x * 256 + grp * 4;
    float q[4][16];
    #pragma unroll
    for (int i = 0; i < 4; i++) {
        const float4* qp = (const float4*)(q_t + (size_t)(p0 + i) * 32 + dh * 16);
        #pragma unroll
        for (int t = 0; t < 4; t++) {
            float4 f = qp[t];
            q[i][4*t] = f.x; q[i][4*t+1] = f.y; q[i][4*t+2] = f.z; q[i][4*t+3] = f.w;
        }
    }
    float o[4][16];
    #pragma unroll
    for (int i = 0; i < 4; i++)
        #pragma unroll
        for (int t = 0; t < 16; t++) o[i][t] = 0.f;
    float ls[4] = {0.f, 0.f, 0.f, 0.f};
    const float* kb = sk + slice * HPAD + dh * 16;
    const float* vb = sv + slice * HPAD + dh * 16;
    for (int j = 0; j < 128; j++) {
        float kf[16];
        #pragma unroll
        for (int t = 0; t < 4; t++) {
            float4 f = *(const float4*)(kb + j * 32 + t * 4);
            kf[4*t] = f.x; kf[4*t+1] = f.y; kf[4*t+2] = f.z; kf[4*t+3] = f.w;
        }
        float ps[4];
        #pragma unroll
        for (int i = 0; i < 4; i++) {
            float a = 0.f, b2 = 0.f, c2 = 0.f, d2 = 0.f;
            #pragma unroll
            for (int t = 0; t < 4; t++) {
                a  += q[i][4*t]   * kf[4*t];
                b2 += q[i][4*t+1] * kf[4*t+1];
                c2 += q[i][4*t+2] * kf[4*t+2];
                d2 += q[i][4*t+3] * kf[4*t+3];
            }
            ps[i] = (a + b2) + (c2 + d2);
        }
        #pragma unroll
        for (int i = 0; i < 4; i++) ps[i] += __shfl_xor(ps[i], 2);
        float w[4];
        #pragma unroll
        for (int i = 0; i < 4; i++) {
            w[i] = __expf(ps[i] - 1.0f);
            ls[i] += w[i];
        }
        float vf[16];
        #pragma unroll
        for (int t = 0; t < 4; t++) {
            float4 f = *(const float4*)(vb + j * 32 + t * 4);
            vf[4*t] = f.x; vf[4*t+1] = f.y; vf[4*t+2] = f.z; vf[4*t+3] = f.w;
        }
        #pragma unroll
        for (int i = 0; i < 4; i++)
            #pragma unroll
            for (int t = 0; t < 16; t++) o[i][t] += w[i] * vf[t];
    }
    #pragma unroll
    for (int i = 0; i < 4; i++) {
        #pragma unroll
        for (int t = 0; t < 16; t++) o[i][t] += __shfl_xor(o[i][t], 1);
        ls[i] += __shfl_xor(ls[i], 1);
    }
    if (slice == 0) {
        #pragma unroll
        for (int i = 0; i < 4; i++) {
            float inv = 1.f / ls[i];
            float4* op = (float4*)(out + (size_t)(p0 + i) * 32 + dh * 16);
            #pragma unroll
            for (int t = 0; t < 4; t++)
                op[t] = make_float4(o[i][4*t]*inv, o[i][4*t+1]*inv,
                                    o[i][4*t+2]*inv, o[i][4*t+3]*inv);
        }
    }
}

// ---------- unfold (bh,L,32) -> (b,256,L) ---------------------------
__global__ __launch_bounds__(256) void unfold_kernel(const float* __restrict__ att,
        float* __restrict__ Fo) {
    __shared__ float tbuf[32][65];
    int bh = blockIdx.y, l0 = blockIdx.x * 64;
    int b = bh >> 3, h = bh & 7;
    int tid = threadIdx.x;
    #pragma unroll
    for (int r = 0; r < 8; r++) {
        int e = r * 256 + tid;
        int l = e >> 5, d = e & 31;
        tbuf[d][l] = att[((size_t)bh * 4096 + l0 + l) * 32 + d];
    }
    __syncthreads();
    #pragma unroll
    for (int r = 0; r < 8; r++) {
        int e = r * 256 + tid;
        int d = e >> 6, l = e & 63;
        Fo[((size_t)b * 256 + h * 32 + d) * LSEQ + l0 + l] = tbuf[d][l];
    }
}

// ---------- final LN + scale + residual (numpy orders) --------------
__global__ __launch_bounds__(64) void lnres_np(const float* __restrict__ x,
        const float* __restrict__ g, const float* __restrict__ bt,
        const float* __restrict__ gs, const float* __restrict__ qsrc,
        float* __restrict__ y) {
    int gid = blockIdx.x * 64 + threadIdx.x;
    int b = gid >> 12, l = gid & 4095;
    const float* xb = x + (size_t)b * CDIM * LSEQ + l;
    float s = 0.f;
    #pragma unroll 8
    for (int c = 0; c < 256; c++) s = fadd(s, xb[(size_t)c * LSEQ]);
    float mean = __fdiv_rn(s, 256.f);
    float s2 = 0.f;
    #pragma unroll 8
    for (int c = 0; c < 256; c++) {
        float d = fsub(xb[(size_t)c * LSEQ], mean);
        s2 = fadd(s2, fmul(d, d));
    }
    float var = __fdiv_rn(s2, 256.f);
    float den = fadd(__fsqrt_rn(var), 1e-6f);
    float scale = gs[0];
    const float* qb = qsrc + (size_t)b * CDIM * LSEQ + l;
    float* yb = y + (size_t)b * CDIM * LSEQ + l;
    #pragma unroll 4
    for (int c = 0; c < 256; c++) {
        float d = fsub(xb[(size_t)c * LSEQ], mean);
        float r = fadd(__fdiv_rn(fmul(g[c], d), den), bt[c]);
        yb[(size_t)c * LSEQ] = fadd(fmul(scale, r), qb[(size_t)c * LSEQ]);
    }
}

// ==================================================================
extern "C" void kernel_launch(void* const* d_in, const int* in_sizes, int n_in,
                              void* d_out, int out_size, void* d_ws, size_t ws_size,
                              hipStream_t stream) {
    const float* qsrc   = (const float*)d_in[0];
    const float* ctx    = (const float*)d_in[1];
    const float* w_q    = (const float*)d_in[2];
    const float* w_kv   = (const float*)d_in[3];
    const float* w_out  = (const float*)d_in[4];
    const float* g_ctx  = (const float*)d_in[5];
    const float* b_ctx  = (const float*)d_in[6];
    const float* g_q    = (const float*)d_in[7];
    const float* b_q    = (const float*)d_in[8];
    const float* g_out  = (const float*)d_in[9];
    const float* b_out  = (const float*)d_in[10];
    const float* gs     = (const float*)d_in[11];

    char* base = (char*)d_ws;
    const size_t MB = 1024 * 1024;
    float* yln   = (float*)base;               // [0,8) ctx LN; later att
    float* att   = (float*)base;
    float* kvbuf = (float*)(base + 8 * MB);    // [8,24) kv conv; later y32 [8,16)
    float* y32   = (float*)(base + 8 * MB);
    float* qbuf  = (float*)(base + 24 * MB);   // [24,32) q conv; later Fo
    float* Fo    = (float*)(base + 24 * MB);
    float* q_t   = (float*)(base + 32 * MB);   // [32,40)
    float* k_t   = (float*)(base + 40 * MB);   // [40,48)
    float* v_t   = (float*)(base + 48 * MB);   // [48,56)
    char* SM = base + 56 * MB;
    float* xx_q      = (float*)(SM + 0);            // 256 KB
    float* cent      = (float*)(SM + 512 * 1024);   // 32 KB
    float* cc        = (float*)(SM + 576 * 1024);   // 1 KB
    int*   totals    = (int*)  (SM + 640 * 1024);   // 1 KB
    int*   asn       = (int*)  (SM + 704 * 1024);   // 256 KB
    int*   hist      = (int*)  (SM + 960 * 1024);   // 256 KB
    int*   chunkbase = (int*)  (SM + 1472 * 1024);  // 256 KB
    int*   perm      = (int*)  (SM + 1984 * 1024);  // 256 KB
    float* kd        = (float*)(SM + 2240 * 1024);  // 256 KB
    float* ksel      = (float*)(SM + 2496 * 1024);  // 512 KB
    float* vsel      = (float*)(SM + 3008 * 1024);  // 512 KB
    float* yln_q     = (float*)(base + 60 * MB);    // [60,68) q LN out

    ln2_np<<<256, 64, 0, stream>>>(ctx, g_ctx, b_ctx, yln,
                                   qsrc, g_q, b_q, yln_q);
    conv_kv<<<dim3(4, 64, 2), 256, 0, stream>>>(w_kv, yln, kvbuf);
    conv_q8<true><<<dim3(4, 32, 2), 256, 0, stream>>>(w_q, yln_q, qbuf);
    fold3_np<<<768, 256, 0, stream>>>(kvbuf, qbuf, k_t, v_t, q_t, xx_q, cent, cc);

    for (int it = 0; it < 10; it++) {
        assign4p<<<256, 256, 0, stream>>>(q_t, xx_q, cent, cc, asn, hist);
        scan_chunks<<<256, 256, 0, stream>>>(hist, chunkbase, totals);
        scatter_v5<<<256, 256, 0, stream>>>(asn, chunkbase, totals, perm);
        sumk_v4<<<256, 256, 0, stream>>>(q_t, perm, totals, cent, cc);
    }

    kdist4p<<<256, 256, 0, stream>>>(k_t, cent, cc, kd);
    topk_v2<<<16, 256, 0, stream>>>(kd, k_t, v_t, ksel, vsel);
    attn_v3d<<<dim3(16, 16), 256, 0, stream>>>(q_t, ksel, vsel, att);
    unfold_kernel<<<dim3(64, 16), 256, 0, stream>>>(att, Fo);
    conv_q8<false><<<dim3(4, 32, 2), 256, 0, stream>>>(w_out, Fo, y32);
    lnres_np<<<128, 64, 0, stream>>>(y32, g_out, b_out, gs, qsrc, (float*)d_out);
}

// Round 20
// 909.680 us; speedup vs baseline: 1.2520x; 1.0350x over previous
//
#include <hip/hip_runtime.h>
#include <math.h>

#define CDIM 256
#define LSEQ 4096
#define NBH 16
#define NPTS 65536
#define KC 256

__device__ __forceinline__ float fadd(float a, float b){ return __fadd_rn(a,b); }
__device__ __forceinline__ float fmul(float a, float b){ return __fmul_rn(a,b); }
__device__ __forceinline__ float fsub(float a, float b){ return __fsub_rn(a,b); }

// numpy contiguous n=32 float32 sum, AVX-512 npyv path (verified R5)
__device__ __forceinline__ float sum32_np(const float* e){
    float l[16];
    #pragma unroll
    for (int j = 0; j < 16; j++) l[j] = fadd(e[j], e[j + 16]);
    float t3[8];
    #pragma unroll
    for (int j = 0; j < 8; j++) t3[j] = fadd(l[j], l[j + 8]);
    float t6[4];
    #pragma unroll
    for (int j = 0; j < 4; j++) t6[j] = fadd(t3[j], t3[j + 4]);
    return fadd(fadd(t6[0], t6[2]), fadd(t6[1], t6[3]));
}

// ---------- both LayerNorms, one launch (numpy exact per position) --
__global__ __launch_bounds__(64) void ln2_np(
        const float* __restrict__ x0, const float* __restrict__ g0,
        const float* __restrict__ bt0, float* __restrict__ y0,
        const float* __restrict__ x1, const float* __restrict__ g1,
        const float* __restrict__ bt1, float* __restrict__ y1) {
    int gid = blockIdx.x * 64 + threadIdx.x;
    int which = gid >> 13;
    int r = gid & 8191;
    int b = r >> 12, l = r & 4095;
    const float* x  = which ? x1 : x0;
    const float* g  = which ? g1 : g0;
    const float* bt = which ? bt1 : bt0;
    float* y        = which ? y1 : y0;
    const float* xb = x + (size_t)b * CDIM * LSEQ + l;
    float s = 0.f;
    #pragma unroll 8
    for (int c = 0; c < 256; c++) s = fadd(s, xb[(size_t)c * LSEQ]);
    float mean = __fdiv_rn(s, 256.f);
    float s2 = 0.f;
    #pragma unroll 8
    for (int c = 0; c < 256; c++) {
        float d = fsub(xb[(size_t)c * LSEQ], mean);
        s2 = fadd(s2, fmul(d, d));
    }
    float var = __fdiv_rn(s2, 256.f);
    float den = fadd(__fsqrt_rn(var), 1e-6f);
    float* yb = y + (size_t)b * CDIM * LSEQ + l;
    #pragma unroll 4
    for (int c = 0; c < 256; c++) {
        float d = fsub(xb[(size_t)c * LSEQ], mean);
        yb[(size_t)c * LSEQ] = fadd(__fdiv_rn(fmul(g[c], d), den), bt[c]);
    }
}

// ---------- conv kv: COT=8, NL=4 (float4), k rows SOP / v rows FMA --
__global__ __launch_bounds__(256) void conv_kv(const float* __restrict__ W,
        const float* __restrict__ X, float* __restrict__ Y) {
    __shared__ float ws[8 * 256];
    int tid = threadIdx.x;
    int l0 = blockIdx.x * 1024 + tid * 4;
    int o0 = blockIdx.y * 8;
    int b = blockIdx.z;
    {
        const float4* wb4 = (const float4*)(W + (size_t)o0 * CDIM);
        float4* ws4 = (float4*)ws;
        for (int i = tid; i < 8 * 64; i += 256) ws4[i] = wb4[i];
    }
    __syncthreads();
    const float* xb = X + (size_t)b * CDIM * LSEQ;
    float acc[8][4];
    #pragma unroll
    for (int oo = 0; oo < 8; oo++)
        #pragma unroll
        for (int i = 0; i < 4; i++) acc[oo][i] = 0.f;
    const float4* ws4 = (const float4*)ws;
    if (blockIdx.y < 32) {
        for (int c = 0; c < 256; c += 4) {
            float4 x0q = *(const float4*)(xb + (size_t)(c + 0) * LSEQ + l0);
            float4 x1q = *(const float4*)(xb + (size_t)(c + 1) * LSEQ + l0);
            float4 x2q = *(const float4*)(xb + (size_t)(c + 2) * LSEQ + l0);
            float4 x3q = *(const float4*)(xb + (size_t)(c + 3) * LSEQ + l0);
            #pragma unroll
            for (int oo = 0; oo < 8; oo++) {
                float4 w = ws4[(oo * 256 + c) >> 2];
                acc[oo][0] = fadd(acc[oo][0], fmul(w.x, x0q.x));
                acc[oo][0] = fadd(acc[oo][0], fmul(w.y, x1q.x));
                acc[oo][0] = fadd(acc[oo][0], fmul(w.z, x2q.x));
                acc[oo][0] = fadd(acc[oo][0], fmul(w.w, x3q.x));
                acc[oo][1] = fadd(acc[oo][1], fmul(w.x, x0q.y));
                acc[oo][1] = fadd(acc[oo][1], fmul(w.y, x1q.y));
                acc[oo][1] = fadd(acc[oo][1], fmul(w.z, x2q.y));
                acc[oo][1] = fadd(acc[oo][1], fmul(w.w, x3q.y));
                acc[oo][2] = fadd(acc[oo][2], fmul(w.x, x0q.z));
                acc[oo][2] = fadd(acc[oo][2], fmul(w.y, x1q.z));
                acc[oo][2] = fadd(acc[oo][2], fmul(w.z, x2q.z));
                acc[oo][2] = fadd(acc[oo][2], fmul(w.w, x3q.z));
                acc[oo][3] = fadd(acc[oo][3], fmul(w.x, x0q.w));
                acc[oo][3] = fadd(acc[oo][3], fmul(w.y, x1q.w));
                acc[oo][3] = fadd(acc[oo][3], fmul(w.z, x2q.w));
                acc[oo][3] = fadd(acc[oo][3], fmul(w.w, x3q.w));
            }
        }
    } else {
        for (int c = 0; c < 256; c += 4) {
            float4 x0q = *(const float4*)(xb + (size_t)(c + 0) * LSEQ + l0);
            float4 x1q = *(const float4*)(xb + (size_t)(c + 1) * LSEQ + l0);
            float4 x2q = *(const float4*)(xb + (size_t)(c + 2) * LSEQ + l0);
            float4 x3q = *(const float4*)(xb + (size_t)(c + 3) * LSEQ + l0);
            #pragma unroll
            for (int oo = 0; oo < 8; oo++) {
                float4 w = ws4[(oo * 256 + c) >> 2];
                acc[oo][0] = __builtin_fmaf(w.x, x0q.x, acc[oo][0]);
                acc[oo][0] = __builtin_fmaf(w.y, x1q.x, acc[oo][0]);
                acc[oo][0] = __builtin_fmaf(w.z, x2q.x, acc[oo][0]);
                acc[oo][0] = __builtin_fmaf(w.w, x3q.x, acc[oo][0]);
                acc[oo][1] = __builtin_fmaf(w.x, x0q.y, acc[oo][1]);
                acc[oo][1] = __builtin_fmaf(w.y, x1q.y, acc[oo][1]);
                acc[oo][1] = __builtin_fmaf(w.z, x2q.y, acc[oo][1]);
                acc[oo][1] = __builtin_fmaf(w.w, x3q.y, acc[oo][1]);
                acc[oo][2] = __builtin_fmaf(w.x, x0q.z, acc[oo][2]);
                acc[oo][2] = __builtin_fmaf(w.y, x1q.z, acc[oo][2]);
                acc[oo][2] = __builtin_fmaf(w.z, x2q.z, acc[oo][2]);
                acc[oo][2] = __builtin_fmaf(w.w, x3q.z, acc[oo][2]);
                acc[oo][3] = __builtin_fmaf(w.x, x0q.w, acc[oo][3]);
                acc[oo][3] = __builtin_fmaf(w.y, x1q.w, acc[oo][3]);
                acc[oo][3] = __builtin_fmaf(w.z, x2q.w, acc[oo][3]);
                acc[oo][3] = __builtin_fmaf(w.w, x3q.w, acc[oo][3]);
            }
        }
    }
    #pragma unroll
    for (int oo = 0; oo < 8; oo++)
        *(float4*)(Y + ((size_t)b * 512 + o0 + oo) * LSEQ + l0) =
            make_float4(acc[oo][0], acc[oo][1], acc[oo][2], acc[oo][3]);
}

// ---------- conv 256-row: COT=8, NL=4; EXACT -> SOP else FMA --------
template<bool EXACT>
__global__ __launch_bounds__(256) void conv_q8(const float* __restrict__ W,
        const float* __restrict__ X, float* __restrict__ Y) {
    __shared__ float ws[8 * 256];
    int tid = threadIdx.x;
    int l0 = blockIdx.x * 1024 + tid * 4;
    int o0 = blockIdx.y * 8;
    int b = blockIdx.z;
    {
        const float4* wb4 = (const float4*)(W + (size_t)o0 * CDIM);
        float4* ws4 = (float4*)ws;
        for (int i = tid; i < 8 * 64; i += 256) ws4[i] = wb4[i];
    }
    __syncthreads();
    const float* xb = X + (size_t)b * CDIM * LSEQ;
    float acc[8][4];
    #pragma unroll
    for (int oo = 0; oo < 8; oo++)
        #pragma unroll
        for (int i = 0; i < 4; i++) acc[oo][i] = 0.f;
    const float4* ws4 = (const float4*)ws;
    for (int c = 0; c < 256; c += 4) {
        float4 x0q = *(const float4*)(xb + (size_t)(c + 0) * LSEQ + l0);
        float4 x1q = *(const float4*)(xb + (size_t)(c + 1) * LSEQ + l0);
        float4 x2q = *(const float4*)(xb + (size_t)(c + 2) * LSEQ + l0);
        float4 x3q = *(const float4*)(xb + (size_t)(c + 3) * LSEQ + l0);
        #pragma unroll
        for (int oo = 0; oo < 8; oo++) {
            float4 w = ws4[(oo * 256 + c) >> 2];
            if (EXACT) {
                acc[oo][0] = fadd(acc[oo][0], fmul(w.x, x0q.x));
                acc[oo][0] = fadd(acc[oo][0], fmul(w.y, x1q.x));
                acc[oo][0] = fadd(acc[oo][0], fmul(w.z, x2q.x));
                acc[oo][0] = fadd(acc[oo][0], fmul(w.w, x3q.x));
                acc[oo][1] = fadd(acc[oo][1], fmul(w.x, x0q.y));
                acc[oo][1] = fadd(acc[oo][1], fmul(w.y, x1q.y));
                acc[oo][1] = fadd(acc[oo][1], fmul(w.z, x2q.y));
                acc[oo][1] = fadd(acc[oo][1], fmul(w.w, x3q.y));
                acc[oo][2] = fadd(acc[oo][2], fmul(w.x, x0q.z));
                acc[oo][2] = fadd(acc[oo][2], fmul(w.y, x1q.z));
                acc[oo][2] = fadd(acc[oo][2], fmul(w.z, x2q.z));
                acc[oo][2] = fadd(acc[oo][2], fmul(w.w, x3q.z));
                acc[oo][3] = fadd(acc[oo][3], fmul(w.x, x0q.w));
                acc[oo][3] = fadd(acc[oo][3], fmul(w.y, x1q.w));
                acc[oo][3] = fadd(acc[oo][3], fmul(w.z, x2q.w));
                acc[oo][3] = fadd(acc[oo][3], fmul(w.w, x3q.w));
            } else {
                acc[oo][0] = __builtin_fmaf(w.x, x0q.x, acc[oo][0]);
                acc[oo][0] = __builtin_fmaf(w.y, x1q.x, acc[oo][0]);
                acc[oo][0] = __builtin_fmaf(w.z, x2q.x, acc[oo][0]);
                acc[oo][0] = __builtin_fmaf(w.w, x3q.x, acc[oo][0]);
                acc[oo][1] = __builtin_fmaf(w.x, x0q.y, acc[oo][1]);
                acc[oo][1] = __builtin_fmaf(w.y, x1q.y, acc[oo][1]);
                acc[oo][1] = __builtin_fmaf(w.z, x2q.y, acc[oo][1]);
                acc[oo][1] = __builtin_fmaf(w.w, x3q.y, acc[oo][1]);
                acc[oo][2] = __builtin_fmaf(w.x, x0q.z, acc[oo][2]);
                acc[oo][2] = __builtin_fmaf(w.y, x1q.z, acc[oo][2]);
                acc[oo][2] = __builtin_fmaf(w.z, x2q.z, acc[oo][2]);
                acc[oo][2] = __builtin_fmaf(w.w, x3q.z, acc[oo][2]);
                acc[oo][3] = __builtin_fmaf(w.x, x0q.w, acc[oo][3]);
                acc[oo][3] = __builtin_fmaf(w.y, x1q.w, acc[oo][3]);
                acc[oo][3] = __builtin_fmaf(w.z, x2q.w, acc[oo][3]);
                acc[oo][3] = __builtin_fmaf(w.w, x3q.w, acc[oo][3]);
            }
        }
    }
    #pragma unroll
    for (int oo = 0; oo < 8; oo++)
        *(float4*)(Y + ((size_t)b * 256 + o0 + oo) * LSEQ + l0) =
            make_float4(acc[oo][0], acc[oo][1], acc[oo][2], acc[oo][3]);
}

// ---------- fold x3 (k norm, v plain, q norm+xx+cent/cc) ------------
__device__ __forceinline__ void fold_body(const float* __restrict__ src,
        int srcRows, int row0, int donorm, float* __restrict__ dst,
        float* __restrict__ xxout, float* __restrict__ centout,
        float* __restrict__ ccout, int p) {
    int bh = p >> 12, l = p & 4095;
    int b = bh >> 3, h = bh & 7;
    const float* sp = src + ((size_t)b * srcRows + row0 + h * 32) * LSEQ + l;
    float x[32];
    #pragma unroll
    for (int t = 0; t < 32; t++) x[t] = sp[(size_t)t * LSEQ];
    float4* dp4 = (float4*)(dst + (size_t)p * 32);
    if (donorm) {
        float ss = 0.f;
        #pragma unroll
        for (int t = 0; t < 32; t++) ss = fadd(ss, fmul(x[t], x[t]));
        float n = __fsqrt_rn(ss);
        float den = fmaxf(n, 1e-12f);
        #pragma unroll
        for (int t = 0; t < 32; t++) x[t] = __fdiv_rn(x[t], den);
    }
    #pragma unroll
    for (int t = 0; t < 8; t++)
        dp4[t] = make_float4(x[4*t], x[4*t+1], x[4*t+2], x[4*t+3]);
    if (xxout) {
        float e[32];
        #pragma unroll
        for (int t = 0; t < 32; t++) e[t] = fmul(x[t], x[t]);
        float xv = sum32_np(e);
        xxout[p] = xv;
        if (centout && p < KC) {
            float4* cp4 = (float4*)(centout + (size_t)p * 32);
            #pragma unroll
            for (int t = 0; t < 8; t++)
                cp4[t] = make_float4(x[4*t], x[4*t+1], x[4*t+2], x[4*t+3]);
            ccout[p] = xv;
        }
    }
}

__global__ __launch_bounds__(256) void fold3_np(const float* __restrict__ kvbuf,
        const float* __restrict__ qbuf, float* __restrict__ k_t,
        float* __restrict__ v_t, float* __restrict__ q_t,
        float* __restrict__ xx, float* __restrict__ cent, float* __restrict__ cc) {
    int blk = blockIdx.x, tid = threadIdx.x;
    if (blk < 256) {
        fold_body(kvbuf, 512, 0, 1, k_t, nullptr, nullptr, nullptr, blk * 256 + tid);
    } else if (blk < 512) {
        fold_body(kvbuf, 512, 256, 0, v_t, nullptr, nullptr, nullptr, (blk - 256) * 256 + tid);
    } else {
        fold_body(qbuf, 256, 0, 1, q_t, xx, cent, cc, (blk - 512) * 256 + tid);
    }
}

// ---------- argmin+hist: 4 pts/thread x quarter clusters (R16) ------
__global__ __launch_bounds__(256) void assign4p(const float* __restrict__ pts,
        const float* __restrict__ xx, const float* __restrict__ cent,
        const float* __restrict__ cc, int* __restrict__ asn, int* __restrict__ hist) {
    __shared__ float sc[8192];
    __shared__ float scc[256];
    __shared__ int bins[256];
    int tid = threadIdx.x, c = blockIdx.x;
    {
        const float4* c4 = (const float4*)cent;
        float4* s4 = (float4*)sc;
        for (int i = tid; i < 2048; i += 256) s4[i] = c4[i];
    }
    scc[tid] = cc[tid];
    bins[tid] = 0;
    __syncthreads();
    int pg = tid >> 2, quarter = tid & 3;
    int pb = c * 256 + pg * 4;
    float x[4][32];
    float xp[4];
    #pragma unroll
    for (int i = 0; i < 4; i++) {
        const float4* pp = (const float4*)(pts + (size_t)(pb + i) * 32);
        #pragma unroll
        for (int t = 0; t < 8; t++) {
            float4 f = pp[t];
            x[i][4*t] = f.x; x[i][4*t+1] = f.y; x[i][4*t+2] = f.z; x[i][4*t+3] = f.w;
        }
        xp[i] = xx[pb + i];
    }
    float bd[4] = {3.4e38f, 3.4e38f, 3.4e38f, 3.4e38f};
    int bj[4] = {0, 0, 0, 0};
    int jbase = quarter * 64;
    for (int jj = 0; jj < 64; jj++) {
        int j = jbase + jj;
        const float4* cj = (const float4*)(sc + j * 32);
        float w[32];
        #pragma unroll
        for (int t = 0; t < 8; t++) {
            float4 f = cj[t];
            w[4*t] = f.x; w[4*t+1] = f.y; w[4*t+2] = f.z; w[4*t+3] = f.w;
        }
        float sj = scc[j];
        #pragma unroll
        for (int i = 0; i < 4; i++) {
            float g = 0.f;
            #pragma unroll
            for (int t = 0; t < 32; t++) g = __builtin_fmaf(x[i][t], w[t], g);
            float d = fadd(fsub(xp[i], fmul(2.f, g)), sj);
            if (d < bd[i]) { bd[i] = d; bj[i] = j; }
        }
    }
    #pragma unroll
    for (int i = 0; i < 4; i++) {
        float ob; int oj;
        ob = __shfl_xor(bd[i], 1); oj = __shfl_xor(bj[i], 1);
        if (ob < bd[i]) { bd[i] = ob; bj[i] = oj; }
        ob = __shfl_xor(bd[i], 2); oj = __shfl_xor(bj[i], 2);
        if (ob < bd[i]) { bd[i] = ob; bj[i] = oj; }
    }
    if (quarter == 0) {
        #pragma unroll
        for (int i = 0; i < 4; i++) {
            asn[pb + i] = bj[i];
            atomicAdd(&bins[bj[i]], 1);
        }
    }
    __syncthreads();
    hist[c * 256 + tid] = bins[tid];
}

// ---------- per-cluster prefix over 256 chunks ----------------------
__global__ __launch_bounds__(256) void scan_chunks(const int* __restrict__ hist,
        int* __restrict__ chunkbase, int* __restrict__ totals) {
    __shared__ int a[256];
    int j = blockIdx.x, c = threadIdx.x;
    a[c] = hist[(size_t)c * 256 + j];
    __syncthreads();
    for (int d = 1; d < 256; d <<= 1) {
        int v = a[c];
        int u = (c >= d) ? a[c - d] : 0;
        __syncthreads();
        a[c] = v + u;
        __syncthreads();
    }
    chunkbase[(size_t)c * 256 + j] = (c == 0) ? 0 : a[c - 1];
    if (c == 255) totals[j] = a[255];
}

// ---------- scatter: parallel cbase scan + stable rank --------------
__global__ __launch_bounds__(256) void scatter_v5(const int* __restrict__ asn,
        const int* __restrict__ chunkbase, const int* __restrict__ totals,
        int* __restrict__ perm) {
    __shared__ int cb[256];
    __shared__ int al[256];
    int c = blockIdx.x, tid = threadIdx.x;
    cb[tid] = totals[tid];
    al[tid] = asn[c * 256 + tid];
    __syncthreads();
    for (int d = 1; d < 256; d <<= 1) {
        int v = cb[tid];
        int u = (tid >= d) ? cb[tid - d] : 0;
        __syncthreads();
        cb[tid] = v + u;
        __syncthreads();
    }
    int my = al[tid];
    int base = (my == 0) ? 0 : cb[my - 1];
    int r = 0;
    for (int i = 0; i < tid; i++) r += (al[i] == my) ? 1 : 0;
    perm[base + chunkbase[(size_t)c * 256 + my] + r] = c * 256 + tid;
}

// ---------- ordered sum + update + cc (parallel cbase scan) ---------
#define STILE 128
__global__ __launch_bounds__(256) void sumk_v4(const float* __restrict__ pts,
        const int* __restrict__ perm, const int* __restrict__ totals,
        float* __restrict__ cent, float* __restrict__ cc) {
    __shared__ int cb[256];
    __shared__ float buf[2][STILE][32];
    int j = blockIdx.x, tid = threadIdx.x;
    cb[tid] = totals[tid];
    __syncthreads();
    for (int d = 1; d < 256; d <<= 1) {
        int v = cb[tid];
        int u = (tid >= d) ? cb[tid - d] : 0;
        __syncthreads();
        cb[tid] = v + u;
        __syncthreads();
    }
    int base = (j == 0) ? 0 : cb[j - 1];
    int n = totals[j];
    int t = tid & 31, r0 = tid >> 5;
    for (int r = r0; r < STILE; r += 8) {
        if (r < n) buf[0][r][t] = pts[(size_t)perm[base + r] * 32 + t];
    }
    __syncthreads();
    float s = 0.f;
    int b = 0;
    for (int i0 = 0; i0 < n; i0 += STILE, b ^= 1) {
        int nx = i0 + STILE;
        if (nx < n) {
            for (int r = r0; r < STILE; r += 8) {
                int g = nx + r;
                if (g < n) buf[b ^ 1][r][t] = pts[(size_t)perm[base + g] * 32 + t];
            }
        }
        if (tid < 32) {
            int m = n - i0; if (m > STILE) m = STILE;
            int i = 0;
            for (; i + 4 <= m; i += 4) {
                s = fadd(s, buf[b][i][tid]);
                s = fadd(s, buf[b][i + 1][tid]);
                s = fadd(s, buf[b][i + 2][tid]);
                s = fadd(s, buf[b][i + 3][tid]);
            }
            for (; i < m; i++) s = fadd(s, buf[b][i][tid]);
        }
        __syncthreads();
    }
    if (tid < 32) {
        float v;
        if (n > 0) {
            v = __fdiv_rn(s, (float)n);
            cent[(size_t)j * 32 + tid] = v;
        } else {
            v = cent[(size_t)j * 32 + tid];
        }
        float e = fmul(v, v);
        e = fadd(e, __shfl_xor(e, 16));
        e = fadd(e, __shfl_xor(e, 8));
        e = fadd(e, __shfl_xor(e, 4));
        e = fadd(e, __shfl_xor(e, 2));
        e = fadd(e, __shfl_xor(e, 1));
        if (tid == 0) cc[j] = e;
    }
}

// ---------- key assign + L1: 4 pts/thread x quarter clusters --------
__global__ __launch_bounds__(256) void kdist4p(const float* __restrict__ pts,
        const float* __restrict__ cent, const float* __restrict__ cc,
        float* __restrict__ kd) {
    __shared__ float sc[8192];
    __shared__ float scc[256];
    int tid = threadIdx.x, c = blockIdx.x;
    {
        const float4* c4 = (const float4*)cent;
        float4* s4 = (float4*)sc;
        for (int i = tid; i < 2048; i += 256) s4[i] = c4[i];
    }
    scc[tid] = cc[tid];
    __syncthreads();
    int pg = tid >> 2, quarter = tid & 3;
    int pb = c * 256 + pg * 4;
    float x[4][32];
    float xp[4];
    #pragma unroll
    for (int i = 0; i < 4; i++) {
        const float4* pp = (const float4*)(pts + (size_t)(pb + i) * 32);
        #pragma unroll
        for (int t = 0; t < 8; t++) {
            float4 f = pp[t];
            x[i][4*t] = f.x; x[i][4*t+1] = f.y; x[i][4*t+2] = f.z; x[i][4*t+3] = f.w;
        }
        float e[32];
        #pragma unroll
        for (int t = 0; t < 32; t++) e[t] = fmul(x[i][t], x[i][t]);
        xp[i] = sum32_np(e);
    }
    float bd[4] = {3.4e38f, 3.4e38f, 3.4e38f, 3.4e38f};
    int bj[4] = {0, 0, 0, 0};
    int jbase = quarter * 64;
    for (int jj = 0; jj < 64; jj++) {
        int j = jbase + jj;
        const float4* cj = (const float4*)(sc + j * 32);
        float w[32];
        #pragma unroll
        for (int t = 0; t < 8; t++) {
            float4 f = cj[t];
            w[4*t] = f.x; w[4*t+1] = f.y; w[4*t+2] = f.z; w[4*t+3] = f.w;
        }
        float sj = scc[j];
        #pragma unroll
        for (int i = 0; i < 4; i++) {
            float g = 0.f;
            #pragma unroll
            for (int t = 0; t < 32; t++) g = __builtin_fmaf(x[i][t], w[t], g);
            float d = fadd(fsub(xp[i], fmul(2.f, g)), sj);
            if (d < bd[i]) { bd[i] = d; bj[i] = j; }
        }
    }
    #pragma unroll
    for (int i = 0; i < 4; i++) {
        float ob; int oj;
        ob = __shfl_xor(bd[i], 1); oj = __shfl_xor(bj[i], 1);
        if (ob < bd[i]) { bd[i] = ob; bj[i] = oj; }
        ob = __shfl_xor(bd[i], 2); oj = __shfl_xor(bj[i], 2);
        if (ob < bd[i]) { bd[i] = ob; bj[i] = oj; }
    }
    if (quarter == 0) {
        #pragma unroll
        for (int i = 0; i < 4; i++) {
            const float* cb = &sc[bj[i] * 32];
            float e[32];
            #pragma unroll
            for (int t = 0; t < 32; t++) e[t] = fabsf(fsub(cb[t], x[i][t]));
            kd[pb + i] = sum32_np(e);
        }
    }
}

// ---------- top-256 via bit-descent select (exact stable set) -------
// T built bit-by-bit: accept bit iff count(u >= cand) >= 256. Yields
// T = 256th-largest uint (== float order, kd >= 0): same threshold and
// remainder r as radix select. No serial LDS chains.
__global__ __launch_bounds__(256) void topk_v3(const float* __restrict__ kd,
        const float* __restrict__ k_t, const float* __restrict__ v_t,
        float* __restrict__ ksel, float* __restrict__ vsel) {
    __shared__ int wsum[4];
    __shared__ int sc1[256];
    __shared__ int out_src[256];
    int bh = blockIdx.x, tid = threadIdx.x;
    int wave = tid >> 6, lane = tid & 63;
    unsigned uv[16];
    {
        const unsigned* kdu = (const unsigned*)(kd + (size_t)bh * 4096);
        #pragma unroll
        for (int q = 0; q < 16; q++) uv[q] = kdu[tid * 16 + q];
    }
    unsigned T = 0u;
    for (int bit = 31; bit >= 0; bit--) {
        unsigned cand = T | (1u << bit);
        int c = 0;
        #pragma unroll
        for (int q = 0; q < 16; q++) c += (uv[q] >= cand) ? 1 : 0;
        c += __shfl_xor(c, 32); c += __shfl_xor(c, 16); c += __shfl_xor(c, 8);
        c += __shfl_xor(c, 4);  c += __shfl_xor(c, 2);  c += __shfl_xor(c, 1);
        if (lane == 0) wsum[wave] = c;
        __syncthreads();
        int tot = wsum[0] + wsum[1] + wsum[2] + wsum[3];
        __syncthreads();
        if (tot >= 256) T = cand;
    }
    int r;
    {
        int c = 0;
        #pragma unroll
        for (int q = 0; q < 16; q++) c += (uv[q] > T) ? 1 : 0;
        c += __shfl_xor(c, 32); c += __shfl_xor(c, 16); c += __shfl_xor(c, 8);
        c += __shfl_xor(c, 4);  c += __shfl_xor(c, 2);  c += __shfl_xor(c, 1);
        if (lane == 0) wsum[wave] = c;
        __syncthreads();
        r = 256 - (wsum[0] + wsum[1] + wsum[2] + wsum[3]);
        __syncthreads();
    }
    // eq-rank scan (index-ascending ties), same as topk_v2
    int ec = 0;
    #pragma unroll
    for (int q = 0; q < 16; q++) ec += (uv[q] == T) ? 1 : 0;
    sc1[tid] = ec;
    __syncthreads();
    for (int d = 1; d < 256; d <<= 1) {
        int t0 = sc1[tid];
        int u0 = (tid >= d) ? sc1[tid - d] : 0;
        __syncthreads();
        sc1[tid] = t0 + u0;
        __syncthreads();
    }
    int erank = (tid == 0) ? 0 : sc1[tid - 1];
    __syncthreads();
    bool incl[16];
    int ic = 0;
    #pragma unroll
    for (int q = 0; q < 16; q++) {
        unsigned u = uv[q];
        bool inc;
        if (u > T) inc = true;
        else if (u == T) { inc = (erank < r); erank++; }
        else inc = false;
        incl[q] = inc;
        ic += inc ? 1 : 0;
    }
    sc1[tid] = ic;
    __syncthreads();
    for (int d = 1; d < 256; d <<= 1) {
        int t0 = sc1[tid];
        int u0 = (tid >= d) ? sc1[tid - d] : 0;
        __syncthreads();
        sc1[tid] = t0 + u0;
        __syncthreads();
    }
    int pos = (tid == 0) ? 0 : sc1[tid - 1];
    int base_i = tid * 16;
    #pragma unroll
    for (int q = 0; q < 16; q++) {
        if (incl[q]) out_src[pos++] = base_i + q;
    }
    __syncthreads();
    for (int e = tid; e < 256 * 32; e += 256) {
        int jj = e >> 5, t = e & 31;
        int src = out_src[jj];
        ksel[(size_t)bh * 8192 + e] = k_t[((size_t)bh * 4096 + src) * 32 + t];
        vsel[(size_t)bh * 8192 + e] = v_t[((size_t)bh * 4096 + src) * 32 + t];
    }
}

// ---------- attention v3d: 4 queries per lane-quad (R18) ------------
#define HPAD 4112
__global__ __launch_bounds__(256) void attn_v3d(const float* __restrict__ q_t,
        const float* __restrict__ ksel, const float* __restrict__ vsel,
        float* __restrict__ out) {
    __shared__ float sk[2 * HPAD];
    __shared__ float sv[2 * HPAD];
    int bh = blockIdx.y, tid = threadIdx.x;
    {
        const float4* gk = (const float4*)(ksel + (size_t)bh * 8192);
        const float4* gv = (const float4*)(vsel + (size_t)bh * 8192);
        for (int i = tid; i < 2048; i += 256) {
            int h = i >> 10, idx = i & 1023;
            ((float4*)(sk + h * HPAD))[idx] = gk[i];
            ((float4*)(sv + h * HPAD))[idx] = gv[i];
        }
    }
    __syncthreads();
    int grp = tid >> 2;
    int slice = tid & 1;
    int dh = (tid >> 1) & 1;
    int p0 = bh * 4096 + blockIdx.x * 256 + grp * 4;
    float q[4][16];
    #pragma unroll
    for (int i = 0; i < 4; i++) {
        const float4* qp = (const float4*)(q_t + (size_t)(p0 + i) * 32 + dh * 16);
        #pragma unroll
        for (int t = 0; t < 4; t++) {
            float4 f = qp[t];
            q[i][4*t] = f.x; q[i][4*t+1] = f.y; q[i][4*t+2] = f.z; q[i][4*t+3] = f.w;
        }
    }
    float o[4][16];
    #pragma unroll
    for (int i = 0; i < 4; i++)
        #pragma unroll
        for (int t = 0; t < 16; t++) o[i][t] = 0.f;
    float ls[4] = {0.f, 0.f, 0.f, 0.f};
    const float* kb = sk + slice * HPAD + dh * 16;
    const float* vb = sv + slice * HPAD + dh * 16;
    for (int j = 0; j < 128; j++) {
        float kf[16];
        #pragma unroll
        for (int t = 0; t < 4; t++) {
            float4 f = *(const float4*)(kb + j * 32 + t * 4);
            kf[4*t] = f.x; kf[4*t+1] = f.y; kf[4*t+2] = f.z; kf[4*t+3] = f.w;
        }
        float ps[4];
        #pragma unroll
        for (int i = 0; i < 4; i++) {
            float a = 0.f, b2 = 0.f, c2 = 0.f, d2 = 0.f;
            #pragma unroll
            for (int t = 0; t < 4; t++) {
                a  += q[i][4*t]   * kf[4*t];
                b2 += q[i][4*t+1] * kf[4*t+1];
                c2 += q[i][4*t+2] * kf[4*t+2];
                d2 += q[i][4*t+3] * kf[4*t+3];
            }
            ps[i] = (a + b2) + (c2 + d2);
        }
        #pragma unroll
        for (int i = 0; i < 4; i++) ps[i] += __shfl_xor(ps[i], 2);
        float w[4];
        #pragma unroll
        for (int i = 0; i < 4; i++) {
            w[i] = __expf(ps[i] - 1.0f);
            ls[i] += w[i];
        }
        float vf[16];
        #pragma unroll
        for (int t = 0; t < 4; t++) {
            float4 f = *(const float4*)(vb + j * 32 + t * 4);
            vf[4*t] = f.x; vf[4*t+1] = f.y; vf[4*t+2] = f.z; vf[4*t+3] = f.w;
        }
        #pragma unroll
        for (int i = 0; i < 4; i++)
            #pragma unroll
            for (int t = 0; t < 16; t++) o[i][t] += w[i] * vf[t];
    }
    #pragma unroll
    for (int i = 0; i < 4; i++) {
        #pragma unroll
        for (int t = 0; t < 16; t++) o[i][t] += __shfl_xor(o[i][t], 1);
        ls[i] += __shfl_xor(ls[i], 1);
    }
    if (slice == 0) {
        #pragma unroll
        for (int i = 0; i < 4; i++) {
            float inv = 1.f / ls[i];
            float4* op = (float4*)(out + (size_t)(p0 + i) * 32 + dh * 16);
            #pragma unroll
            for (int t = 0; t < 4; t++)
                op[t] = make_float4(o[i][4*t]*inv, o[i][4*t+1]*inv,
                                    o[i][4*t+2]*inv, o[i][4*t+3]*inv);
        }
    }
}

// ---------- unfold (bh,L,32) -> (b,256,L) ---------------------------
__global__ __launch_bounds__(256) void unfold_kernel(const float* __restrict__ att,
        float* __restrict__ Fo) {
    __shared__ float tbuf[32][65];
    int bh = blockIdx.y, l0 = blockIdx.x * 64;
    int b = bh >> 3, h = bh & 7;
    int tid = threadIdx.x;
    #pragma unroll
    for (int r = 0; r < 8; r++) {
        int e = r * 256 + tid;
        int l = e >> 5, d = e & 31;
        tbuf[d][l] = att[((size_t)bh * 4096 + l0 + l) * 32 + d];
    }
    __syncthreads();
    #pragma unroll
    for (int r = 0; r < 8; r++) {
        int e = r * 256 + tid;
        int d = e >> 6, l = e & 63;
        Fo[((size_t)b * 256 + h * 32 + d) * LSEQ + l0 + l] = tbuf[d][l];
    }
}

// ---------- final LN + scale + residual (numpy orders) --------------
__global__ __launch_bounds__(64) void lnres_np(const float* __restrict__ x,
        const float* __restrict__ g, const float* __restrict__ bt,
        const float* __restrict__ gs, const float* __restrict__ qsrc,
        float* __restrict__ y) {
    int gid = blockIdx.x * 64 + threadIdx.x;
    int b = gid >> 12, l = gid & 4095;
    const float* xb = x + (size_t)b * CDIM * LSEQ + l;
    float s = 0.f;
    #pragma unroll 8
    for (int c = 0; c < 256; c++) s = fadd(s, xb[(size_t)c * LSEQ]);
    float mean = __fdiv_rn(s, 256.f);
    float s2 = 0.f;
    #pragma unroll 8
    for (int c = 0; c < 256; c++) {
        float d = fsub(xb[(size_t)c * LSEQ], mean);
        s2 = fadd(s2, fmul(d, d));
    }
    float var = __fdiv_rn(s2, 256.f);
    float den = fadd(__fsqrt_rn(var), 1e-6f);
    float scale = gs[0];
    const float* qb = qsrc + (size_t)b * CDIM * LSEQ + l;
    float* yb = y + (size_t)b * CDIM * LSEQ + l;
    #pragma unroll 4
    for (int c = 0; c < 256; c++) {
        float d = fsub(xb[(size_t)c * LSEQ], mean);
        float r = fadd(__fdiv_rn(fmul(g[c], d), den), bt[c]);
        yb[(size_t)c * LSEQ] = fadd(fmul(scale, r), qb[(size_t)c * LSEQ]);
    }
}

// ==================================================================
extern "C" void kernel_launch(void* const* d_in, const int* in_sizes, int n_in,
                              void* d_out, int out_size, void* d_ws, size_t ws_size,
                              hipStream_t stream) {
    const float* qsrc   = (const float*)d_in[0];
    const float* ctx    = (const float*)d_in[1];
    const float* w_q    = (const float*)d_in[2];
    const float* w_kv   = (const float*)d_in[3];
    const float* w_out  = (const float*)d_in[4];
    const float* g_ctx  = (const float*)d_in[5];
    const float* b_ctx  = (const float*)d_in[6];
    const float* g_q    = (const float*)d_in[7];
    const float* b_q    = (const float*)d_in[8];
    const float* g_out  = (const float*)d_in[9];
    const float* b_out  = (const float*)d_in[10];
    const float* gs     = (const float*)d_in[11];

    char* base = (char*)d_ws;
    const size_t MB = 1024 * 1024;
    float* yln   = (float*)base;               // [0,8) ctx LN; later att
    float* att   = (float*)base;
    float* kvbuf = (float*)(base + 8 * MB);    // [8,24) kv conv; later y32 [8,16)
    float* y32   = (float*)(base + 8 * MB);
    float* qbuf  = (float*)(base + 24 * MB);   // [24,32) q conv; later Fo
    float* Fo    = (float*)(base + 24 * MB);
    float* q_t   = (float*)(base + 32 * MB);   // [32,40)
    float* k_t   = (float*)(base + 40 * MB);   // [40,48)
    float* v_t   = (float*)(base + 48 * MB);   // [48,56)
    char* SM = base + 56 * MB;
    float* xx_q      = (float*)(SM + 0);            // 256 KB
    float* cent      = (float*)(SM + 512 * 1024);   // 32 KB
    float* cc        = (float*)(SM + 576 * 1024);   // 1 KB
    int*   totals    = (int*)  (SM + 640 * 1024);   // 1 KB
    int*   asn       = (int*)  (SM + 704 * 1024);   // 256 KB
    int*   hist      = (int*)  (SM + 960 * 1024);   // 256 KB
    int*   chunkbase = (int*)  (SM + 1472 * 1024);  // 256 KB
    int*   perm      = (int*)  (SM + 1984 * 1024);  // 256 KB
    float* kd        = (float*)(SM + 2240 * 1024);  // 256 KB
    float* ksel      = (float*)(SM + 2496 * 1024);  // 512 KB
    float* vsel      = (float*)(SM + 3008 * 1024);  // 512 KB
    float* yln_q     = (float*)(base + 60 * MB);    // [60,68) q LN out

    ln2_np<<<256, 64, 0, stream>>>(ctx, g_ctx, b_ctx, yln,
                                   qsrc, g_q, b_q, yln_q);
    conv_kv<<<dim3(4, 64, 2), 256, 0, stream>>>(w_kv, yln, kvbuf);
    conv_q8<true><<<dim3(4, 32, 2), 256, 0, stream>>>(w_q, yln_q, qbuf);
    fold3_np<<<768, 256, 0, stream>>>(kvbuf, qbuf, k_t, v_t, q_t, xx_q, cent, cc);

    for (int it = 0; it < 10; it++) {
        assign4p<<<256, 256, 0, stream>>>(q_t, xx_q, cent, cc, asn, hist);
        scan_chunks<<<256, 256, 0, stream>>>(hist, chunkbase, totals);
        scatter_v5<<<256, 256, 0, stream>>>(asn, chunkbase, totals, perm);
        sumk_v4<<<256, 256, 0, stream>>>(q_t, perm, totals, cent, cc);
    }

    kdist4p<<<256, 256, 0, stream>>>(k_t, cent, cc, kd);
    topk_v3<<<16, 256, 0, stream>>>(kd, k_t, v_t, ksel, vsel);
    attn_v3d<<<dim3(16, 16), 256, 0, stream>>>(q_t, ksel, vsel, att);
    unfold_kernel<<<dim3(64, 16), 256, 0, stream>>>(att, Fo);
    conv_q8<false><<<dim3(4, 32, 2), 256, 0, stream>>>(w_out, Fo, y32);
    lnres_np<<<128, 64, 0, stream>>>(y32, g_out, b_out, gs, qsrc, (float*)d_out);
}